// Round 1
// baseline (1351.633 us; speedup 1.0000x reference)
//
#include <hip/hip_runtime.h>

#define NN 50000
#define EE 800000
#define DD 128

// ---------------------------------------------------------------------------
// h1 = relu(h @ W + b)   [NN,DD] x [DD,DD]
// block 256 = 2 rows x 128 cols; W staged in 64KB LDS (conflict-free reads)
// ---------------------------------------------------------------------------
__global__ __launch_bounds__(256) void k_linear_relu(
    const float* __restrict__ h, const float* __restrict__ W,
    const float* __restrict__ b, float* __restrict__ out)
{
    __shared__ float Wl[DD * DD];   // 64 KB exactly
    int tid = threadIdx.x;
    for (int i = tid * 4; i < DD * DD; i += 256 * 4)
        *(float4*)&Wl[i] = *(const float4*)&W[i];
    int j  = tid & 127;
    int rr = tid >> 7;
    float bj = b[j];
    __syncthreads();
    for (int r0 = blockIdx.x * 2; r0 < NN; r0 += gridDim.x * 2) {
        int r = r0 + rr;                       // NN even -> always < NN
        const float* hr = h + (size_t)r * DD;
        float acc = 0.f;
        #pragma unroll 4
        for (int k = 0; k < DD; ++k)
            acc = fmaf(hr[k], Wl[k * DD + j], acc);
        float v = acc + bj;
        out[(size_t)r * DD + j] = v > 0.f ? v : 0.f;
    }
}

// ---------------------------------------------------------------------------
// degree histograms for all 4 index arrays
// ---------------------------------------------------------------------------
__global__ __launch_bounds__(256) void k_count(
    const int* __restrict__ s0, const int* __restrict__ d0,
    const int* __restrict__ s1, const int* __restrict__ d1,
    int* cs0, int* cd0, int* cs1, int* cd1)
{
    int i = blockIdx.x * 256 + threadIdx.x;
    int stride = gridDim.x * 256;
    for (; i < EE; i += stride) {
        atomicAdd(&cs0[s0[i]], 1);
        atomicAdd(&cd0[d0[i]], 1);
        atomicAdd(&cs1[s1[i]], 1);
        atomicAdd(&cd1[d1[i]], 1);
    }
}

// ---------------------------------------------------------------------------
// norm = clip(deg,1)^-0.5 for the 4 degree arrays
// ---------------------------------------------------------------------------
__global__ __launch_bounds__(256) void k_norm(
    const int* __restrict__ cs0, const int* __restrict__ cd0,
    const int* __restrict__ cs1, const int* __restrict__ cd1,
    float* ns0, float* nd0, float* ns1, float* nd1)
{
    int i = blockIdx.x * 256 + threadIdx.x;
    if (i < NN) {
        ns0[i] = rsqrtf((float)(cs0[i] > 1 ? cs0[i] : 1));
        nd0[i] = rsqrtf((float)(cd0[i] > 1 ? cd0[i] : 1));
        ns1[i] = rsqrtf((float)(cs1[i] > 1 ? cs1[i] : 1));
        nd1[i] = rsqrtf((float)(cd1[i] > 1 ? cd1[i] : 1));
    }
}

// ---------------------------------------------------------------------------
// single-block exclusive scan of in-degree counts -> CSR offsets (per path)
// grid = 2 blocks (one per path), block = 1024
// ---------------------------------------------------------------------------
__global__ __launch_bounds__(1024) void k_scan(
    const int* __restrict__ cd0, int* off0,
    const int* __restrict__ cd1, int* off1)
{
    const int* cnt = blockIdx.x ? cd1 : cd0;
    int* off       = blockIdx.x ? off1 : off0;
    __shared__ int buf[1024];
    __shared__ int carry;
    int tid = threadIdx.x;
    if (tid == 0) { carry = 0; off[0] = 0; }
    __syncthreads();
    for (int base = 0; base < NN; base += 1024) {
        int i = base + tid;
        int v = (i < NN) ? cnt[i] : 0;
        buf[tid] = v;
        __syncthreads();
        for (int s = 1; s < 1024; s <<= 1) {
            int t = (tid >= s) ? buf[tid - s] : 0;
            __syncthreads();
            buf[tid] += t;
            __syncthreads();
        }
        int inc = buf[tid] + carry;
        if (i < NN) off[i + 1] = inc;
        __syncthreads();
        if (tid == 1023) carry = inc;
        __syncthreads();
    }
}

// ---------------------------------------------------------------------------
// fill CSR edge lists sorted by dst (stores src per slot); grid.y = path
// ---------------------------------------------------------------------------
__global__ __launch_bounds__(256) void k_fill(
    const int* __restrict__ src0, const int* __restrict__ dst0,
    const int* __restrict__ off0, int* cur0, int* es0,
    const int* __restrict__ src1, const int* __restrict__ dst1,
    const int* __restrict__ off1, int* cur1, int* es1)
{
    const int* src = blockIdx.y ? src1 : src0;
    const int* dst = blockIdx.y ? dst1 : dst0;
    const int* off = blockIdx.y ? off1 : off0;
    int* cur       = blockIdx.y ? cur1 : cur0;
    int* es        = blockIdx.y ? es1  : es0;
    int i = blockIdx.x * 256 + threadIdx.x;
    int stride = gridDim.x * 256;
    for (; i < EE; i += stride) {
        int d = dst[i];
        int p = off[d] + atomicAdd(&cur[d], 1);
        es[p] = src[i];
    }
}

// ---------------------------------------------------------------------------
// one APPNP step: xout[v] = 0.9*norm_d[v]*sum_{e:dst=v} norm_s[u]*xin[u] + 0.1*h0[v]
// one wave per node, lane covers 2 of the 128 features (float2)
// ---------------------------------------------------------------------------
__global__ __launch_bounds__(256) void k_appnp(
    const float* __restrict__ xin, float* __restrict__ xout,
    const float* __restrict__ h0,
    const int* __restrict__ off, const int* __restrict__ esrc,
    const float* __restrict__ ns, const float* __restrict__ nd)
{
    int wid  = (blockIdx.x * 256 + threadIdx.x) >> 6;   // node id
    int lane = threadIdx.x & 63;
    if (wid >= NN) return;
    int v = wid;
    int beg = off[v], end = off[v + 1];
    const float2* xin2 = (const float2*)xin;
    float2 acc = make_float2(0.f, 0.f);
    int e = beg;
    for (; e + 1 < end; e += 2) {          // 2-deep unroll for load pipelining
        int u0 = esrc[e], u1 = esrc[e + 1];
        float s0 = ns[u0], s1 = ns[u1];
        float2 a0 = xin2[u0 * 64 + lane];
        float2 a1 = xin2[u1 * 64 + lane];
        acc.x = fmaf(a0.x, s0, acc.x);
        acc.y = fmaf(a0.y, s0, acc.y);
        acc.x = fmaf(a1.x, s1, acc.x);
        acc.y = fmaf(a1.y, s1, acc.y);
    }
    if (e < end) {
        int u0 = esrc[e];
        float s0 = ns[u0];
        float2 a0 = xin2[u0 * 64 + lane];
        acc.x = fmaf(a0.x, s0, acc.x);
        acc.y = fmaf(a0.y, s0, acc.y);
    }
    float scale = 0.9f * nd[v];
    float2 h0v = ((const float2*)h0)[v * 64 + lane];
    float2 r;
    r.x = fmaf(acc.x, scale, 0.1f * h0v.x);
    r.y = fmaf(acc.y, scale, 0.1f * h0v.y);
    ((float2*)xout)[v * 64 + lane] = r;
}

// ---------------------------------------------------------------------------
// S[p] = sum_n tanh(z_p[n] @ W_att + b_att) . q_att      (grid.y = path)
// one atomicAdd per block
// ---------------------------------------------------------------------------
__global__ __launch_bounds__(256) void k_attn(
    const float* __restrict__ z0, const float* __restrict__ z1,
    const float* __restrict__ W, const float* __restrict__ b,
    const float* __restrict__ q, float* __restrict__ S)
{
    __shared__ float Wl[DD * DD];   // 64 KB; tail reused for reduction
    const float* z = blockIdx.y ? z1 : z0;
    int tid = threadIdx.x;
    for (int i = tid * 4; i < DD * DD; i += 256 * 4)
        *(float4*)&Wl[i] = *(const float4*)&W[i];
    int j  = tid & 127;
    int rr = tid >> 7;
    float bj = b[j], qj = q[j];
    __syncthreads();
    float tacc = 0.f;
    for (int r0 = blockIdx.x * 2; r0 < NN; r0 += gridDim.x * 2) {
        int r = r0 + rr;
        const float* zr = z + (size_t)r * DD;
        float acc = 0.f;
        #pragma unroll 4
        for (int k = 0; k < DD; ++k)
            acc = fmaf(zr[k], Wl[k * DD + j], acc);
        tacc += tanhf(acc + bj) * qj;
    }
    __syncthreads();                       // done with W; reuse Wl[0..3]
    for (int s = 32; s > 0; s >>= 1)
        tacc += __shfl_down(tacc, s);      // wave64 reduce
    if ((tid & 63) == 0) Wl[tid >> 6] = tacc;
    __syncthreads();
    if (tid == 0)
        atomicAdd(&S[blockIdx.y], Wl[0] + Wl[1] + Wl[2] + Wl[3]);
}

// ---------------------------------------------------------------------------
// beta = softmax(S/N); out = beta0*z0 + beta1*z1
// ---------------------------------------------------------------------------
__global__ __launch_bounds__(256) void k_combine(
    const float* __restrict__ z0, const float* __restrict__ z1,
    const float* __restrict__ S, float* __restrict__ out)
{
    float w0 = S[0] * (1.0f / NN);
    float w1 = S[1] * (1.0f / NN);
    float m  = fmaxf(w0, w1);
    float e0 = expf(w0 - m), e1 = expf(w1 - m);
    float inv = 1.0f / (e0 + e1);
    float b0 = e0 * inv, b1 = e1 * inv;
    const float4* a = (const float4*)z0;
    const float4* c = (const float4*)z1;
    float4* o = (float4*)out;
    int i = blockIdx.x * 256 + threadIdx.x;
    int stride = gridDim.x * 256;
    for (; i < NN * DD / 4; i += stride) {
        float4 x = a[i], y = c[i];
        float4 r;
        r.x = b0 * x.x + b1 * y.x;
        r.y = b0 * x.y + b1 * y.y;
        r.z = b0 * x.z + b1 * y.z;
        r.w = b0 * x.w + b1 * y.w;
        o[i] = r;
    }
}

// ---------------------------------------------------------------------------
extern "C" void kernel_launch(void* const* d_in, const int* in_sizes, int n_in,
                              void* d_out, int out_size, void* d_ws, size_t ws_size,
                              hipStream_t stream)
{
    const float* h     = (const float*)d_in[0];
    const int*   src0  = (const int*)d_in[1];
    const int*   dst0  = (const int*)d_in[2];
    const int*   src1  = (const int*)d_in[3];
    const int*   dst1  = (const int*)d_in[4];
    const float* W_h   = (const float*)d_in[5];
    const float* b_h   = (const float*)d_in[6];
    const float* W_att = (const float*)d_in[7];
    const float* b_att = (const float*)d_in[8];
    const float* q_att = (const float*)d_in[9];
    float* out = (float*)d_out;

    char* ws = (char*)d_ws;
    size_t o = 0;
    auto alloc = [&](size_t bytes) -> void* {
        void* p = ws + o;
        o += (bytes + 255) & ~(size_t)255;
        return p;
    };
    const size_t ND = (size_t)NN * DD * sizeof(float);
    float* h1 = (float*)alloc(ND);
    float* T  = (float*)alloc(ND);
    float* z0 = (float*)alloc(ND);
    float* z1 = (float*)alloc(ND);
    float* ns0 = (float*)alloc(NN * 4);
    float* nd0 = (float*)alloc(NN * 4);
    float* ns1 = (float*)alloc(NN * 4);
    float* nd1 = (float*)alloc(NN * 4);
    int* off0 = (int*)alloc((NN + 1) * 4);
    int* off1 = (int*)alloc((NN + 1) * 4);
    int* es0  = (int*)alloc(EE * 4);
    int* es1  = (int*)alloc(EE * 4);
    // ---- zeroed region (contiguous): counts(4N) + cursors(2N) + S(2) ----
    char* zbase = (char*)alloc(6 * (size_t)NN * 4 + 256);
    int* cs0 = (int*)zbase;
    int* cd0 = cs0 + NN;
    int* cs1 = cd0 + NN;
    int* cd1 = cs1 + NN;
    int* cur0 = cd1 + NN;
    int* cur1 = cur0 + NN;
    float* S  = (float*)(cur1 + NN);
    hipMemsetAsync(zbase, 0, 6 * (size_t)NN * 4 + 256, stream);

    // 1. h1 = relu(h @ W_h + b_h)
    k_linear_relu<<<1024, 256, 0, stream>>>(h, W_h, b_h, h1);
    // 2. degree histograms
    k_count<<<512, 256, 0, stream>>>(src0, dst0, src1, dst1, cs0, cd0, cs1, cd1);
    // 3. norms
    k_norm<<<(NN + 255) / 256, 256, 0, stream>>>(cs0, cd0, cs1, cd1, ns0, nd0, ns1, nd1);
    // 4. CSR offsets (scan of in-degrees), both paths
    k_scan<<<2, 1024, 0, stream>>>(cd0, off0, cd1, off1);
    // 5. CSR fill
    k_fill<<<dim3(512, 2), 256, 0, stream>>>(src0, dst0, off0, cur0, es0,
                                             src1, dst1, off1, cur1, es1);
    // 6. APPNP: 3 steps per path (ping-pong with single temp T)
    const int ablocks = (NN + 3) / 4;
    // path 0: h1 -> z0 -> T -> z0
    k_appnp<<<ablocks, 256, 0, stream>>>(h1, z0, h1, off0, es0, ns0, nd0);
    k_appnp<<<ablocks, 256, 0, stream>>>(z0, T,  h1, off0, es0, ns0, nd0);
    k_appnp<<<ablocks, 256, 0, stream>>>(T,  z0, h1, off0, es0, ns0, nd0);
    // path 1: h1 -> z1 -> T -> z1
    k_appnp<<<ablocks, 256, 0, stream>>>(h1, z1, h1, off1, es1, ns1, nd1);
    k_appnp<<<ablocks, 256, 0, stream>>>(z1, T,  h1, off1, es1, ns1, nd1);
    k_appnp<<<ablocks, 256, 0, stream>>>(T,  z1, h1, off1, es1, ns1, nd1);
    // 7. semantic attention scores
    k_attn<<<dim3(1024, 2), 256, 0, stream>>>(z0, z1, W_att, b_att, q_att, S);
    // 8. softmax + weighted combine
    k_combine<<<2048, 256, 0, stream>>>(z0, z1, S, out);
    (void)in_sizes; (void)n_in; (void)out_size; (void)ws_size;
}

// Round 2
// 929.906 us; speedup vs baseline: 1.4535x; 1.4535x over previous
//
#include <hip/hip_runtime.h>

#define NN 50000
#define EE 800000
#define DD 128

// ---------------------------------------------------------------------------
// h1 = relu(h @ W + b)   [NN,DD] x [DD,DD]
// block 256 = 16 rows x 32 colgroups (float4). W staged in 64KB LDS.
// Each thread: 2 rows x 4 cols, A read as broadcast float4, W as ds_read_b128.
// ---------------------------------------------------------------------------
__global__ __launch_bounds__(256) void k_linear_relu(
    const float* __restrict__ h, const float* __restrict__ W,
    const float* __restrict__ b, float* __restrict__ out)
{
    __shared__ float Wl[DD * DD];   // 64 KB exactly
    int tid = threadIdx.x;
    for (int i = tid * 4; i < DD * DD; i += 256 * 4)
        *(float4*)&Wl[i] = *(const float4*)&W[i];
    int cg = tid & 31;              // colgroup: cols 4cg..4cg+3
    int rr = tid >> 5;              // 0..7
    float4 bj = *(const float4*)&b[cg * 4];
    __syncthreads();
    const float4* h4 = (const float4*)h;
    for (int t = blockIdx.x * 16; t < NN; t += gridDim.x * 16) {
        int r0 = t + rr, r1 = r0 + 8;            // NN % 16 == 0
        float4 acc0 = make_float4(0.f, 0.f, 0.f, 0.f);
        float4 acc1 = make_float4(0.f, 0.f, 0.f, 0.f);
        #pragma unroll 4
        for (int kk = 0; kk < 32; ++kk) {
            float4 a0 = h4[(size_t)r0 * 32 + kk];
            float4 a1 = h4[(size_t)r1 * 32 + kk];
            const float* wb = &Wl[(kk * 4) * DD + cg * 4];
            float4 w;
            w = *(const float4*)(wb);
            acc0.x = fmaf(a0.x, w.x, acc0.x); acc0.y = fmaf(a0.x, w.y, acc0.y);
            acc0.z = fmaf(a0.x, w.z, acc0.z); acc0.w = fmaf(a0.x, w.w, acc0.w);
            acc1.x = fmaf(a1.x, w.x, acc1.x); acc1.y = fmaf(a1.x, w.y, acc1.y);
            acc1.z = fmaf(a1.x, w.z, acc1.z); acc1.w = fmaf(a1.x, w.w, acc1.w);
            w = *(const float4*)(wb + DD);
            acc0.x = fmaf(a0.y, w.x, acc0.x); acc0.y = fmaf(a0.y, w.y, acc0.y);
            acc0.z = fmaf(a0.y, w.z, acc0.z); acc0.w = fmaf(a0.y, w.w, acc0.w);
            acc1.x = fmaf(a1.y, w.x, acc1.x); acc1.y = fmaf(a1.y, w.y, acc1.y);
            acc1.z = fmaf(a1.y, w.z, acc1.z); acc1.w = fmaf(a1.y, w.w, acc1.w);
            w = *(const float4*)(wb + 2 * DD);
            acc0.x = fmaf(a0.z, w.x, acc0.x); acc0.y = fmaf(a0.z, w.y, acc0.y);
            acc0.z = fmaf(a0.z, w.z, acc0.z); acc0.w = fmaf(a0.z, w.w, acc0.w);
            acc1.x = fmaf(a1.z, w.x, acc1.x); acc1.y = fmaf(a1.z, w.y, acc1.y);
            acc1.z = fmaf(a1.z, w.z, acc1.z); acc1.w = fmaf(a1.z, w.w, acc1.w);
            w = *(const float4*)(wb + 3 * DD);
            acc0.x = fmaf(a0.w, w.x, acc0.x); acc0.y = fmaf(a0.w, w.y, acc0.y);
            acc0.z = fmaf(a0.w, w.z, acc0.z); acc0.w = fmaf(a0.w, w.w, acc0.w);
            acc1.x = fmaf(a1.w, w.x, acc1.x); acc1.y = fmaf(a1.w, w.y, acc1.y);
            acc1.z = fmaf(a1.w, w.z, acc1.z); acc1.w = fmaf(a1.w, w.w, acc1.w);
        }
        float4 o0, o1;
        o0.x = fmaxf(acc0.x + bj.x, 0.f); o0.y = fmaxf(acc0.y + bj.y, 0.f);
        o0.z = fmaxf(acc0.z + bj.z, 0.f); o0.w = fmaxf(acc0.w + bj.w, 0.f);
        o1.x = fmaxf(acc1.x + bj.x, 0.f); o1.y = fmaxf(acc1.y + bj.y, 0.f);
        o1.z = fmaxf(acc1.z + bj.z, 0.f); o1.w = fmaxf(acc1.w + bj.w, 0.f);
        ((float4*)out)[(size_t)r0 * 32 + cg] = o0;
        ((float4*)out)[(size_t)r1 * 32 + cg] = o1;
    }
}

// ---------------------------------------------------------------------------
// degree histograms for all 4 index arrays
// ---------------------------------------------------------------------------
__global__ __launch_bounds__(256) void k_count(
    const int* __restrict__ s0, const int* __restrict__ d0,
    const int* __restrict__ s1, const int* __restrict__ d1,
    int* cs0, int* cd0, int* cs1, int* cd1)
{
    int i = blockIdx.x * 256 + threadIdx.x;
    int stride = gridDim.x * 256;
    for (; i < EE; i += stride) {
        atomicAdd(&cs0[s0[i]], 1);
        atomicAdd(&cd0[d0[i]], 1);
        atomicAdd(&cs1[s1[i]], 1);
        atomicAdd(&cd1[d1[i]], 1);
    }
}

// ---------------------------------------------------------------------------
// norm = clip(deg,1)^-0.5 for the 4 degree arrays
// ---------------------------------------------------------------------------
__global__ __launch_bounds__(256) void k_norm(
    const int* __restrict__ cs0, const int* __restrict__ cd0,
    const int* __restrict__ cs1, const int* __restrict__ cd1,
    float* ns0, float* nd0, float* ns1, float* nd1)
{
    int i = blockIdx.x * 256 + threadIdx.x;
    if (i < NN) {
        ns0[i] = rsqrtf((float)(cs0[i] > 1 ? cs0[i] : 1));
        nd0[i] = rsqrtf((float)(cd0[i] > 1 ? cd0[i] : 1));
        ns1[i] = rsqrtf((float)(cs1[i] > 1 ? cs1[i] : 1));
        nd1[i] = rsqrtf((float)(cd1[i] > 1 ? cd1[i] : 1));
    }
}

// ---------------------------------------------------------------------------
// single-block exclusive scan of in-degree counts -> CSR offsets (per path)
// ---------------------------------------------------------------------------
__global__ __launch_bounds__(1024) void k_scan(
    const int* __restrict__ cd0, int* off0,
    const int* __restrict__ cd1, int* off1)
{
    const int* cnt = blockIdx.x ? cd1 : cd0;
    int* off       = blockIdx.x ? off1 : off0;
    __shared__ int buf[1024];
    __shared__ int carry;
    int tid = threadIdx.x;
    if (tid == 0) { carry = 0; off[0] = 0; }
    __syncthreads();
    for (int base = 0; base < NN; base += 1024) {
        int i = base + tid;
        int v = (i < NN) ? cnt[i] : 0;
        buf[tid] = v;
        __syncthreads();
        for (int s = 1; s < 1024; s <<= 1) {
            int t = (tid >= s) ? buf[tid - s] : 0;
            __syncthreads();
            buf[tid] += t;
            __syncthreads();
        }
        int inc = buf[tid] + carry;
        if (i < NN) off[i + 1] = inc;
        __syncthreads();
        if (tid == 1023) carry = inc;
        __syncthreads();
    }
}

// ---------------------------------------------------------------------------
// fill CSR edge lists sorted by dst (stores src per slot); grid.y = path
// ---------------------------------------------------------------------------
__global__ __launch_bounds__(256) void k_fill(
    const int* __restrict__ src0, const int* __restrict__ dst0,
    const int* __restrict__ off0, int* cur0, int* es0,
    const int* __restrict__ src1, const int* __restrict__ dst1,
    const int* __restrict__ off1, int* cur1, int* es1)
{
    const int* src = blockIdx.y ? src1 : src0;
    const int* dst = blockIdx.y ? dst1 : dst0;
    const int* off = blockIdx.y ? off1 : off0;
    int* cur       = blockIdx.y ? cur1 : cur0;
    int* es        = blockIdx.y ? es1  : es0;
    int i = blockIdx.x * 256 + threadIdx.x;
    int stride = gridDim.x * 256;
    for (; i < EE; i += stride) {
        int d = dst[i];
        int p = off[d] + atomicAdd(&cur[d], 1);
        es[p] = src[i];
    }
}

// ---------------------------------------------------------------------------
// one APPNP step: xout[v] = 0.9*nd[v]*sum_{e:dst=v} ns[u]*xin[u] + 0.1*h0[v]
// one wave per node, lane covers 2 of the 128 features (float2)
// ---------------------------------------------------------------------------
__global__ __launch_bounds__(256) void k_appnp(
    const float* __restrict__ xin, float* __restrict__ xout,
    const float* __restrict__ h0,
    const int* __restrict__ off, const int* __restrict__ esrc,
    const float* __restrict__ ns, const float* __restrict__ nd)
{
    int wid  = (blockIdx.x * 256 + threadIdx.x) >> 6;   // node id
    int lane = threadIdx.x & 63;
    if (wid >= NN) return;
    int v = wid;
    int beg = off[v], end = off[v + 1];
    const float2* xin2 = (const float2*)xin;
    float2 acc = make_float2(0.f, 0.f);
    int e = beg;
    for (; e + 1 < end; e += 2) {
        int u0 = esrc[e], u1 = esrc[e + 1];
        float s0 = ns[u0], s1 = ns[u1];
        float2 a0 = xin2[u0 * 64 + lane];
        float2 a1 = xin2[u1 * 64 + lane];
        acc.x = fmaf(a0.x, s0, acc.x);
        acc.y = fmaf(a0.y, s0, acc.y);
        acc.x = fmaf(a1.x, s1, acc.x);
        acc.y = fmaf(a1.y, s1, acc.y);
    }
    if (e < end) {
        int u0 = esrc[e];
        float s0 = ns[u0];
        float2 a0 = xin2[u0 * 64 + lane];
        acc.x = fmaf(a0.x, s0, acc.x);
        acc.y = fmaf(a0.y, s0, acc.y);
    }
    float scale = 0.9f * nd[v];
    float2 h0v = ((const float2*)h0)[v * 64 + lane];
    float2 r;
    r.x = fmaf(acc.x, scale, 0.1f * h0v.x);
    r.y = fmaf(acc.y, scale, 0.1f * h0v.y);
    ((float2*)xout)[v * 64 + lane] = r;
}

// ---------------------------------------------------------------------------
// S[p] = sum_n tanh(z_p[n] @ W_att + b_att) . q_att      (grid.y = path)
// same tiling as k_linear_relu; one atomicAdd per block
// ---------------------------------------------------------------------------
__global__ __launch_bounds__(256) void k_attn(
    const float* __restrict__ z0, const float* __restrict__ z1,
    const float* __restrict__ W, const float* __restrict__ b,
    const float* __restrict__ q, float* __restrict__ S)
{
    __shared__ float Wl[DD * DD];   // 64 KB; head reused for reduction
    const float* z = blockIdx.y ? z1 : z0;
    int tid = threadIdx.x;
    for (int i = tid * 4; i < DD * DD; i += 256 * 4)
        *(float4*)&Wl[i] = *(const float4*)&W[i];
    int cg = tid & 31;
    int rr = tid >> 5;
    float4 bj = *(const float4*)&b[cg * 4];
    float4 qj = *(const float4*)&q[cg * 4];
    __syncthreads();
    const float4* z4 = (const float4*)z;
    float tacc = 0.f;
    for (int t = blockIdx.x * 16; t < NN; t += gridDim.x * 16) {
        int r0 = t + rr, r1 = r0 + 8;
        float4 acc0 = make_float4(0.f, 0.f, 0.f, 0.f);
        float4 acc1 = make_float4(0.f, 0.f, 0.f, 0.f);
        #pragma unroll 4
        for (int kk = 0; kk < 32; ++kk) {
            float4 a0 = z4[(size_t)r0 * 32 + kk];
            float4 a1 = z4[(size_t)r1 * 32 + kk];
            const float* wb = &Wl[(kk * 4) * DD + cg * 4];
            float4 w;
            w = *(const float4*)(wb);
            acc0.x = fmaf(a0.x, w.x, acc0.x); acc0.y = fmaf(a0.x, w.y, acc0.y);
            acc0.z = fmaf(a0.x, w.z, acc0.z); acc0.w = fmaf(a0.x, w.w, acc0.w);
            acc1.x = fmaf(a1.x, w.x, acc1.x); acc1.y = fmaf(a1.x, w.y, acc1.y);
            acc1.z = fmaf(a1.x, w.z, acc1.z); acc1.w = fmaf(a1.x, w.w, acc1.w);
            w = *(const float4*)(wb + DD);
            acc0.x = fmaf(a0.y, w.x, acc0.x); acc0.y = fmaf(a0.y, w.y, acc0.y);
            acc0.z = fmaf(a0.y, w.z, acc0.z); acc0.w = fmaf(a0.y, w.w, acc0.w);
            acc1.x = fmaf(a1.y, w.x, acc1.x); acc1.y = fmaf(a1.y, w.y, acc1.y);
            acc1.z = fmaf(a1.y, w.z, acc1.z); acc1.w = fmaf(a1.y, w.w, acc1.w);
            w = *(const float4*)(wb + 2 * DD);
            acc0.x = fmaf(a0.z, w.x, acc0.x); acc0.y = fmaf(a0.z, w.y, acc0.y);
            acc0.z = fmaf(a0.z, w.z, acc0.z); acc0.w = fmaf(a0.z, w.w, acc0.w);
            acc1.x = fmaf(a1.z, w.x, acc1.x); acc1.y = fmaf(a1.z, w.y, acc1.y);
            acc1.z = fmaf(a1.z, w.z, acc1.z); acc1.w = fmaf(a1.z, w.w, acc1.w);
            w = *(const float4*)(wb + 3 * DD);
            acc0.x = fmaf(a0.w, w.x, acc0.x); acc0.y = fmaf(a0.w, w.y, acc0.y);
            acc0.z = fmaf(a0.w, w.z, acc0.z); acc0.w = fmaf(a0.w, w.w, acc0.w);
            acc1.x = fmaf(a1.w, w.x, acc1.x); acc1.y = fmaf(a1.w, w.y, acc1.y);
            acc1.z = fmaf(a1.w, w.z, acc1.z); acc1.w = fmaf(a1.w, w.w, acc1.w);
        }
        tacc += tanhf(acc0.x + bj.x) * qj.x + tanhf(acc0.y + bj.y) * qj.y
              + tanhf(acc0.z + bj.z) * qj.z + tanhf(acc0.w + bj.w) * qj.w;
        tacc += tanhf(acc1.x + bj.x) * qj.x + tanhf(acc1.y + bj.y) * qj.y
              + tanhf(acc1.z + bj.z) * qj.z + tanhf(acc1.w + bj.w) * qj.w;
    }
    __syncthreads();                 // all reads of Wl done
    for (int s = 32; s > 0; s >>= 1)
        tacc += __shfl_down(tacc, s);
    if ((tid & 63) == 0) Wl[tid >> 6] = tacc;
    __syncthreads();
    if (tid == 0)
        atomicAdd(&S[blockIdx.y], Wl[0] + Wl[1] + Wl[2] + Wl[3]);
}

// ---------------------------------------------------------------------------
// beta = softmax(S/N); out = beta0*z0 + beta1*z1
// ---------------------------------------------------------------------------
__global__ __launch_bounds__(256) void k_combine(
    const float* __restrict__ z0, const float* __restrict__ z1,
    const float* __restrict__ S, float* __restrict__ out)
{
    float w0 = S[0] * (1.0f / NN);
    float w1 = S[1] * (1.0f / NN);
    float m  = fmaxf(w0, w1);
    float e0 = expf(w0 - m), e1 = expf(w1 - m);
    float inv = 1.0f / (e0 + e1);
    float b0 = e0 * inv, b1 = e1 * inv;
    const float4* a = (const float4*)z0;
    const float4* c = (const float4*)z1;
    float4* o = (float4*)out;
    int i = blockIdx.x * 256 + threadIdx.x;
    int stride = gridDim.x * 256;
    for (; i < NN * DD / 4; i += stride) {
        float4 x = a[i], y = c[i];
        float4 r;
        r.x = b0 * x.x + b1 * y.x;
        r.y = b0 * x.y + b1 * y.y;
        r.z = b0 * x.z + b1 * y.z;
        r.w = b0 * x.w + b1 * y.w;
        o[i] = r;
    }
}

// ---------------------------------------------------------------------------
extern "C" void kernel_launch(void* const* d_in, const int* in_sizes, int n_in,
                              void* d_out, int out_size, void* d_ws, size_t ws_size,
                              hipStream_t stream)
{
    const float* h     = (const float*)d_in[0];
    const int*   src0  = (const int*)d_in[1];
    const int*   dst0  = (const int*)d_in[2];
    const int*   src1  = (const int*)d_in[3];
    const int*   dst1  = (const int*)d_in[4];
    const float* W_h   = (const float*)d_in[5];
    const float* b_h   = (const float*)d_in[6];
    const float* W_att = (const float*)d_in[7];
    const float* b_att = (const float*)d_in[8];
    const float* q_att = (const float*)d_in[9];
    float* out = (float*)d_out;

    char* ws = (char*)d_ws;
    size_t o = 0;
    auto alloc = [&](size_t bytes) -> void* {
        void* p = ws + o;
        o += (bytes + 255) & ~(size_t)255;
        return p;
    };
    const size_t ND = (size_t)NN * DD * sizeof(float);
    float* h1 = (float*)alloc(ND);
    float* T  = (float*)alloc(ND);
    float* z0 = (float*)alloc(ND);
    float* z1 = (float*)alloc(ND);
    float* ns0 = (float*)alloc(NN * 4);
    float* nd0 = (float*)alloc(NN * 4);
    float* ns1 = (float*)alloc(NN * 4);
    float* nd1 = (float*)alloc(NN * 4);
    int* off0 = (int*)alloc((NN + 1) * 4);
    int* off1 = (int*)alloc((NN + 1) * 4);
    int* es0  = (int*)alloc(EE * 4);
    int* es1  = (int*)alloc(EE * 4);
    // ---- zeroed region (contiguous): counts(4N) + cursors(2N) + S(2) ----
    char* zbase = (char*)alloc(6 * (size_t)NN * 4 + 256);
    int* cs0 = (int*)zbase;
    int* cd0 = cs0 + NN;
    int* cs1 = cd0 + NN;
    int* cd1 = cs1 + NN;
    int* cur0 = cd1 + NN;
    int* cur1 = cur0 + NN;
    float* S  = (float*)(cur1 + NN);
    hipMemsetAsync(zbase, 0, 6 * (size_t)NN * 4 + 256, stream);

    // 1. h1 = relu(h @ W_h + b_h)
    k_linear_relu<<<1024, 256, 0, stream>>>(h, W_h, b_h, h1);
    // 2. degree histograms
    k_count<<<512, 256, 0, stream>>>(src0, dst0, src1, dst1, cs0, cd0, cs1, cd1);
    // 3. norms
    k_norm<<<(NN + 255) / 256, 256, 0, stream>>>(cs0, cd0, cs1, cd1, ns0, nd0, ns1, nd1);
    // 4. CSR offsets (scan of in-degrees), both paths
    k_scan<<<2, 1024, 0, stream>>>(cd0, off0, cd1, off1);
    // 5. CSR fill
    k_fill<<<dim3(512, 2), 256, 0, stream>>>(src0, dst0, off0, cur0, es0,
                                             src1, dst1, off1, cur1, es1);
    // 6. APPNP: 3 steps per path (ping-pong with single temp T)
    const int ablocks = (NN + 3) / 4;
    k_appnp<<<ablocks, 256, 0, stream>>>(h1, z0, h1, off0, es0, ns0, nd0);
    k_appnp<<<ablocks, 256, 0, stream>>>(z0, T,  h1, off0, es0, ns0, nd0);
    k_appnp<<<ablocks, 256, 0, stream>>>(T,  z0, h1, off0, es0, ns0, nd0);
    k_appnp<<<ablocks, 256, 0, stream>>>(h1, z1, h1, off1, es1, ns1, nd1);
    k_appnp<<<ablocks, 256, 0, stream>>>(z1, T,  h1, off1, es1, ns1, nd1);
    k_appnp<<<ablocks, 256, 0, stream>>>(T,  z1, h1, off1, es1, ns1, nd1);
    // 7. semantic attention scores
    k_attn<<<dim3(1024, 2), 256, 0, stream>>>(z0, z1, W_att, b_att, q_att, S);
    // 8. softmax + weighted combine
    k_combine<<<2048, 256, 0, stream>>>(z0, z1, S, out);
    (void)in_sizes; (void)n_in; (void)out_size; (void)ws_size;
}

// Round 3
// 719.501 us; speedup vs baseline: 1.8786x; 1.2924x over previous
//
#include <hip/hip_runtime.h>

#define NN 50000
#define EE 800000
#define DD 128
#define NCHUNK 32
#define CH (EE / NCHUNK)        // 25000
#define NRANGE 4
#define RSIZE (NN / NRANGE)     // 12500
#define NSB 49                  // ceil(NN/1024)

// ---------------------------------------------------------------------------
// h1 = relu(h @ W + b)   [NN,DD] x [DD,DD]
// block 256 = 16 rows x 32 colgroups (float4). W staged in 64KB LDS.
// ---------------------------------------------------------------------------
__global__ __launch_bounds__(256) void k_linear_relu(
    const float* __restrict__ h, const float* __restrict__ W,
    const float* __restrict__ b, float* __restrict__ out)
{
    __shared__ float Wl[DD * DD];
    int tid = threadIdx.x;
    for (int i = tid * 4; i < DD * DD; i += 256 * 4)
        *(float4*)&Wl[i] = *(const float4*)&W[i];
    int cg = tid & 31;
    int rr = tid >> 5;
    float4 bj = *(const float4*)&b[cg * 4];
    __syncthreads();
    const float4* h4 = (const float4*)h;
    for (int t = blockIdx.x * 16; t < NN; t += gridDim.x * 16) {
        int r0 = t + rr, r1 = r0 + 8;
        float4 acc0 = make_float4(0.f, 0.f, 0.f, 0.f);
        float4 acc1 = make_float4(0.f, 0.f, 0.f, 0.f);
        #pragma unroll 4
        for (int kk = 0; kk < 32; ++kk) {
            float4 a0 = h4[(size_t)r0 * 32 + kk];
            float4 a1 = h4[(size_t)r1 * 32 + kk];
            const float* wb = &Wl[(kk * 4) * DD + cg * 4];
            float4 w;
            w = *(const float4*)(wb);
            acc0.x = fmaf(a0.x, w.x, acc0.x); acc0.y = fmaf(a0.x, w.y, acc0.y);
            acc0.z = fmaf(a0.x, w.z, acc0.z); acc0.w = fmaf(a0.x, w.w, acc0.w);
            acc1.x = fmaf(a1.x, w.x, acc1.x); acc1.y = fmaf(a1.x, w.y, acc1.y);
            acc1.z = fmaf(a1.x, w.z, acc1.z); acc1.w = fmaf(a1.x, w.w, acc1.w);
            w = *(const float4*)(wb + DD);
            acc0.x = fmaf(a0.y, w.x, acc0.x); acc0.y = fmaf(a0.y, w.y, acc0.y);
            acc0.z = fmaf(a0.y, w.z, acc0.z); acc0.w = fmaf(a0.y, w.w, acc0.w);
            acc1.x = fmaf(a1.y, w.x, acc1.x); acc1.y = fmaf(a1.y, w.y, acc1.y);
            acc1.z = fmaf(a1.y, w.z, acc1.z); acc1.w = fmaf(a1.y, w.w, acc1.w);
            w = *(const float4*)(wb + 2 * DD);
            acc0.x = fmaf(a0.z, w.x, acc0.x); acc0.y = fmaf(a0.z, w.y, acc0.y);
            acc0.z = fmaf(a0.z, w.z, acc0.z); acc0.w = fmaf(a0.z, w.w, acc0.w);
            acc1.x = fmaf(a1.z, w.x, acc1.x); acc1.y = fmaf(a1.z, w.y, acc1.y);
            acc1.z = fmaf(a1.z, w.z, acc1.z); acc1.w = fmaf(a1.z, w.w, acc1.w);
            w = *(const float4*)(wb + 3 * DD);
            acc0.x = fmaf(a0.w, w.x, acc0.x); acc0.y = fmaf(a0.w, w.y, acc0.y);
            acc0.z = fmaf(a0.w, w.z, acc0.z); acc0.w = fmaf(a0.w, w.w, acc0.w);
            acc1.x = fmaf(a1.w, w.x, acc1.x); acc1.y = fmaf(a1.w, w.y, acc1.y);
            acc1.z = fmaf(a1.w, w.z, acc1.z); acc1.w = fmaf(a1.w, w.w, acc1.w);
        }
        float4 o0, o1;
        o0.x = fmaxf(acc0.x + bj.x, 0.f); o0.y = fmaxf(acc0.y + bj.y, 0.f);
        o0.z = fmaxf(acc0.z + bj.z, 0.f); o0.w = fmaxf(acc0.w + bj.w, 0.f);
        o1.x = fmaxf(acc1.x + bj.x, 0.f); o1.y = fmaxf(acc1.y + bj.y, 0.f);
        o1.z = fmaxf(acc1.z + bj.z, 0.f); o1.w = fmaxf(acc1.w + bj.w, 0.f);
        ((float4*)out)[(size_t)r0 * 32 + cg] = o0;
        ((float4*)out)[(size_t)r1 * 32 + cg] = o1;
    }
}

// ---------------------------------------------------------------------------
// per-chunk partial histograms, LDS-atomic only, plain stores out.
// grid = (NCHUNK, NRANGE, 4 arrays); partial[a][c][node]
// ---------------------------------------------------------------------------
__global__ __launch_bounds__(256) void k_hist(
    const int* __restrict__ s0, const int* __restrict__ d0,
    const int* __restrict__ s1, const int* __restrict__ d1,
    int* __restrict__ partial)
{
    __shared__ int hist[RSIZE];          // 50 KB
    int c = blockIdx.x, rg = blockIdx.y, a = blockIdx.z;
    const int* idx = (a == 0) ? s0 : (a == 1) ? d0 : (a == 2) ? s1 : d1;
    int lo = rg * RSIZE;
    for (int i = threadIdx.x; i < RSIZE; i += 256) hist[i] = 0;
    __syncthreads();
    int beg = c * CH, end = beg + CH;
    for (int i = beg + threadIdx.x; i < end; i += 256) {
        int v = idx[i] - lo;
        if ((unsigned)v < (unsigned)RSIZE) atomicAdd(&hist[v], 1);
    }
    __syncthreads();
    int* dst = partial + ((size_t)a * NCHUNK + c) * NN + lo;
    for (int i = threadIdx.x; i < RSIZE; i += 256) dst[i] = hist[i];
}

// ---------------------------------------------------------------------------
// reduce partials -> degree + norm; for dst arrays (a odd) convert partials
// in-place to per-chunk EXCLUSIVE prefix (for atomic-free CSR fill).
// grid = (ceil(NN/256), 4)
// ---------------------------------------------------------------------------
__global__ __launch_bounds__(256) void k_reduce(
    int* __restrict__ partial,
    float* ns0, float* nd0, float* ns1, float* nd1,
    int* cdeg0, int* cdeg1)
{
    int n = blockIdx.x * 256 + threadIdx.x;
    int a = blockIdx.y;
    if (n >= NN) return;
    int run = 0;
    bool isdst = a & 1;
    for (int c = 0; c < NCHUNK; ++c) {
        size_t ix = ((size_t)a * NCHUNK + c) * NN + n;
        int t = partial[ix];
        if (isdst) partial[ix] = run;
        run += t;
    }
    float nv = rsqrtf((float)(run > 1 ? run : 1));
    if (a == 0) ns0[n] = nv;
    else if (a == 1) { nd0[n] = nv; cdeg0[n] = run; }
    else if (a == 2) ns1[n] = nv;
    else { nd1[n] = nv; cdeg1[n] = run; }
}

// ---------------------------------------------------------------------------
// scan pass 1: per 1024-node block sums.  grid = (NSB, 2)
// ---------------------------------------------------------------------------
__global__ __launch_bounds__(256) void k_scan1(
    const int* __restrict__ cdeg0, const int* __restrict__ cdeg1,
    int* __restrict__ bsum)
{
    const int* dg = blockIdx.y ? cdeg1 : cdeg0;
    __shared__ int ws_[4];
    int tid = threadIdx.x;
    int n0 = blockIdx.x * 1024 + tid * 4;
    int s = 0;
    #pragma unroll
    for (int k = 0; k < 4; ++k) {
        int n = n0 + k;
        if (n < NN) s += dg[n];
    }
    for (int sh = 32; sh > 0; sh >>= 1) s += __shfl_down(s, sh);
    if ((tid & 63) == 0) ws_[tid >> 6] = s;
    __syncthreads();
    if (tid == 0)
        bsum[blockIdx.y * NSB + blockIdx.x] = ws_[0] + ws_[1] + ws_[2] + ws_[3];
}

// ---------------------------------------------------------------------------
// scan pass 2: tiny serial scan of block sums (both paths), writes off[NN]
// ---------------------------------------------------------------------------
__global__ __launch_bounds__(64) void k_scan2(
    const int* __restrict__ bsum, int* __restrict__ bbase,
    int* off0, int* off1)
{
    int p = threadIdx.x;
    if (p < 2) {
        int run = 0;
        for (int b = 0; b < NSB; ++b) {
            bbase[p * NSB + b] = run;
            run += bsum[p * NSB + b];
        }
        (p ? off1 : off0)[NN] = run;
    }
}

// ---------------------------------------------------------------------------
// scan pass 3: per-block exclusive scan + base, writes off[0..NN-1]
// ---------------------------------------------------------------------------
__global__ __launch_bounds__(256) void k_scan3(
    const int* __restrict__ cdeg0, const int* __restrict__ cdeg1,
    const int* __restrict__ bbase, int* off0, int* off1)
{
    const int* dg = blockIdx.y ? cdeg1 : cdeg0;
    int* off      = blockIdx.y ? off1  : off0;
    __shared__ int ts[256];
    int tid = threadIdx.x;
    int n0 = blockIdx.x * 1024 + tid * 4;
    int d0 = 0, d1 = 0, d2 = 0, d3 = 0;
    if (n0 + 0 < NN) d0 = dg[n0 + 0];
    if (n0 + 1 < NN) d1 = dg[n0 + 1];
    if (n0 + 2 < NN) d2 = dg[n0 + 2];
    if (n0 + 3 < NN) d3 = dg[n0 + 3];
    int tot = d0 + d1 + d2 + d3;
    ts[tid] = tot;
    __syncthreads();
    for (int s = 1; s < 256; s <<= 1) {
        int u = (tid >= s) ? ts[tid - s] : 0;
        __syncthreads();
        ts[tid] += u;
        __syncthreads();
    }
    int base = bbase[blockIdx.y * NSB + blockIdx.x] + ts[tid] - tot;
    if (n0 + 0 < NN) off[n0 + 0] = base;
    if (n0 + 1 < NN) off[n0 + 1] = base + d0;
    if (n0 + 2 < NN) off[n0 + 2] = base + d0 + d1;
    if (n0 + 3 < NN) off[n0 + 3] = base + d0 + d1 + d2;
}

// ---------------------------------------------------------------------------
// atomic-free CSR fill: slot = off[d] + chunk_prefix[c][d] + lds_rank
// grid = (NCHUNK, NRANGE, 2 paths)
// ---------------------------------------------------------------------------
__global__ __launch_bounds__(256) void k_fill2(
    const int* __restrict__ src0, const int* __restrict__ dst0,
    const int* __restrict__ src1, const int* __restrict__ dst1,
    const int* __restrict__ partial,
    const int* __restrict__ off0, const int* __restrict__ off1,
    int* __restrict__ es0, int* __restrict__ es1)
{
    __shared__ int cur[RSIZE];           // 50 KB
    int c = blockIdx.x, rg = blockIdx.y, p = blockIdx.z;
    const int* src = p ? src1 : src0;
    const int* dst = p ? dst1 : dst0;
    const int* off = p ? off1 : off0;
    int* es        = p ? es1  : es0;
    const int* pfx = partial + ((size_t)(1 + 2 * p) * NCHUNK + c) * NN;
    int lo = rg * RSIZE;
    for (int i = threadIdx.x; i < RSIZE; i += 256) cur[i] = 0;
    __syncthreads();
    int beg = c * CH, end = beg + CH;
    for (int i = beg + threadIdx.x; i < end; i += 256) {
        int d = dst[i];
        int s = src[i];
        int v = d - lo;
        if ((unsigned)v < (unsigned)RSIZE) {
            int r = atomicAdd(&cur[v], 1);
            es[off[d] + pfx[d] + r] = s;
        }
    }
}

// ---------------------------------------------------------------------------
// one APPNP step: xout[v] = 0.9*nd[v]*sum_{e:dst=v} ns[u]*xin[u] + 0.1*h0[v]
// one wave per node, lane covers 2 of the 128 features; 4-deep edge unroll
// ---------------------------------------------------------------------------
__global__ __launch_bounds__(256) void k_appnp(
    const float* __restrict__ xin, float* __restrict__ xout,
    const float* __restrict__ h0,
    const int* __restrict__ off, const int* __restrict__ esrc,
    const float* __restrict__ ns, const float* __restrict__ nd)
{
    int wid  = (blockIdx.x * 256 + threadIdx.x) >> 6;
    int lane = threadIdx.x & 63;
    if (wid >= NN) return;
    int v = wid;
    int beg = off[v], end = off[v + 1];
    const float2* xin2 = (const float2*)xin;
    float2 acc = make_float2(0.f, 0.f);
    int e = beg;
    for (; e + 3 < end; e += 4) {
        int u0 = esrc[e], u1 = esrc[e + 1], u2 = esrc[e + 2], u3 = esrc[e + 3];
        float s0 = ns[u0], s1 = ns[u1], s2 = ns[u2], s3 = ns[u3];
        float2 a0 = xin2[u0 * 64 + lane];
        float2 a1 = xin2[u1 * 64 + lane];
        float2 a2 = xin2[u2 * 64 + lane];
        float2 a3 = xin2[u3 * 64 + lane];
        acc.x = fmaf(a0.x, s0, acc.x); acc.y = fmaf(a0.y, s0, acc.y);
        acc.x = fmaf(a1.x, s1, acc.x); acc.y = fmaf(a1.y, s1, acc.y);
        acc.x = fmaf(a2.x, s2, acc.x); acc.y = fmaf(a2.y, s2, acc.y);
        acc.x = fmaf(a3.x, s3, acc.x); acc.y = fmaf(a3.y, s3, acc.y);
    }
    for (; e < end; ++e) {
        int u0 = esrc[e];
        float s0 = ns[u0];
        float2 a0 = xin2[u0 * 64 + lane];
        acc.x = fmaf(a0.x, s0, acc.x); acc.y = fmaf(a0.y, s0, acc.y);
    }
    float scale = 0.9f * nd[v];
    float2 h0v = ((const float2*)h0)[v * 64 + lane];
    float2 r;
    r.x = fmaf(acc.x, scale, 0.1f * h0v.x);
    r.y = fmaf(acc.y, scale, 0.1f * h0v.y);
    ((float2*)xout)[v * 64 + lane] = r;
}

// ---------------------------------------------------------------------------
// S[p] = sum_n tanh(z_p[n] @ W_att + b_att) . q_att      (grid.y = path)
// ---------------------------------------------------------------------------
__global__ __launch_bounds__(256) void k_attn(
    const float* __restrict__ z0, const float* __restrict__ z1,
    const float* __restrict__ W, const float* __restrict__ b,
    const float* __restrict__ q, float* __restrict__ S)
{
    __shared__ float Wl[DD * DD];
    const float* z = blockIdx.y ? z1 : z0;
    int tid = threadIdx.x;
    for (int i = tid * 4; i < DD * DD; i += 256 * 4)
        *(float4*)&Wl[i] = *(const float4*)&W[i];
    int cg = tid & 31;
    int rr = tid >> 5;
    float4 bj = *(const float4*)&b[cg * 4];
    float4 qj = *(const float4*)&q[cg * 4];
    __syncthreads();
    const float4* z4 = (const float4*)z;
    float tacc = 0.f;
    for (int t = blockIdx.x * 16; t < NN; t += gridDim.x * 16) {
        int r0 = t + rr, r1 = r0 + 8;
        float4 acc0 = make_float4(0.f, 0.f, 0.f, 0.f);
        float4 acc1 = make_float4(0.f, 0.f, 0.f, 0.f);
        #pragma unroll 4
        for (int kk = 0; kk < 32; ++kk) {
            float4 a0 = z4[(size_t)r0 * 32 + kk];
            float4 a1 = z4[(size_t)r1 * 32 + kk];
            const float* wb = &Wl[(kk * 4) * DD + cg * 4];
            float4 w;
            w = *(const float4*)(wb);
            acc0.x = fmaf(a0.x, w.x, acc0.x); acc0.y = fmaf(a0.x, w.y, acc0.y);
            acc0.z = fmaf(a0.x, w.z, acc0.z); acc0.w = fmaf(a0.x, w.w, acc0.w);
            acc1.x = fmaf(a1.x, w.x, acc1.x); acc1.y = fmaf(a1.x, w.y, acc1.y);
            acc1.z = fmaf(a1.x, w.z, acc1.z); acc1.w = fmaf(a1.x, w.w, acc1.w);
            w = *(const float4*)(wb + DD);
            acc0.x = fmaf(a0.y, w.x, acc0.x); acc0.y = fmaf(a0.y, w.y, acc0.y);
            acc0.z = fmaf(a0.y, w.z, acc0.z); acc0.w = fmaf(a0.y, w.w, acc0.w);
            acc1.x = fmaf(a1.y, w.x, acc1.x); acc1.y = fmaf(a1.y, w.y, acc1.y);
            acc1.z = fmaf(a1.y, w.z, acc1.z); acc1.w = fmaf(a1.y, w.w, acc1.w);
            w = *(const float4*)(wb + 2 * DD);
            acc0.x = fmaf(a0.z, w.x, acc0.x); acc0.y = fmaf(a0.z, w.y, acc0.y);
            acc0.z = fmaf(a0.z, w.z, acc0.z); acc0.w = fmaf(a0.z, w.w, acc0.w);
            acc1.x = fmaf(a1.z, w.x, acc1.x); acc1.y = fmaf(a1.z, w.y, acc1.y);
            acc1.z = fmaf(a1.z, w.z, acc1.z); acc1.w = fmaf(a1.z, w.w, acc1.w);
            w = *(const float4*)(wb + 3 * DD);
            acc0.x = fmaf(a0.w, w.x, acc0.x); acc0.y = fmaf(a0.w, w.y, acc0.y);
            acc0.z = fmaf(a0.w, w.z, acc0.z); acc0.w = fmaf(a0.w, w.w, acc0.w);
            acc1.x = fmaf(a1.w, w.x, acc1.x); acc1.y = fmaf(a1.w, w.y, acc1.y);
            acc1.z = fmaf(a1.w, w.z, acc1.z); acc1.w = fmaf(a1.w, w.w, acc1.w);
        }
        tacc += tanhf(acc0.x + bj.x) * qj.x + tanhf(acc0.y + bj.y) * qj.y
              + tanhf(acc0.z + bj.z) * qj.z + tanhf(acc0.w + bj.w) * qj.w;
        tacc += tanhf(acc1.x + bj.x) * qj.x + tanhf(acc1.y + bj.y) * qj.y
              + tanhf(acc1.z + bj.z) * qj.z + tanhf(acc1.w + bj.w) * qj.w;
    }
    __syncthreads();
    for (int s = 32; s > 0; s >>= 1)
        tacc += __shfl_down(tacc, s);
    if ((tid & 63) == 0) Wl[tid >> 6] = tacc;
    __syncthreads();
    if (tid == 0)
        atomicAdd(&S[blockIdx.y], Wl[0] + Wl[1] + Wl[2] + Wl[3]);
}

// ---------------------------------------------------------------------------
// beta = softmax(S/N); out = beta0*z0 + beta1*z1
// ---------------------------------------------------------------------------
__global__ __launch_bounds__(256) void k_combine(
    const float* __restrict__ z0, const float* __restrict__ z1,
    const float* __restrict__ S, float* __restrict__ out)
{
    float w0 = S[0] * (1.0f / NN);
    float w1 = S[1] * (1.0f / NN);
    float m  = fmaxf(w0, w1);
    float e0 = expf(w0 - m), e1 = expf(w1 - m);
    float inv = 1.0f / (e0 + e1);
    float b0 = e0 * inv, b1 = e1 * inv;
    const float4* a = (const float4*)z0;
    const float4* c = (const float4*)z1;
    float4* o = (float4*)out;
    int i = blockIdx.x * 256 + threadIdx.x;
    int stride = gridDim.x * 256;
    for (; i < NN * DD / 4; i += stride) {
        float4 x = a[i], y = c[i];
        float4 r;
        r.x = b0 * x.x + b1 * y.x;
        r.y = b0 * x.y + b1 * y.y;
        r.z = b0 * x.z + b1 * y.z;
        r.w = b0 * x.w + b1 * y.w;
        o[i] = r;
    }
}

// ---------------------------------------------------------------------------
extern "C" void kernel_launch(void* const* d_in, const int* in_sizes, int n_in,
                              void* d_out, int out_size, void* d_ws, size_t ws_size,
                              hipStream_t stream)
{
    const float* h     = (const float*)d_in[0];
    const int*   src0  = (const int*)d_in[1];
    const int*   dst0  = (const int*)d_in[2];
    const int*   src1  = (const int*)d_in[3];
    const int*   dst1  = (const int*)d_in[4];
    const float* W_h   = (const float*)d_in[5];
    const float* b_h   = (const float*)d_in[6];
    const float* W_att = (const float*)d_in[7];
    const float* b_att = (const float*)d_in[8];
    const float* q_att = (const float*)d_in[9];
    float* out = (float*)d_out;

    char* ws = (char*)d_ws;
    size_t o = 0;
    auto alloc = [&](size_t bytes) -> void* {
        void* p = ws + o;
        o += (bytes + 255) & ~(size_t)255;
        return p;
    };
    const size_t ND = (size_t)NN * DD * sizeof(float);
    float* h1 = (float*)alloc(ND);
    // partial histograms (4 arrays x 32 chunks x NN); reused later as appnp temp T
    int*   partial = (int*)alloc((size_t)4 * NCHUNK * NN * sizeof(int));
    float* T  = (float*)partial;          // alias: partial dead after k_fill2
    float* z0 = (float*)alloc(ND);
    float* z1 = (float*)alloc(ND);
    float* ns0 = (float*)alloc(NN * 4);
    float* nd0 = (float*)alloc(NN * 4);
    float* ns1 = (float*)alloc(NN * 4);
    float* nd1 = (float*)alloc(NN * 4);
    int* cdeg0 = (int*)alloc(NN * 4);
    int* cdeg1 = (int*)alloc(NN * 4);
    int* off0 = (int*)alloc((NN + 1) * 4);
    int* off1 = (int*)alloc((NN + 1) * 4);
    int* es0  = (int*)alloc(EE * 4);
    int* es1  = (int*)alloc(EE * 4);
    int* bsum  = (int*)alloc(2 * NSB * 4);
    int* bbase = (int*)alloc(2 * NSB * 4);
    float* S   = (float*)alloc(256);
    hipMemsetAsync(S, 0, 256, stream);

    // 1. h1 = relu(h @ W_h + b_h)
    k_linear_relu<<<1024, 256, 0, stream>>>(h, W_h, b_h, h1);
    // 2. per-chunk histograms (atomic-free at global scope)
    k_hist<<<dim3(NCHUNK, NRANGE, 4), 256, 0, stream>>>(src0, dst0, src1, dst1, partial);
    // 3. reduce -> degrees/norms + in-place chunk prefixes for dst arrays
    k_reduce<<<dim3((NN + 255) / 256, 4), 256, 0, stream>>>(
        partial, ns0, nd0, ns1, nd1, cdeg0, cdeg1);
    // 4. CSR offsets: 3-pass scan
    k_scan1<<<dim3(NSB, 2), 256, 0, stream>>>(cdeg0, cdeg1, bsum);
    k_scan2<<<1, 64, 0, stream>>>(bsum, bbase, off0, off1);
    k_scan3<<<dim3(NSB, 2), 256, 0, stream>>>(cdeg0, cdeg1, bbase, off0, off1);
    // 5. atomic-free CSR fill
    k_fill2<<<dim3(NCHUNK, NRANGE, 2), 256, 0, stream>>>(
        src0, dst0, src1, dst1, partial, off0, off1, es0, es1);
    // 6. APPNP: 3 steps per path (T aliases partial — safe, partial now dead)
    const int ablocks = (NN + 3) / 4;
    k_appnp<<<ablocks, 256, 0, stream>>>(h1, z0, h1, off0, es0, ns0, nd0);
    k_appnp<<<ablocks, 256, 0, stream>>>(z0, T,  h1, off0, es0, ns0, nd0);
    k_appnp<<<ablocks, 256, 0, stream>>>(T,  z0, h1, off0, es0, ns0, nd0);
    k_appnp<<<ablocks, 256, 0, stream>>>(h1, z1, h1, off1, es1, ns1, nd1);
    k_appnp<<<ablocks, 256, 0, stream>>>(z1, T,  h1, off1, es1, ns1, nd1);
    k_appnp<<<ablocks, 256, 0, stream>>>(T,  z1, h1, off1, es1, ns1, nd1);
    // 7. semantic attention scores
    k_attn<<<dim3(1024, 2), 256, 0, stream>>>(z0, z1, W_att, b_att, q_att, S);
    // 8. softmax + weighted combine
    k_combine<<<2048, 256, 0, stream>>>(z0, z1, S, out);
    (void)in_sizes; (void)n_in; (void)out_size; (void)ws_size;
}

// Round 5
// 652.770 us; speedup vs baseline: 2.0706x; 1.1022x over previous
//
#include <hip/hip_runtime.h>

#define NN 50000
#define EE 800000
#define DD 128
#define NCHUNK 32
#define CH (EE / NCHUNK)        // 25000
#define NRANGE 4
#define RSIZE (NN / NRANGE)     // 12500
#define NSB 49                  // ceil(NN/1024)
#define NSTRIP (NN / 16)        // 3125 (exact)

typedef __attribute__((ext_vector_type(8))) short bf16x8;
typedef __attribute__((ext_vector_type(4))) float f32x4;

// f32 -> bf16 bits, round-to-nearest-even (no NaN handling needed here)
__device__ __forceinline__ short f2b(float x) {
    unsigned u = __float_as_uint(x);
    unsigned r = (u + 0x7fffu + ((u >> 16) & 1u)) >> 16;
    return (short)r;
}

// ---------------------------------------------------------------------------
// prep: WT[n][k] = bf16(W[k][n]) for W_h (block 0) and W_att (block 1)
// ---------------------------------------------------------------------------
__global__ __launch_bounds__(256) void k_prep(
    const float* __restrict__ Wh, const float* __restrict__ Wa,
    short* __restrict__ WTh, short* __restrict__ WTa)
{
    const float* W = blockIdx.x ? Wa : Wh;
    short* WT      = blockIdx.x ? WTa : WTh;
    for (int i = threadIdx.x; i < DD * DD; i += 256) {
        int n = i >> 7, k = i & 127;
        WT[i] = f2b(W[k * DD + n]);
    }
}

// ---------------------------------------------------------------------------
// h1 = relu(h @ W + b) via bf16 MFMA. 4 waves/block, wave = 16-row strip.
// WT (bf16, [n][k]) staged in LDS with XOR swizzle; A converted f32->bf16
// in-register.
// ---------------------------------------------------------------------------
__global__ __launch_bounds__(256) void k_linear_mfma(
    const float* __restrict__ h, const short* __restrict__ WT,
    const float* __restrict__ b, float* __restrict__ out)
{
    __shared__ char ldsb[32768];
    int tid = threadIdx.x;
    // stage WT -> LDS (swizzled): chunk i = 16B; row n = i>>4, k8 = i&15
    for (int i = tid; i < DD * DD / 8; i += 256) {
        int n = i >> 4, k8 = i & 15;
        int4 v = ((const int4*)WT)[i];
        *(int4*)(ldsb + n * 256 + ((k8 * 16) ^ ((n & 7) << 4))) = v;
    }
    __syncthreads();
    int wid = tid >> 6, l = tid & 63;
    int s = blockIdx.x * 4 + wid;
    if (s >= NSTRIP) return;
    int lr = l & 15, lg = l >> 4;
    int row0 = s * 16;
    const float4* ap = (const float4*)(h + (size_t)(row0 + lr) * DD + lg * 8);
    bf16x8 a[4];
    #pragma unroll 4
    for (int t = 0; t < 4; ++t) {
        float4 f0 = ap[8 * t], f1 = ap[8 * t + 1];
        a[t][0] = f2b(f0.x); a[t][1] = f2b(f0.y); a[t][2] = f2b(f0.z); a[t][3] = f2b(f0.w);
        a[t][4] = f2b(f1.x); a[t][5] = f2b(f1.y); a[t][6] = f2b(f1.z); a[t][7] = f2b(f1.w);
    }
    f32x4 acc[8];
    #pragma unroll 8
    for (int c = 0; c < 8; ++c) acc[c] = (f32x4){0.f, 0.f, 0.f, 0.f};
    #pragma unroll 8
    for (int c = 0; c < 8; ++c) {
        int n = c * 16 + lr;
        #pragma unroll 4
        for (int t = 0; t < 4; ++t) {
            bf16x8 bv = *(bf16x8*)(ldsb + n * 256 + ((t * 64 + lg * 16) ^ ((n & 7) << 4)));
            acc[c] = __builtin_amdgcn_mfma_f32_16x16x32_bf16(a[t], bv, acc[c], 0, 0, 0);
        }
    }
    #pragma unroll 8
    for (int c = 0; c < 8; ++c) {
        int col = c * 16 + lr;
        float bc = b[col];
        #pragma unroll 4
        for (int r = 0; r < 4; ++r) {
            float v = acc[c][r] + bc;
            out[(size_t)(row0 + lg * 4 + r) * DD + col] = fmaxf(v, 0.f);
        }
    }
}

// ---------------------------------------------------------------------------
// S[p] = sum_n tanh(z_p[n] @ W_att + b_att) . q_att  via bf16 MFMA
// grid = (782, 2 paths); one atomicAdd per block
// ---------------------------------------------------------------------------
__global__ __launch_bounds__(256) void k_attn_mfma(
    const float* __restrict__ z0, const float* __restrict__ z1,
    const short* __restrict__ WT, const float* __restrict__ b,
    const float* __restrict__ q, float* __restrict__ S)
{
    __shared__ char ldsb[32768];
    __shared__ float red[4];
    const float* z = blockIdx.y ? z1 : z0;
    int tid = threadIdx.x;
    for (int i = tid; i < DD * DD / 8; i += 256) {
        int n = i >> 4, k8 = i & 15;
        int4 v = ((const int4*)WT)[i];
        *(int4*)(ldsb + n * 256 + ((k8 * 16) ^ ((n & 7) << 4))) = v;
    }
    __syncthreads();
    int wid = tid >> 6, l = tid & 63;
    int s = blockIdx.x * 4 + wid;
    float part = 0.f;
    if (s < NSTRIP) {
        int lr = l & 15, lg = l >> 4;
        int row0 = s * 16;
        const float4* ap = (const float4*)(z + (size_t)(row0 + lr) * DD + lg * 8);
        bf16x8 a[4];
        #pragma unroll 4
        for (int t = 0; t < 4; ++t) {
            float4 f0 = ap[8 * t], f1 = ap[8 * t + 1];
            a[t][0] = f2b(f0.x); a[t][1] = f2b(f0.y); a[t][2] = f2b(f0.z); a[t][3] = f2b(f0.w);
            a[t][4] = f2b(f1.x); a[t][5] = f2b(f1.y); a[t][6] = f2b(f1.z); a[t][7] = f2b(f1.w);
        }
        f32x4 acc[8];
        #pragma unroll 8
        for (int c = 0; c < 8; ++c) acc[c] = (f32x4){0.f, 0.f, 0.f, 0.f};
        #pragma unroll 8
        for (int c = 0; c < 8; ++c) {
            int n = c * 16 + lr;
            #pragma unroll 4
            for (int t = 0; t < 4; ++t) {
                bf16x8 bv = *(bf16x8*)(ldsb + n * 256 + ((t * 64 + lg * 16) ^ ((n & 7) << 4)));
                acc[c] = __builtin_amdgcn_mfma_f32_16x16x32_bf16(a[t], bv, acc[c], 0, 0, 0);
            }
        }
        #pragma unroll 8
        for (int c = 0; c < 8; ++c) {
            int col = c * 16 + lr;
            float bc = b[col], qc = q[col];
            #pragma unroll 4
            for (int r = 0; r < 4; ++r)
                part += tanhf(acc[c][r] + bc) * qc;
        }
    }
    for (int sh = 32; sh > 0; sh >>= 1)
        part += __shfl_down(part, sh);
    if (l == 0) red[wid] = part;
    __syncthreads();
    if (tid == 0)
        atomicAdd(&S[blockIdx.y], red[0] + red[1] + red[2] + red[3]);
}

// ---------------------------------------------------------------------------
// per-chunk partial histograms, LDS-atomic only, plain stores out.
// ---------------------------------------------------------------------------
__global__ __launch_bounds__(256) void k_hist(
    const int* __restrict__ s0, const int* __restrict__ d0,
    const int* __restrict__ s1, const int* __restrict__ d1,
    int* __restrict__ partial)
{
    __shared__ int hist[RSIZE];          // 50 KB
    int c = blockIdx.x, rg = blockIdx.y, a = blockIdx.z;
    const int* idx = (a == 0) ? s0 : (a == 1) ? d0 : (a == 2) ? s1 : d1;
    int lo = rg * RSIZE;
    for (int i = threadIdx.x; i < RSIZE; i += 256) hist[i] = 0;
    __syncthreads();
    int beg = c * CH, end = beg + CH;
    for (int i = beg + threadIdx.x; i < end; i += 256) {
        int v = idx[i] - lo;
        if ((unsigned)v < (unsigned)RSIZE) atomicAdd(&hist[v], 1);
    }
    __syncthreads();
    int* dst = partial + ((size_t)a * NCHUNK + c) * NN + lo;
    for (int i = threadIdx.x; i < RSIZE; i += 256) dst[i] = hist[i];
}

// ---------------------------------------------------------------------------
// reduce partials -> degree + norm; dst arrays get in-place chunk prefixes
// ---------------------------------------------------------------------------
__global__ __launch_bounds__(256) void k_reduce(
    int* __restrict__ partial,
    float* ns0, float* nd0, float* ns1, float* nd1,
    int* cdeg0, int* cdeg1)
{
    int n = blockIdx.x * 256 + threadIdx.x;
    int a = blockIdx.y;
    if (n >= NN) return;
    int run = 0;
    bool isdst = a & 1;
    for (int c = 0; c < NCHUNK; ++c) {
        size_t ix = ((size_t)a * NCHUNK + c) * NN + n;
        int t = partial[ix];
        if (isdst) partial[ix] = run;
        run += t;
    }
    float nv = rsqrtf((float)(run > 1 ? run : 1));
    if (a == 0) ns0[n] = nv;
    else if (a == 1) { nd0[n] = nv; cdeg0[n] = run; }
    else if (a == 2) ns1[n] = nv;
    else { nd1[n] = nv; cdeg1[n] = run; }
}

// ---------------------------------------------------------------------------
__global__ __launch_bounds__(256) void k_scan1(
    const int* __restrict__ cdeg0, const int* __restrict__ cdeg1,
    int* __restrict__ bsum)
{
    const int* dg = blockIdx.y ? cdeg1 : cdeg0;
    __shared__ int ws_[4];
    int tid = threadIdx.x;
    int n0 = blockIdx.x * 1024 + tid * 4;
    int s = 0;
    #pragma unroll
    for (int k = 0; k < 4; ++k) {
        int n = n0 + k;
        if (n < NN) s += dg[n];
    }
    for (int sh = 32; sh > 0; sh >>= 1) s += __shfl_down(s, sh);
    if ((tid & 63) == 0) ws_[tid >> 6] = s;
    __syncthreads();
    if (tid == 0)
        bsum[blockIdx.y * NSB + blockIdx.x] = ws_[0] + ws_[1] + ws_[2] + ws_[3];
}

__global__ __launch_bounds__(64) void k_scan2(
    const int* __restrict__ bsum, int* __restrict__ bbase,
    int* off0, int* off1)
{
    int p = threadIdx.x;
    if (p < 2) {
        int run = 0;
        for (int b = 0; b < NSB; ++b) {
            bbase[p * NSB + b] = run;
            run += bsum[p * NSB + b];
        }
        (p ? off1 : off0)[NN] = run;
    }
}

__global__ __launch_bounds__(256) void k_scan3(
    const int* __restrict__ cdeg0, const int* __restrict__ cdeg1,
    const int* __restrict__ bbase, int* off0, int* off1)
{
    const int* dg = blockIdx.y ? cdeg1 : cdeg0;
    int* off      = blockIdx.y ? off1  : off0;
    __shared__ int ts[256];
    int tid = threadIdx.x;
    int n0 = blockIdx.x * 1024 + tid * 4;
    int d0 = 0, d1 = 0, d2 = 0, d3 = 0;
    if (n0 + 0 < NN) d0 = dg[n0 + 0];
    if (n0 + 1 < NN) d1 = dg[n0 + 1];
    if (n0 + 2 < NN) d2 = dg[n0 + 2];
    if (n0 + 3 < NN) d3 = dg[n0 + 3];
    int tot = d0 + d1 + d2 + d3;
    ts[tid] = tot;
    __syncthreads();
    for (int s = 1; s < 256; s <<= 1) {
        int u = (tid >= s) ? ts[tid - s] : 0;
        __syncthreads();
        ts[tid] += u;
        __syncthreads();
    }
    int base = bbase[blockIdx.y * NSB + blockIdx.x] + ts[tid] - tot;
    if (n0 + 0 < NN) off[n0 + 0] = base;
    if (n0 + 1 < NN) off[n0 + 1] = base + d0;
    if (n0 + 2 < NN) off[n0 + 2] = base + d0 + d1;
    if (n0 + 3 < NN) off[n0 + 3] = base + d0 + d1 + d2;
}

// ---------------------------------------------------------------------------
// atomic-free CSR fill: slot = off[d] + chunk_prefix[c][d] + lds_rank
// ---------------------------------------------------------------------------
__global__ __launch_bounds__(256) void k_fill2(
    const int* __restrict__ src0, const int* __restrict__ dst0,
    const int* __restrict__ src1, const int* __restrict__ dst1,
    const int* __restrict__ partial,
    const int* __restrict__ off0, const int* __restrict__ off1,
    int* __restrict__ es0, int* __restrict__ es1)
{
    __shared__ int cur[RSIZE];           // 50 KB
    int c = blockIdx.x, rg = blockIdx.y, p = blockIdx.z;
    const int* src = p ? src1 : src0;
    const int* dst = p ? dst1 : dst0;
    const int* off = p ? off1 : off0;
    int* es        = p ? es1  : es0;
    const int* pfx = partial + ((size_t)(1 + 2 * p) * NCHUNK + c) * NN;
    int lo = rg * RSIZE;
    for (int i = threadIdx.x; i < RSIZE; i += 256) cur[i] = 0;
    __syncthreads();
    int beg = c * CH, end = beg + CH;
    for (int i = beg + threadIdx.x; i < end; i += 256) {
        int d = dst[i];
        int s = src[i];
        int v = d - lo;
        if ((unsigned)v < (unsigned)RSIZE) {
            int r = atomicAdd(&cur[v], 1);
            es[off[d] + pfx[d] + r] = s;
        }
    }
}

// ---------------------------------------------------------------------------
// one APPNP step: xout[v] = 0.9*nd[v]*sum_{e:dst=v} ns[u]*xin[u] + 0.1*h0[v]
// ---------------------------------------------------------------------------
__global__ __launch_bounds__(256) void k_appnp(
    const float* __restrict__ xin, float* __restrict__ xout,
    const float* __restrict__ h0,
    const int* __restrict__ off, const int* __restrict__ esrc,
    const float* __restrict__ ns, const float* __restrict__ nd)
{
    int wid  = (blockIdx.x * 256 + threadIdx.x) >> 6;
    int lane = threadIdx.x & 63;
    if (wid >= NN) return;
    int v = wid;
    int beg = off[v], end = off[v + 1];
    const float2* xin2 = (const float2*)xin;
    float2 acc = make_float2(0.f, 0.f);
    int e = beg;
    for (; e + 3 < end; e += 4) {
        int u0 = esrc[e], u1 = esrc[e + 1], u2 = esrc[e + 2], u3 = esrc[e + 3];
        float s0 = ns[u0], s1 = ns[u1], s2 = ns[u2], s3 = ns[u3];
        float2 a0 = xin2[u0 * 64 + lane];
        float2 a1 = xin2[u1 * 64 + lane];
        float2 a2 = xin2[u2 * 64 + lane];
        float2 a3 = xin2[u3 * 64 + lane];
        acc.x = fmaf(a0.x, s0, acc.x); acc.y = fmaf(a0.y, s0, acc.y);
        acc.x = fmaf(a1.x, s1, acc.x); acc.y = fmaf(a1.y, s1, acc.y);
        acc.x = fmaf(a2.x, s2, acc.x); acc.y = fmaf(a2.y, s2, acc.y);
        acc.x = fmaf(a3.x, s3, acc.x); acc.y = fmaf(a3.y, s3, acc.y);
    }
    for (; e < end; ++e) {
        int u0 = esrc[e];
        float s0 = ns[u0];
        float2 a0 = xin2[u0 * 64 + lane];
        acc.x = fmaf(a0.x, s0, acc.x); acc.y = fmaf(a0.y, s0, acc.y);
    }
    float scale = 0.9f * nd[v];
    float2 h0v = ((const float2*)h0)[v * 64 + lane];
    float2 r;
    r.x = fmaf(acc.x, scale, 0.1f * h0v.x);
    r.y = fmaf(acc.y, scale, 0.1f * h0v.y);
    ((float2*)xout)[v * 64 + lane] = r;
}

// ---------------------------------------------------------------------------
// beta = softmax(S/N); out = beta0*z0 + beta1*z1
// ---------------------------------------------------------------------------
__global__ __launch_bounds__(256) void k_combine(
    const float* __restrict__ z0, const float* __restrict__ z1,
    const float* __restrict__ S, float* __restrict__ out)
{
    float w0 = S[0] * (1.0f / NN);
    float w1 = S[1] * (1.0f / NN);
    float m  = fmaxf(w0, w1);
    float e0 = expf(w0 - m), e1 = expf(w1 - m);
    float inv = 1.0f / (e0 + e1);
    float b0 = e0 * inv, b1 = e1 * inv;
    const float4* a = (const float4*)z0;
    const float4* c = (const float4*)z1;
    float4* o = (float4*)out;
    int i = blockIdx.x * 256 + threadIdx.x;
    int stride = gridDim.x * 256;
    for (; i < NN * DD / 4; i += stride) {
        float4 x = a[i], y = c[i];
        float4 r;
        r.x = b0 * x.x + b1 * y.x;
        r.y = b0 * x.y + b1 * y.y;
        r.z = b0 * x.z + b1 * y.z;
        r.w = b0 * x.w + b1 * y.w;
        o[i] = r;
    }
}

// ---------------------------------------------------------------------------
extern "C" void kernel_launch(void* const* d_in, const int* in_sizes, int n_in,
                              void* d_out, int out_size, void* d_ws, size_t ws_size,
                              hipStream_t stream)
{
    const float* h     = (const float*)d_in[0];
    const int*   src0  = (const int*)d_in[1];
    const int*   dst0  = (const int*)d_in[2];
    const int*   src1  = (const int*)d_in[3];
    const int*   dst1  = (const int*)d_in[4];
    const float* W_h   = (const float*)d_in[5];
    const float* b_h   = (const float*)d_in[6];
    const float* W_att = (const float*)d_in[7];
    const float* b_att = (const float*)d_in[8];
    const float* q_att = (const float*)d_in[9];
    float* out = (float*)d_out;

    char* ws = (char*)d_ws;
    size_t o = 0;
    auto alloc = [&](size_t bytes) -> void* {
        void* p = ws + o;
        o += (bytes + 255) & ~(size_t)255;
        return p;
    };
    const size_t ND = (size_t)NN * DD * sizeof(float);
    float* h1 = (float*)alloc(ND);
    int*   partial = (int*)alloc((size_t)4 * NCHUNK * NN * sizeof(int));
    float* T  = (float*)partial;          // alias: partial dead after k_fill2
    float* z0 = (float*)alloc(ND);
    float* z1 = (float*)alloc(ND);
    float* ns0 = (float*)alloc(NN * 4);
    float* nd0 = (float*)alloc(NN * 4);
    float* ns1 = (float*)alloc(NN * 4);
    float* nd1 = (float*)alloc(NN * 4);
    int* cdeg0 = (int*)alloc(NN * 4);
    int* cdeg1 = (int*)alloc(NN * 4);
    int* off0 = (int*)alloc((NN + 1) * 4);
    int* off1 = (int*)alloc((NN + 1) * 4);
    int* es0  = (int*)alloc(EE * 4);
    int* es1  = (int*)alloc(EE * 4);
    int* bsum  = (int*)alloc(2 * NSB * 4);
    int* bbase = (int*)alloc(2 * NSB * 4);
    short* WTh = (short*)alloc(DD * DD * 2);
    short* WTa = (short*)alloc(DD * DD * 2);
    float* S   = (float*)alloc(256);
    hipMemsetAsync(S, 0, 256, stream);

    // 0. transpose+convert weights to bf16
    k_prep<<<2, 256, 0, stream>>>(W_h, W_att, WTh, WTa);
    // 1. h1 = relu(h @ W_h + b_h)  (MFMA)
    k_linear_mfma<<<(NSTRIP + 3) / 4, 256, 0, stream>>>(h, WTh, b_h, h1);
    // 2. per-chunk histograms
    k_hist<<<dim3(NCHUNK, NRANGE, 4), 256, 0, stream>>>(src0, dst0, src1, dst1, partial);
    // 3. reduce -> degrees/norms + chunk prefixes
    k_reduce<<<dim3((NN + 255) / 256, 4), 256, 0, stream>>>(
        partial, ns0, nd0, ns1, nd1, cdeg0, cdeg1);
    // 4. CSR offsets: 3-pass scan
    k_scan1<<<dim3(NSB, 2), 256, 0, stream>>>(cdeg0, cdeg1, bsum);
    k_scan2<<<1, 64, 0, stream>>>(bsum, bbase, off0, off1);
    k_scan3<<<dim3(NSB, 2), 256, 0, stream>>>(cdeg0, cdeg1, bbase, off0, off1);
    // 5. atomic-free CSR fill
    k_fill2<<<dim3(NCHUNK, NRANGE, 2), 256, 0, stream>>>(
        src0, dst0, src1, dst1, partial, off0, off1, es0, es1);
    // 6. APPNP: 3 steps per path
    const int ablocks = (NN + 3) / 4;
    k_appnp<<<ablocks, 256, 0, stream>>>(h1, z0, h1, off0, es0, ns0, nd0);
    k_appnp<<<ablocks, 256, 0, stream>>>(z0, T,  h1, off0, es0, ns0, nd0);
    k_appnp<<<ablocks, 256, 0, stream>>>(T,  z0, h1, off0, es0, ns0, nd0);
    k_appnp<<<ablocks, 256, 0, stream>>>(h1, z1, h1, off1, es1, ns1, nd1);
    k_appnp<<<ablocks, 256, 0, stream>>>(z1, T,  h1, off1, es1, ns1, nd1);
    k_appnp<<<ablocks, 256, 0, stream>>>(T,  z1, h1, off1, es1, ns1, nd1);
    // 7. semantic attention scores (MFMA)
    k_attn_mfma<<<dim3((NSTRIP + 3) / 4, 2), 256, 0, stream>>>(
        z0, z1, WTa, b_att, q_att, S);
    // 8. softmax + weighted combine
    k_combine<<<2048, 256, 0, stream>>>(z0, z1, S, out);
    (void)in_sizes; (void)n_in; (void)out_size; (void)ws_size;
}

// Round 6
// 501.551 us; speedup vs baseline: 2.6949x; 1.3015x over previous
//
#include <hip/hip_runtime.h>

#define NN 50000
#define EE 800000
#define DD 128
#define NCHUNK 32
#define CH (EE / NCHUNK)        // 25000
#define NRANGE 4
#define RSIZE (NN / NRANGE)     // 12500
#define NSB 49                  // ceil(NN/1024)
#define NSTRIP (NN / 16)        // 3125 (exact)

typedef __attribute__((ext_vector_type(8))) short bf16x8;
typedef __attribute__((ext_vector_type(4))) float f32x4;

// f32 -> bf16 bits, round-to-nearest-even
__device__ __forceinline__ unsigned short f2b(float x) {
    unsigned u = __float_as_uint(x);
    unsigned r = (u + 0x7fffu + ((u >> 16) & 1u)) >> 16;
    return (unsigned short)r;
}
__device__ __forceinline__ float b2f_lo(unsigned w) {
    return __uint_as_float((w & 0xffffu) << 16);
}
__device__ __forceinline__ float b2f_hi(unsigned w) {
    return __uint_as_float(w & 0xffff0000u);
}

// ---------------------------------------------------------------------------
// prep: WT[n][k] = bf16(W[k][n]) for W_h (block 0) and W_att (block 1)
// ---------------------------------------------------------------------------
__global__ __launch_bounds__(256) void k_prep(
    const float* __restrict__ Wh, const float* __restrict__ Wa,
    short* __restrict__ WTh, short* __restrict__ WTa)
{
    const float* W = blockIdx.x ? Wa : Wh;
    short* WT      = blockIdx.x ? WTa : WTh;
    for (int i = threadIdx.x; i < DD * DD; i += 256) {
        int n = i >> 7, k = i & 127;
        WT[i] = (short)f2b(W[k * DD + n]);
    }
}

// ---------------------------------------------------------------------------
// h1 = relu(h @ W + b) via bf16 MFMA -> bf16 output (gather payload format)
// ---------------------------------------------------------------------------
__global__ __launch_bounds__(256) void k_linear_mfma(
    const float* __restrict__ h, const short* __restrict__ WT,
    const float* __restrict__ b, unsigned short* __restrict__ out)
{
    __shared__ char ldsb[32768];
    int tid = threadIdx.x;
    for (int i = tid; i < DD * DD / 8; i += 256) {
        int n = i >> 4, k8 = i & 15;
        int4 v = ((const int4*)WT)[i];
        *(int4*)(ldsb + n * 256 + ((k8 * 16) ^ ((n & 7) << 4))) = v;
    }
    __syncthreads();
    int wid = tid >> 6, l = tid & 63;
    int s = blockIdx.x * 4 + wid;
    if (s >= NSTRIP) return;
    int lr = l & 15, lg = l >> 4;
    int row0 = s * 16;
    const float4* ap = (const float4*)(h + (size_t)(row0 + lr) * DD + lg * 8);
    bf16x8 a[4];
    #pragma unroll 4
    for (int t = 0; t < 4; ++t) {
        float4 f0 = ap[8 * t], f1 = ap[8 * t + 1];
        a[t][0] = f2b(f0.x); a[t][1] = f2b(f0.y); a[t][2] = f2b(f0.z); a[t][3] = f2b(f0.w);
        a[t][4] = f2b(f1.x); a[t][5] = f2b(f1.y); a[t][6] = f2b(f1.z); a[t][7] = f2b(f1.w);
    }
    f32x4 acc[8];
    #pragma unroll 8
    for (int c = 0; c < 8; ++c) acc[c] = (f32x4){0.f, 0.f, 0.f, 0.f};
    #pragma unroll 8
    for (int c = 0; c < 8; ++c) {
        int n = c * 16 + lr;
        #pragma unroll 4
        for (int t = 0; t < 4; ++t) {
            bf16x8 bv = *(bf16x8*)(ldsb + n * 256 + ((t * 64 + lg * 16) ^ ((n & 7) << 4)));
            acc[c] = __builtin_amdgcn_mfma_f32_16x16x32_bf16(a[t], bv, acc[c], 0, 0, 0);
        }
    }
    #pragma unroll 8
    for (int c = 0; c < 8; ++c) {
        int col = c * 16 + lr;
        float bc = b[col];
        #pragma unroll 4
        for (int r = 0; r < 4; ++r) {
            float v = acc[c][r] + bc;
            out[(size_t)(row0 + lg * 4 + r) * DD + col] = f2b(fmaxf(v, 0.f));
        }
    }
}

// ---------------------------------------------------------------------------
// S[p] = sum_n tanh(z_p[n] @ W_att + b_att) . q_att  via bf16 MFMA (z f32)
// ---------------------------------------------------------------------------
__global__ __launch_bounds__(256) void k_attn_mfma(
    const float* __restrict__ z0, const float* __restrict__ z1,
    const short* __restrict__ WT, const float* __restrict__ b,
    const float* __restrict__ q, float* __restrict__ S)
{
    __shared__ char ldsb[32768];
    __shared__ float red[4];
    const float* z = blockIdx.y ? z1 : z0;
    int tid = threadIdx.x;
    for (int i = tid; i < DD * DD / 8; i += 256) {
        int n = i >> 4, k8 = i & 15;
        int4 v = ((const int4*)WT)[i];
        *(int4*)(ldsb + n * 256 + ((k8 * 16) ^ ((n & 7) << 4))) = v;
    }
    __syncthreads();
    int wid = tid >> 6, l = tid & 63;
    int s = blockIdx.x * 4 + wid;
    float part = 0.f;
    if (s < NSTRIP) {
        int lr = l & 15, lg = l >> 4;
        int row0 = s * 16;
        const float4* ap = (const float4*)(z + (size_t)(row0 + lr) * DD + lg * 8);
        bf16x8 a[4];
        #pragma unroll 4
        for (int t = 0; t < 4; ++t) {
            float4 f0 = ap[8 * t], f1 = ap[8 * t + 1];
            a[t][0] = f2b(f0.x); a[t][1] = f2b(f0.y); a[t][2] = f2b(f0.z); a[t][3] = f2b(f0.w);
            a[t][4] = f2b(f1.x); a[t][5] = f2b(f1.y); a[t][6] = f2b(f1.z); a[t][7] = f2b(f1.w);
        }
        f32x4 acc[8];
        #pragma unroll 8
        for (int c = 0; c < 8; ++c) acc[c] = (f32x4){0.f, 0.f, 0.f, 0.f};
        #pragma unroll 8
        for (int c = 0; c < 8; ++c) {
            int n = c * 16 + lr;
            #pragma unroll 4
            for (int t = 0; t < 4; ++t) {
                bf16x8 bv = *(bf16x8*)(ldsb + n * 256 + ((t * 64 + lg * 16) ^ ((n & 7) << 4)));
                acc[c] = __builtin_amdgcn_mfma_f32_16x16x32_bf16(a[t], bv, acc[c], 0, 0, 0);
            }
        }
        #pragma unroll 8
        for (int c = 0; c < 8; ++c) {
            int col = c * 16 + lr;
            float bc = b[col], qc = q[col];
            #pragma unroll 4
            for (int r = 0; r < 4; ++r)
                part += tanhf(acc[c][r] + bc) * qc;
        }
    }
    for (int sh = 32; sh > 0; sh >>= 1)
        part += __shfl_down(part, sh);
    if (l == 0) red[wid] = part;
    __syncthreads();
    if (tid == 0)
        atomicAdd(&S[blockIdx.y], red[0] + red[1] + red[2] + red[3]);
}

// ---------------------------------------------------------------------------
// per-chunk partial histograms, LDS-atomic only, plain stores out.
// ---------------------------------------------------------------------------
__global__ __launch_bounds__(256) void k_hist(
    const int* __restrict__ s0, const int* __restrict__ d0,
    const int* __restrict__ s1, const int* __restrict__ d1,
    int* __restrict__ partial)
{
    __shared__ int hist[RSIZE];          // 50 KB
    int c = blockIdx.x, rg = blockIdx.y, a = blockIdx.z;
    const int* idx = (a == 0) ? s0 : (a == 1) ? d0 : (a == 2) ? s1 : d1;
    int lo = rg * RSIZE;
    for (int i = threadIdx.x; i < RSIZE; i += 256) hist[i] = 0;
    __syncthreads();
    int beg = c * CH, end = beg + CH;
    for (int i = beg + threadIdx.x; i < end; i += 256) {
        int v = idx[i] - lo;
        if ((unsigned)v < (unsigned)RSIZE) atomicAdd(&hist[v], 1);
    }
    __syncthreads();
    int* dst = partial + ((size_t)a * NCHUNK + c) * NN + lo;
    for (int i = threadIdx.x; i < RSIZE; i += 256) dst[i] = hist[i];
}

// ---------------------------------------------------------------------------
// reduce partials -> degree + norm; dst arrays get in-place chunk prefixes
// ---------------------------------------------------------------------------
__global__ __launch_bounds__(256) void k_reduce(
    int* __restrict__ partial,
    float* ns0, float* nd0, float* ns1, float* nd1,
    int* cdeg0, int* cdeg1)
{
    int n = blockIdx.x * 256 + threadIdx.x;
    int a = blockIdx.y;
    if (n >= NN) return;
    int run = 0;
    bool isdst = a & 1;
    for (int c = 0; c < NCHUNK; ++c) {
        size_t ix = ((size_t)a * NCHUNK + c) * NN + n;
        int t = partial[ix];
        if (isdst) partial[ix] = run;
        run += t;
    }
    float nv = rsqrtf((float)(run > 1 ? run : 1));
    if (a == 0) ns0[n] = nv;
    else if (a == 1) { nd0[n] = nv; cdeg0[n] = run; }
    else if (a == 2) ns1[n] = nv;
    else { nd1[n] = nv; cdeg1[n] = run; }
}

// ---------------------------------------------------------------------------
__global__ __launch_bounds__(256) void k_scan1(
    const int* __restrict__ cdeg0, const int* __restrict__ cdeg1,
    int* __restrict__ bsum)
{
    const int* dg = blockIdx.y ? cdeg1 : cdeg0;
    __shared__ int ws_[4];
    int tid = threadIdx.x;
    int n0 = blockIdx.x * 1024 + tid * 4;
    int s = 0;
    #pragma unroll
    for (int k = 0; k < 4; ++k) {
        int n = n0 + k;
        if (n < NN) s += dg[n];
    }
    for (int sh = 32; sh > 0; sh >>= 1) s += __shfl_down(s, sh);
    if ((tid & 63) == 0) ws_[tid >> 6] = s;
    __syncthreads();
    if (tid == 0)
        bsum[blockIdx.y * NSB + blockIdx.x] = ws_[0] + ws_[1] + ws_[2] + ws_[3];
}

__global__ __launch_bounds__(64) void k_scan2(
    const int* __restrict__ bsum, int* __restrict__ bbase,
    int* off0, int* off1)
{
    int p = threadIdx.x;
    if (p < 2) {
        int run = 0;
        for (int b = 0; b < NSB; ++b) {
            bbase[p * NSB + b] = run;
            run += bsum[p * NSB + b];
        }
        (p ? off1 : off0)[NN] = run;
    }
}

__global__ __launch_bounds__(256) void k_scan3(
    const int* __restrict__ cdeg0, const int* __restrict__ cdeg1,
    const int* __restrict__ bbase, int* off0, int* off1)
{
    const int* dg = blockIdx.y ? cdeg1 : cdeg0;
    int* off      = blockIdx.y ? off1  : off0;
    __shared__ int ts[256];
    int tid = threadIdx.x;
    int n0 = blockIdx.x * 1024 + tid * 4;
    int d0 = 0, d1 = 0, d2 = 0, d3 = 0;
    if (n0 + 0 < NN) d0 = dg[n0 + 0];
    if (n0 + 1 < NN) d1 = dg[n0 + 1];
    if (n0 + 2 < NN) d2 = dg[n0 + 2];
    if (n0 + 3 < NN) d3 = dg[n0 + 3];
    int tot = d0 + d1 + d2 + d3;
    ts[tid] = tot;
    __syncthreads();
    for (int s = 1; s < 256; s <<= 1) {
        int u = (tid >= s) ? ts[tid - s] : 0;
        __syncthreads();
        ts[tid] += u;
        __syncthreads();
    }
    int base = bbase[blockIdx.y * NSB + blockIdx.x] + ts[tid] - tot;
    if (n0 + 0 < NN) off[n0 + 0] = base;
    if (n0 + 1 < NN) off[n0 + 1] = base + d0;
    if (n0 + 2 < NN) off[n0 + 2] = base + d0 + d1;
    if (n0 + 3 < NN) off[n0 + 3] = base + d0 + d1 + d2;
}

// ---------------------------------------------------------------------------
// atomic-free CSR fill: slot = off[d] + chunk_prefix[c][d] + lds_rank
// ---------------------------------------------------------------------------
__global__ __launch_bounds__(256) void k_fill2(
    const int* __restrict__ src0, const int* __restrict__ dst0,
    const int* __restrict__ src1, const int* __restrict__ dst1,
    const int* __restrict__ partial,
    const int* __restrict__ off0, const int* __restrict__ off1,
    int* __restrict__ es0, int* __restrict__ es1)
{
    __shared__ int cur[RSIZE];           // 50 KB
    int c = blockIdx.x, rg = blockIdx.y, p = blockIdx.z;
    const int* src = p ? src1 : src0;
    const int* dst = p ? dst1 : dst0;
    const int* off = p ? off1 : off0;
    int* es        = p ? es1  : es0;
    const int* pfx = partial + ((size_t)(1 + 2 * p) * NCHUNK + c) * NN;
    int lo = rg * RSIZE;
    for (int i = threadIdx.x; i < RSIZE; i += 256) cur[i] = 0;
    __syncthreads();
    int beg = c * CH, end = beg + CH;
    for (int i = beg + threadIdx.x; i < end; i += 256) {
        int d = dst[i];
        int v = d - lo;
        if ((unsigned)v < (unsigned)RSIZE) {
            int s = src[i];
            int r = atomicAdd(&cur[v], 1);
            es[off[d] + pfx[d] + r] = s;
        }
    }
}

// ---------------------------------------------------------------------------
// merged APPNP step (both paths, grid.y = path), bf16 gather payload.
// xout[v] = 0.9*nd[v]*sum_{e:dst=v} ns[u]*xin[u] + 0.1*h0[v]
// OUTF32=0 -> bf16 out (intermediate); OUTF32=1 -> f32 out (final z)
// ---------------------------------------------------------------------------
template<int OUTF32>
__global__ __launch_bounds__(256) void k_appnp2(
    const unsigned* __restrict__ xin0, const unsigned* __restrict__ xin1,
    void* __restrict__ xo0, void* __restrict__ xo1,
    const unsigned* __restrict__ h0,
    const int* __restrict__ off0, const int* __restrict__ es0,
    const float* __restrict__ ns0, const float* __restrict__ nd0,
    const int* __restrict__ off1, const int* __restrict__ es1,
    const float* __restrict__ ns1, const float* __restrict__ nd1)
{
    int p = blockIdx.y;
    const unsigned* xin = p ? xin1 : xin0;
    const int* off = p ? off1 : off0;
    const int* es  = p ? es1  : es0;
    const float* ns = p ? ns1 : ns0;
    const float* nd = p ? nd1 : nd0;
    int wid  = (blockIdx.x * 256 + threadIdx.x) >> 6;
    int lane = threadIdx.x & 63;
    if (wid >= NN) return;
    int v = wid;
    int beg = off[v], end = off[v + 1];
    float ax = 0.f, ay = 0.f;
    int e = beg;
    for (; e + 3 < end; e += 4) {
        int u0 = es[e], u1 = es[e + 1], u2 = es[e + 2], u3 = es[e + 3];
        float s0 = ns[u0], s1 = ns[u1], s2 = ns[u2], s3 = ns[u3];
        unsigned w0 = xin[u0 * 64 + lane];
        unsigned w1 = xin[u1 * 64 + lane];
        unsigned w2 = xin[u2 * 64 + lane];
        unsigned w3 = xin[u3 * 64 + lane];
        ax = fmaf(b2f_lo(w0), s0, ax); ay = fmaf(b2f_hi(w0), s0, ay);
        ax = fmaf(b2f_lo(w1), s1, ax); ay = fmaf(b2f_hi(w1), s1, ay);
        ax = fmaf(b2f_lo(w2), s2, ax); ay = fmaf(b2f_hi(w2), s2, ay);
        ax = fmaf(b2f_lo(w3), s3, ax); ay = fmaf(b2f_hi(w3), s3, ay);
    }
    for (; e < end; ++e) {
        int u0 = es[e];
        float s0 = ns[u0];
        unsigned w0 = xin[u0 * 64 + lane];
        ax = fmaf(b2f_lo(w0), s0, ax); ay = fmaf(b2f_hi(w0), s0, ay);
    }
    float scale = 0.9f * nd[v];
    unsigned hw = h0[v * 64 + lane];
    float rx = fmaf(ax, scale, 0.1f * b2f_lo(hw));
    float ry = fmaf(ay, scale, 0.1f * b2f_hi(hw));
    if (OUTF32) {
        float2* xo = (float2*)(p ? xo1 : xo0);
        xo[v * 64 + lane] = make_float2(rx, ry);
    } else {
        unsigned* xo = (unsigned*)(p ? xo1 : xo0);
        xo[v * 64 + lane] = (unsigned)f2b(rx) | ((unsigned)f2b(ry) << 16);
    }
}

// ---------------------------------------------------------------------------
// beta = softmax(S/N); out = beta0*z0 + beta1*z1
// ---------------------------------------------------------------------------
__global__ __launch_bounds__(256) void k_combine(
    const float* __restrict__ z0, const float* __restrict__ z1,
    const float* __restrict__ S, float* __restrict__ out)
{
    float w0 = S[0] * (1.0f / NN);
    float w1 = S[1] * (1.0f / NN);
    float m  = fmaxf(w0, w1);
    float e0 = expf(w0 - m), e1 = expf(w1 - m);
    float inv = 1.0f / (e0 + e1);
    float b0 = e0 * inv, b1 = e1 * inv;
    const float4* a = (const float4*)z0;
    const float4* c = (const float4*)z1;
    float4* o = (float4*)out;
    int i = blockIdx.x * 256 + threadIdx.x;
    int stride = gridDim.x * 256;
    for (; i < NN * DD / 4; i += stride) {
        float4 x = a[i], y = c[i];
        float4 r;
        r.x = b0 * x.x + b1 * y.x;
        r.y = b0 * x.y + b1 * y.y;
        r.z = b0 * x.z + b1 * y.z;
        r.w = b0 * x.w + b1 * y.w;
        o[i] = r;
    }
}

// ---------------------------------------------------------------------------
extern "C" void kernel_launch(void* const* d_in, const int* in_sizes, int n_in,
                              void* d_out, int out_size, void* d_ws, size_t ws_size,
                              hipStream_t stream)
{
    const float* h     = (const float*)d_in[0];
    const int*   src0  = (const int*)d_in[1];
    const int*   dst0  = (const int*)d_in[2];
    const int*   src1  = (const int*)d_in[3];
    const int*   dst1  = (const int*)d_in[4];
    const float* W_h   = (const float*)d_in[5];
    const float* b_h   = (const float*)d_in[6];
    const float* W_att = (const float*)d_in[7];
    const float* b_att = (const float*)d_in[8];
    const float* q_att = (const float*)d_in[9];
    float* out = (float*)d_out;

    char* ws = (char*)d_ws;
    size_t o = 0;
    auto alloc = [&](size_t bytes) -> void* {
        void* p = ws + o;
        o += (bytes + 255) & ~(size_t)255;
        return p;
    };
    const size_t ND  = (size_t)NN * DD * sizeof(float);
    const size_t NDb = (size_t)NN * DD * sizeof(short);
    unsigned short* h1b = (unsigned short*)alloc(NDb);           // bf16 h1
    int*   partial = (int*)alloc((size_t)4 * NCHUNK * NN * sizeof(int));
    // A0/A1 (bf16 step-1 outputs) alias partial — dead after k_fill2
    unsigned* A0 = (unsigned*)partial;
    unsigned* A1 = A0 + (size_t)NN * DD / 2;
    float* z0 = (float*)alloc(ND);
    float* z1 = (float*)alloc(ND);
    unsigned* B0 = (unsigned*)alloc(NDb);
    unsigned* B1 = (unsigned*)alloc(NDb);
    float* ns0 = (float*)alloc(NN * 4);
    float* nd0 = (float*)alloc(NN * 4);
    float* ns1 = (float*)alloc(NN * 4);
    float* nd1 = (float*)alloc(NN * 4);
    int* cdeg0 = (int*)alloc(NN * 4);
    int* cdeg1 = (int*)alloc(NN * 4);
    int* off0 = (int*)alloc((NN + 1) * 4);
    int* off1 = (int*)alloc((NN + 1) * 4);
    int* es0  = (int*)alloc(EE * 4);
    int* es1  = (int*)alloc(EE * 4);
    int* bsum  = (int*)alloc(2 * NSB * 4);
    int* bbase = (int*)alloc(2 * NSB * 4);
    short* WTh = (short*)alloc(DD * DD * 2);
    short* WTa = (short*)alloc(DD * DD * 2);
    float* S   = (float*)alloc(256);
    hipMemsetAsync(S, 0, 256, stream);

    // 0. transpose+convert weights to bf16
    k_prep<<<2, 256, 0, stream>>>(W_h, W_att, WTh, WTa);
    // 1. h1 = relu(h @ W_h + b_h)  (MFMA, bf16 out)
    k_linear_mfma<<<(NSTRIP + 3) / 4, 256, 0, stream>>>(h, WTh, b_h, h1b);
    // 2. per-chunk histograms
    k_hist<<<dim3(NCHUNK, NRANGE, 4), 256, 0, stream>>>(src0, dst0, src1, dst1, partial);
    // 3. reduce -> degrees/norms + chunk prefixes
    k_reduce<<<dim3((NN + 255) / 256, 4), 256, 0, stream>>>(
        partial, ns0, nd0, ns1, nd1, cdeg0, cdeg1);
    // 4. CSR offsets: 3-pass scan
    k_scan1<<<dim3(NSB, 2), 256, 0, stream>>>(cdeg0, cdeg1, bsum);
    k_scan2<<<1, 64, 0, stream>>>(bsum, bbase, off0, off1);
    k_scan3<<<dim3(NSB, 2), 256, 0, stream>>>(cdeg0, cdeg1, bbase, off0, off1);
    // 5. atomic-free CSR fill
    k_fill2<<<dim3(NCHUNK, NRANGE, 2), 256, 0, stream>>>(
        src0, dst0, src1, dst1, partial, off0, off1, es0, es1);
    // 6. APPNP: 3 merged steps (both paths per launch); bf16 intermediates
    const unsigned* h1u = (const unsigned*)h1b;
    const int ablocks = (NN + 3) / 4;
    k_appnp2<0><<<dim3(ablocks, 2), 256, 0, stream>>>(
        h1u, h1u, A0, A1, h1u,
        off0, es0, ns0, nd0, off1, es1, ns1, nd1);
    k_appnp2<0><<<dim3(ablocks, 2), 256, 0, stream>>>(
        A0, A1, B0, B1, h1u,
        off0, es0, ns0, nd0, off1, es1, ns1, nd1);
    k_appnp2<1><<<dim3(ablocks, 2), 256, 0, stream>>>(
        B0, B1, z0, z1, h1u,
        off0, es0, ns0, nd0, off1, es1, ns1, nd1);
    // 7. semantic attention scores (MFMA)
    k_attn_mfma<<<dim3((NSTRIP + 3) / 4, 2), 256, 0, stream>>>(
        z0, z1, WTa, b_att, q_att, S);
    // 8. softmax + weighted combine
    k_combine<<<2048, 256, 0, stream>>>(z0, z1, S, out);
    (void)in_sizes; (void)n_in; (void)out_size; (void)ws_size;
}

// Round 8
// 479.486 us; speedup vs baseline: 2.8189x; 1.0460x over previous
//
#include <hip/hip_runtime.h>

#define NN 50000
#define EE 800000
#define DD 128
#define NCHUNK 32
#define CH (EE / NCHUNK)        // 25000
#define NRANGE 4
#define RSIZE (NN / NRANGE)     // 12500
#define NSB 49                  // ceil(NN/1024)
#define NSTRIP (NN / 16)        // 3125 (exact)

typedef __attribute__((ext_vector_type(8))) short bf16x8;
typedef __attribute__((ext_vector_type(4))) float f32x4;

// f32 -> bf16 bits, round-to-nearest-even
__device__ __forceinline__ unsigned short f2b(float x) {
    unsigned u = __float_as_uint(x);
    unsigned r = (u + 0x7fffu + ((u >> 16) & 1u)) >> 16;
    return (unsigned short)r;
}
__device__ __forceinline__ float b2f_lo(unsigned w) {
    return __uint_as_float((w & 0xffffu) << 16);
}
__device__ __forceinline__ float b2f_hi(unsigned w) {
    return __uint_as_float(w & 0xffff0000u);
}

// ---------------------------------------------------------------------------
// prep: WT[n][k] = bf16(W[k][n]) for W_h (block 0) and W_att (block 1)
// ---------------------------------------------------------------------------
__global__ __launch_bounds__(256) void k_prep(
    const float* __restrict__ Wh, const float* __restrict__ Wa,
    short* __restrict__ WTh, short* __restrict__ WTa)
{
    const float* W = blockIdx.x ? Wa : Wh;
    short* WT      = blockIdx.x ? WTa : WTh;
    for (int i = threadIdx.x; i < DD * DD; i += 256) {
        int n = i >> 7, k = i & 127;
        WT[i] = (short)f2b(W[k * DD + n]);
    }
}

// ---------------------------------------------------------------------------
// h1 = relu(h @ W + b) via bf16 MFMA -> bf16 output (gather payload format)
// ---------------------------------------------------------------------------
__global__ __launch_bounds__(256) void k_linear_mfma(
    const float* __restrict__ h, const short* __restrict__ WT,
    const float* __restrict__ b, unsigned short* __restrict__ out)
{
    __shared__ char ldsb[32768];
    int tid = threadIdx.x;
    for (int i = tid; i < DD * DD / 8; i += 256) {
        int n = i >> 4, k8 = i & 15;
        int4 v = ((const int4*)WT)[i];
        *(int4*)(ldsb + n * 256 + ((k8 * 16) ^ ((n & 7) << 4))) = v;
    }
    __syncthreads();
    int wid = tid >> 6, l = tid & 63;
    int s = blockIdx.x * 4 + wid;
    if (s >= NSTRIP) return;
    int lr = l & 15, lg = l >> 4;
    int row0 = s * 16;
    const float4* ap = (const float4*)(h + (size_t)(row0 + lr) * DD + lg * 8);
    bf16x8 a[4];
    #pragma unroll 4
    for (int t = 0; t < 4; ++t) {
        float4 f0 = ap[8 * t], f1 = ap[8 * t + 1];
        a[t][0] = f2b(f0.x); a[t][1] = f2b(f0.y); a[t][2] = f2b(f0.z); a[t][3] = f2b(f0.w);
        a[t][4] = f2b(f1.x); a[t][5] = f2b(f1.y); a[t][6] = f2b(f1.z); a[t][7] = f2b(f1.w);
    }
    f32x4 acc[8];
    #pragma unroll 8
    for (int c = 0; c < 8; ++c) acc[c] = (f32x4){0.f, 0.f, 0.f, 0.f};
    #pragma unroll 8
    for (int c = 0; c < 8; ++c) {
        int n = c * 16 + lr;
        #pragma unroll 4
        for (int t = 0; t < 4; ++t) {
            bf16x8 bv = *(bf16x8*)(ldsb + n * 256 + ((t * 64 + lg * 16) ^ ((n & 7) << 4)));
            acc[c] = __builtin_amdgcn_mfma_f32_16x16x32_bf16(a[t], bv, acc[c], 0, 0, 0);
        }
    }
    #pragma unroll 8
    for (int c = 0; c < 8; ++c) {
        int col = c * 16 + lr;
        float bc = b[col];
        #pragma unroll 4
        for (int r = 0; r < 4; ++r) {
            float v = acc[c][r] + bc;
            out[(size_t)(row0 + lg * 4 + r) * DD + col] = f2b(fmaxf(v, 0.f));
        }
    }
}

// ---------------------------------------------------------------------------
// S[p] = sum_n tanh(z_p[n] @ W_att + b_att) . q_att  via bf16 MFMA (z f32)
// ---------------------------------------------------------------------------
__global__ __launch_bounds__(256) void k_attn_mfma(
    const float* __restrict__ z0, const float* __restrict__ z1,
    const short* __restrict__ WT, const float* __restrict__ b,
    const float* __restrict__ q, float* __restrict__ S)
{
    __shared__ char ldsb[32768];
    __shared__ float red[4];
    const float* z = blockIdx.y ? z1 : z0;
    int tid = threadIdx.x;
    for (int i = tid; i < DD * DD / 8; i += 256) {
        int n = i >> 4, k8 = i & 15;
        int4 v = ((const int4*)WT)[i];
        *(int4*)(ldsb + n * 256 + ((k8 * 16) ^ ((n & 7) << 4))) = v;
    }
    __syncthreads();
    int wid = tid >> 6, l = tid & 63;
    int s = blockIdx.x * 4 + wid;
    float part = 0.f;
    if (s < NSTRIP) {
        int lr = l & 15, lg = l >> 4;
        int row0 = s * 16;
        const float4* ap = (const float4*)(z + (size_t)(row0 + lr) * DD + lg * 8);
        bf16x8 a[4];
        #pragma unroll 4
        for (int t = 0; t < 4; ++t) {
            float4 f0 = ap[8 * t], f1 = ap[8 * t + 1];
            a[t][0] = f2b(f0.x); a[t][1] = f2b(f0.y); a[t][2] = f2b(f0.z); a[t][3] = f2b(f0.w);
            a[t][4] = f2b(f1.x); a[t][5] = f2b(f1.y); a[t][6] = f2b(f1.z); a[t][7] = f2b(f1.w);
        }
        f32x4 acc[8];
        #pragma unroll 8
        for (int c = 0; c < 8; ++c) acc[c] = (f32x4){0.f, 0.f, 0.f, 0.f};
        #pragma unroll 8
        for (int c = 0; c < 8; ++c) {
            int n = c * 16 + lr;
            #pragma unroll 4
            for (int t = 0; t < 4; ++t) {
                bf16x8 bv = *(bf16x8*)(ldsb + n * 256 + ((t * 64 + lg * 16) ^ ((n & 7) << 4)));
                acc[c] = __builtin_amdgcn_mfma_f32_16x16x32_bf16(a[t], bv, acc[c], 0, 0, 0);
            }
        }
        #pragma unroll 8
        for (int c = 0; c < 8; ++c) {
            int col = c * 16 + lr;
            float bc = b[col], qc = q[col];
            #pragma unroll 4
            for (int r = 0; r < 4; ++r)
                part += tanhf(acc[c][r] + bc) * qc;
        }
    }
    for (int sh = 32; sh > 0; sh >>= 1)
        part += __shfl_down(part, sh);
    if (l == 0) red[wid] = part;
    __syncthreads();
    if (tid == 0)
        atomicAdd(&S[blockIdx.y], red[0] + red[1] + red[2] + red[3]);
}

// ---------------------------------------------------------------------------
// per-chunk partial histograms, LDS-atomic only, plain stores out.
// ---------------------------------------------------------------------------
__global__ __launch_bounds__(256) void k_hist(
    const int* __restrict__ s0, const int* __restrict__ d0,
    const int* __restrict__ s1, const int* __restrict__ d1,
    int* __restrict__ partial)
{
    __shared__ int hist[RSIZE];          // 50 KB
    int c = blockIdx.x, rg = blockIdx.y, a = blockIdx.z;
    const int* idx = (a == 0) ? s0 : (a == 1) ? d0 : (a == 2) ? s1 : d1;
    int lo = rg * RSIZE;
    for (int i = threadIdx.x; i < RSIZE; i += 256) hist[i] = 0;
    __syncthreads();
    int beg = c * CH, end = beg + CH;
    for (int i = beg + threadIdx.x; i < end; i += 256) {
        int v = idx[i] - lo;
        if ((unsigned)v < (unsigned)RSIZE) atomicAdd(&hist[v], 1);
    }
    __syncthreads();
    int* dst = partial + ((size_t)a * NCHUNK + c) * NN + lo;
    for (int i = threadIdx.x; i < RSIZE; i += 256) dst[i] = hist[i];
}

// ---------------------------------------------------------------------------
// reduce partials -> degree + norm; dst arrays get in-place chunk prefixes
// ---------------------------------------------------------------------------
__global__ __launch_bounds__(256) void k_reduce(
    int* __restrict__ partial,
    float* ns0, float* nd0, float* ns1, float* nd1,
    int* cdeg0, int* cdeg1)
{
    int n = blockIdx.x * 256 + threadIdx.x;
    int a = blockIdx.y;
    if (n >= NN) return;
    int run = 0;
    bool isdst = a & 1;
    for (int c = 0; c < NCHUNK; ++c) {
        size_t ix = ((size_t)a * NCHUNK + c) * NN + n;
        int t = partial[ix];
        if (isdst) partial[ix] = run;
        run += t;
    }
    float nv = rsqrtf((float)(run > 1 ? run : 1));
    if (a == 0) ns0[n] = nv;
    else if (a == 1) { nd0[n] = nv; cdeg0[n] = run; }
    else if (a == 2) ns1[n] = nv;
    else { nd1[n] = nv; cdeg1[n] = run; }
}

// ---------------------------------------------------------------------------
__global__ __launch_bounds__(256) void k_scan1(
    const int* __restrict__ cdeg0, const int* __restrict__ cdeg1,
    int* __restrict__ bsum)
{
    const int* dg = blockIdx.y ? cdeg1 : cdeg0;
    __shared__ int ws_[4];
    int tid = threadIdx.x;
    int n0 = blockIdx.x * 1024 + tid * 4;
    int s = 0;
    #pragma unroll
    for (int k = 0; k < 4; ++k) {
        int n = n0 + k;
        if (n < NN) s += dg[n];
    }
    for (int sh = 32; sh > 0; sh >>= 1) s += __shfl_down(s, sh);
    if ((tid & 63) == 0) ws_[tid >> 6] = s;
    __syncthreads();
    if (tid == 0)
        bsum[blockIdx.y * NSB + blockIdx.x] = ws_[0] + ws_[1] + ws_[2] + ws_[3];
}

__global__ __launch_bounds__(64) void k_scan2(
    const int* __restrict__ bsum, int* __restrict__ bbase,
    int* off0, int* off1)
{
    int p = threadIdx.x;
    if (p < 2) {
        int run = 0;
        for (int b = 0; b < NSB; ++b) {
            bbase[p * NSB + b] = run;
            run += bsum[p * NSB + b];
        }
        (p ? off1 : off0)[NN] = run;
    }
}

__global__ __launch_bounds__(256) void k_scan3(
    const int* __restrict__ cdeg0, const int* __restrict__ cdeg1,
    const int* __restrict__ bbase, int* off0, int* off1)
{
    const int* dg = blockIdx.y ? cdeg1 : cdeg0;
    int* off      = blockIdx.y ? off1  : off0;
    __shared__ int ts[256];
    int tid = threadIdx.x;
    int n0 = blockIdx.x * 1024 + tid * 4;
    int d0 = 0, d1 = 0, d2 = 0, d3 = 0;
    if (n0 + 0 < NN) d0 = dg[n0 + 0];
    if (n0 + 1 < NN) d1 = dg[n0 + 1];
    if (n0 + 2 < NN) d2 = dg[n0 + 2];
    if (n0 + 3 < NN) d3 = dg[n0 + 3];
    int tot = d0 + d1 + d2 + d3;
    ts[tid] = tot;
    __syncthreads();
    for (int s = 1; s < 256; s <<= 1) {
        int u = (tid >= s) ? ts[tid - s] : 0;
        __syncthreads();
        ts[tid] += u;
        __syncthreads();
    }
    int base = bbase[blockIdx.y * NSB + blockIdx.x] + ts[tid] - tot;
    if (n0 + 0 < NN) off[n0 + 0] = base;
    if (n0 + 1 < NN) off[n0 + 1] = base + d0;
    if (n0 + 2 < NN) off[n0 + 2] = base + d0 + d1;
    if (n0 + 3 < NN) off[n0 + 3] = base + d0 + d1 + d2;
}

// ---------------------------------------------------------------------------
// atomic-free CSR fill: slot = off[d] + chunk_prefix[c][d] + lds_rank
// ---------------------------------------------------------------------------
__global__ __launch_bounds__(256) void k_fill2(
    const int* __restrict__ src0, const int* __restrict__ dst0,
    const int* __restrict__ src1, const int* __restrict__ dst1,
    const int* __restrict__ partial,
    const int* __restrict__ off0, const int* __restrict__ off1,
    int* __restrict__ es0, int* __restrict__ es1)
{
    __shared__ int cur[RSIZE];           // 50 KB
    int c = blockIdx.x, rg = blockIdx.y, p = blockIdx.z;
    const int* src = p ? src1 : src0;
    const int* dst = p ? dst1 : dst0;
    const int* off = p ? off1 : off0;
    int* es        = p ? es1  : es0;
    const int* pfx = partial + ((size_t)(1 + 2 * p) * NCHUNK + c) * NN;
    int lo = rg * RSIZE;
    for (int i = threadIdx.x; i < RSIZE; i += 256) cur[i] = 0;
    __syncthreads();
    int beg = c * CH, end = beg + CH;
    for (int i = beg + threadIdx.x; i < end; i += 256) {
        int d = dst[i];
        int v = d - lo;
        if ((unsigned)v < (unsigned)RSIZE) {
            int s = src[i];
            int r = atomicAdd(&cur[v], 1);
            es[off[d] + pfx[d] + r] = s;
        }
    }
}

// ---------------------------------------------------------------------------
// merged APPNP step, 16 B/lane gather: wave = 4 groups x 16 lanes;
// group g handles edge e+g; lane reads uint4 (8 bf16 feats).
// Cross-group shfl_xor reduce; lanes 0-15 write the row.
// ---------------------------------------------------------------------------
template<int OUTF32>
__global__ __launch_bounds__(256) void k_appnp3(
    const unsigned* __restrict__ xin0, const unsigned* __restrict__ xin1,
    void* __restrict__ xo0, void* __restrict__ xo1,
    const unsigned* __restrict__ h0,
    const int* __restrict__ off0, const int* __restrict__ es0,
    const float* __restrict__ ns0, const float* __restrict__ nd0,
    const int* __restrict__ off1, const int* __restrict__ es1,
    const float* __restrict__ ns1, const float* __restrict__ nd1)
{
    int p = blockIdx.y;
    const unsigned* xin = p ? xin1 : xin0;
    const int* off = p ? off1 : off0;
    const int* es  = p ? es1  : es0;
    const float* ns = p ? ns1 : ns0;
    const float* nd = p ? nd1 : nd0;
    int wid  = (blockIdx.x * 256 + threadIdx.x) >> 6;
    if (wid >= NN) return;
    int l = threadIdx.x & 63;
    int g = l >> 4, f = l & 15;
    int v = wid;
    int beg = off[v], end = off[v + 1];
    const uint4* xin4 = (const uint4*)xin;
    float acc[8];
    #pragma unroll
    for (int i = 0; i < 8; ++i) acc[i] = 0.f;
    for (int e = beg; e < end; e += 8) {
        int e0 = e + g, e1 = e + 4 + g;
        bool p0 = e0 < end, p1 = e1 < end;
        int u0 = p0 ? es[e0] : 0;
        int u1 = p1 ? es[e1] : 0;
        float s0 = p0 ? ns[u0] : 0.f;
        float s1 = p1 ? ns[u1] : 0.f;
        uint4 w0 = xin4[(size_t)u0 * 16 + f];
        uint4 w1 = xin4[(size_t)u1 * 16 + f];
        acc[0] = fmaf(b2f_lo(w0.x), s0, acc[0]);
        acc[1] = fmaf(b2f_hi(w0.x), s0, acc[1]);
        acc[2] = fmaf(b2f_lo(w0.y), s0, acc[2]);
        acc[3] = fmaf(b2f_hi(w0.y), s0, acc[3]);
        acc[4] = fmaf(b2f_lo(w0.z), s0, acc[4]);
        acc[5] = fmaf(b2f_hi(w0.z), s0, acc[5]);
        acc[6] = fmaf(b2f_lo(w0.w), s0, acc[6]);
        acc[7] = fmaf(b2f_hi(w0.w), s0, acc[7]);
        acc[0] = fmaf(b2f_lo(w1.x), s1, acc[0]);
        acc[1] = fmaf(b2f_hi(w1.x), s1, acc[1]);
        acc[2] = fmaf(b2f_lo(w1.y), s1, acc[2]);
        acc[3] = fmaf(b2f_hi(w1.y), s1, acc[3]);
        acc[4] = fmaf(b2f_lo(w1.z), s1, acc[4]);
        acc[5] = fmaf(b2f_hi(w1.z), s1, acc[5]);
        acc[6] = fmaf(b2f_lo(w1.w), s1, acc[6]);
        acc[7] = fmaf(b2f_hi(w1.w), s1, acc[7]);
    }
    #pragma unroll
    for (int i = 0; i < 8; ++i) {
        acc[i] += __shfl_xor(acc[i], 16);
        acc[i] += __shfl_xor(acc[i], 32);
    }
    if (g == 0) {
        float scale = 0.9f * nd[v];
        uint4 hw = ((const uint4*)h0)[(size_t)v * 16 + f];
        float r0 = fmaf(acc[0], scale, 0.1f * b2f_lo(hw.x));
        float r1 = fmaf(acc[1], scale, 0.1f * b2f_hi(hw.x));
        float r2 = fmaf(acc[2], scale, 0.1f * b2f_lo(hw.y));
        float r3 = fmaf(acc[3], scale, 0.1f * b2f_hi(hw.y));
        float r4 = fmaf(acc[4], scale, 0.1f * b2f_lo(hw.z));
        float r5 = fmaf(acc[5], scale, 0.1f * b2f_hi(hw.z));
        float r6 = fmaf(acc[6], scale, 0.1f * b2f_lo(hw.w));
        float r7 = fmaf(acc[7], scale, 0.1f * b2f_hi(hw.w));
        if (OUTF32) {
            float4* xo = (float4*)(p ? xo1 : xo0);
            xo[(size_t)v * 32 + f * 2]     = make_float4(r0, r1, r2, r3);
            xo[(size_t)v * 32 + f * 2 + 1] = make_float4(r4, r5, r6, r7);
        } else {
            uint4* xo = (uint4*)(p ? xo1 : xo0);
            uint4 ov;
            ov.x = (unsigned)f2b(r0) | ((unsigned)f2b(r1) << 16);
            ov.y = (unsigned)f2b(r2) | ((unsigned)f2b(r3) << 16);
            ov.z = (unsigned)f2b(r4) | ((unsigned)f2b(r5) << 16);
            ov.w = (unsigned)f2b(r6) | ((unsigned)f2b(r7) << 16);
            xo[(size_t)v * 16 + f] = ov;
        }
    }
}

// ---------------------------------------------------------------------------
// beta = softmax(S/N); out = beta0*z0 + beta1*z1
// ---------------------------------------------------------------------------
__global__ __launch_bounds__(256) void k_combine(
    const float* __restrict__ z0, const float* __restrict__ z1,
    const float* __restrict__ S, float* __restrict__ out)
{
    float w0 = S[0] * (1.0f / NN);
    float w1 = S[1] * (1.0f / NN);
    float m  = fmaxf(w0, w1);
    float e0 = expf(w0 - m), e1 = expf(w1 - m);
    float inv = 1.0f / (e0 + e1);
    float b0 = e0 * inv, b1 = e1 * inv;
    const float4* a = (const float4*)z0;
    const float4* c = (const float4*)z1;
    float4* o = (float4*)out;
    int i = blockIdx.x * 256 + threadIdx.x;
    int stride = gridDim.x * 256;
    for (; i < NN * DD / 4; i += stride) {
        float4 x = a[i], y = c[i];
        float4 r;
        r.x = b0 * x.x + b1 * y.x;
        r.y = b0 * x.y + b1 * y.y;
        r.z = b0 * x.z + b1 * y.z;
        r.w = b0 * x.w + b1 * y.w;
        o[i] = r;
    }
}

// ---------------------------------------------------------------------------
extern "C" void kernel_launch(void* const* d_in, const int* in_sizes, int n_in,
                              void* d_out, int out_size, void* d_ws, size_t ws_size,
                              hipStream_t stream)
{
    const float* h     = (const float*)d_in[0];
    const int*   src0  = (const int*)d_in[1];
    const int*   dst0  = (const int*)d_in[2];
    const int*   src1  = (const int*)d_in[3];
    const int*   dst1  = (const int*)d_in[4];
    const float* W_h   = (const float*)d_in[5];
    const float* b_h   = (const float*)d_in[6];
    const float* W_att = (const float*)d_in[7];
    const float* b_att = (const float*)d_in[8];
    const float* q_att = (const float*)d_in[9];
    float* out = (float*)d_out;

    char* ws = (char*)d_ws;
    size_t o = 0;
    auto alloc = [&](size_t bytes) -> void* {
        void* p = ws + o;
        o += (bytes + 255) & ~(size_t)255;
        return p;
    };
    const size_t ND  = (size_t)NN * DD * sizeof(float);
    const size_t NDb = (size_t)NN * DD * sizeof(short);
    unsigned short* h1b = (unsigned short*)alloc(NDb);           // bf16 h1
    int*   partial = (int*)alloc((size_t)4 * NCHUNK * NN * sizeof(int));
    // A0/A1 (bf16 step-1 outputs) alias partial — dead after k_fill2
    unsigned* A0 = (unsigned*)partial;
    unsigned* A1 = A0 + (size_t)NN * DD / 2;
    float* z0 = (float*)alloc(ND);
    float* z1 = (float*)alloc(ND);
    unsigned* B0 = (unsigned*)alloc(NDb);
    unsigned* B1 = (unsigned*)alloc(NDb);
    float* ns0 = (float*)alloc(NN * 4);
    float* nd0 = (float*)alloc(NN * 4);
    float* ns1 = (float*)alloc(NN * 4);
    float* nd1 = (float*)alloc(NN * 4);
    int* cdeg0 = (int*)alloc(NN * 4);
    int* cdeg1 = (int*)alloc(NN * 4);
    int* off0 = (int*)alloc((NN + 1) * 4);
    int* off1 = (int*)alloc((NN + 1) * 4);
    int* es0  = (int*)alloc(EE * 4);
    int* es1  = (int*)alloc(EE * 4);
    int* bsum  = (int*)alloc(2 * NSB * 4);
    int* bbase = (int*)alloc(2 * NSB * 4);
    short* WTh = (short*)alloc(DD * DD * 2);
    short* WTa = (short*)alloc(DD * DD * 2);
    float* S   = (float*)alloc(256);
    hipMemsetAsync(S, 0, 256, stream);

    // 0. transpose+convert weights to bf16
    k_prep<<<2, 256, 0, stream>>>(W_h, W_att, WTh, WTa);
    // 1. h1 = relu(h @ W_h + b_h)  (MFMA, bf16 out)
    k_linear_mfma<<<(NSTRIP + 3) / 4, 256, 0, stream>>>(h, WTh, b_h, h1b);
    // 2. per-chunk histograms
    k_hist<<<dim3(NCHUNK, NRANGE, 4), 256, 0, stream>>>(src0, dst0, src1, dst1, partial);
    // 3. reduce -> degrees/norms + chunk prefixes
    k_reduce<<<dim3((NN + 255) / 256, 4), 256, 0, stream>>>(
        partial, ns0, nd0, ns1, nd1, cdeg0, cdeg1);
    // 4. CSR offsets: 3-pass scan
    k_scan1<<<dim3(NSB, 2), 256, 0, stream>>>(cdeg0, cdeg1, bsum);
    k_scan2<<<1, 64, 0, stream>>>(bsum, bbase, off0, off1);
    k_scan3<<<dim3(NSB, 2), 256, 0, stream>>>(cdeg0, cdeg1, bbase, off0, off1);
    // 5. atomic-free CSR fill
    k_fill2<<<dim3(NCHUNK, NRANGE, 2), 256, 0, stream>>>(
        src0, dst0, src1, dst1, partial, off0, off1, es0, es1);
    // 6. APPNP: 3 merged steps (both paths per launch); bf16 intermediates
    const unsigned* h1u = (const unsigned*)h1b;
    const int ablocks = (NN + 3) / 4;
    k_appnp3<0><<<dim3(ablocks, 2), 256, 0, stream>>>(
        h1u, h1u, A0, A1, h1u,
        off0, es0, ns0, nd0, off1, es1, ns1, nd1);
    k_appnp3<0><<<dim3(ablocks, 2), 256, 0, stream>>>(
        A0, A1, B0, B1, h1u,
        off0, es0, ns0, nd0, off1, es1, ns1, nd1);
    k_appnp3<1><<<dim3(ablocks, 2), 256, 0, stream>>>(
        B0, B1, z0, z1, h1u,
        off0, es0, ns0, nd0, off1, es1, ns1, nd1);
    // 7. semantic attention scores (MFMA)
    k_attn_mfma<<<dim3((NSTRIP + 3) / 4, 2), 256, 0, stream>>>(
        z0, z1, WTa, b_att, q_att, S);
    // 8. softmax + weighted combine
    k_combine<<<2048, 256, 0, stream>>>(z0, z1, S, out);
    (void)in_sizes; (void)n_in; (void)out_size; (void)ws_size;
}

// Round 10
// 462.095 us; speedup vs baseline: 2.9250x; 1.0376x over previous
//
#include <hip/hip_runtime.h>

#define NN 50000
#define EE 800000
#define DD 128
#define NCHUNK 32
#define CH (EE / NCHUNK)        // 25000
#define NRANGE 4
#define RSIZE (NN / NRANGE)     // 12500
#define NSB 49                  // ceil(NN/1024)
#define NSTRIP (NN / 16)        // 3125 (exact)

typedef __attribute__((ext_vector_type(8))) short bf16x8;
typedef __attribute__((ext_vector_type(4))) float f32x4;

// f32 -> bf16 bits, round-to-nearest-even
__device__ __forceinline__ unsigned short f2b(float x) {
    unsigned u = __float_as_uint(x);
    unsigned r = (u + 0x7fffu + ((u >> 16) & 1u)) >> 16;
    return (unsigned short)r;
}
__device__ __forceinline__ float b2f_lo(unsigned w) {
    return __uint_as_float((w & 0xffffu) << 16);
}
__device__ __forceinline__ float b2f_hi(unsigned w) {
    return __uint_as_float(w & 0xffff0000u);
}

// ---------------------------------------------------------------------------
// prep: WT[n][k] = bf16(W[k][n]) for W_h (block 0) and W_att (block 1)
// ---------------------------------------------------------------------------
__global__ __launch_bounds__(256) void k_prep(
    const float* __restrict__ Wh, const float* __restrict__ Wa,
    short* __restrict__ WTh, short* __restrict__ WTa)
{
    const float* W = blockIdx.x ? Wa : Wh;
    short* WT      = blockIdx.x ? WTa : WTh;
    for (int i = threadIdx.x; i < DD * DD; i += 256) {
        int n = i >> 7, k = i & 127;
        WT[i] = (short)f2b(W[k * DD + n]);
    }
}

// ---------------------------------------------------------------------------
// h1 = relu(h @ W + b) via bf16 MFMA -> bf16 output (gather payload format)
// ---------------------------------------------------------------------------
__global__ __launch_bounds__(256) void k_linear_mfma(
    const float* __restrict__ h, const short* __restrict__ WT,
    const float* __restrict__ b, unsigned short* __restrict__ out)
{
    __shared__ char ldsb[32768];
    int tid = threadIdx.x;
    for (int i = tid; i < DD * DD / 8; i += 256) {
        int n = i >> 4, k8 = i & 15;
        int4 v = ((const int4*)WT)[i];
        *(int4*)(ldsb + n * 256 + ((k8 * 16) ^ ((n & 7) << 4))) = v;
    }
    __syncthreads();
    int wid = tid >> 6, l = tid & 63;
    int s = blockIdx.x * 4 + wid;
    if (s >= NSTRIP) return;
    int lr = l & 15, lg = l >> 4;
    int row0 = s * 16;
    const float4* ap = (const float4*)(h + (size_t)(row0 + lr) * DD + lg * 8);
    bf16x8 a[4];
    #pragma unroll 4
    for (int t = 0; t < 4; ++t) {
        float4 f0 = ap[8 * t], f1 = ap[8 * t + 1];
        a[t][0] = f2b(f0.x); a[t][1] = f2b(f0.y); a[t][2] = f2b(f0.z); a[t][3] = f2b(f0.w);
        a[t][4] = f2b(f1.x); a[t][5] = f2b(f1.y); a[t][6] = f2b(f1.z); a[t][7] = f2b(f1.w);
    }
    f32x4 acc[8];
    #pragma unroll 8
    for (int c = 0; c < 8; ++c) acc[c] = (f32x4){0.f, 0.f, 0.f, 0.f};
    #pragma unroll 8
    for (int c = 0; c < 8; ++c) {
        int n = c * 16 + lr;
        #pragma unroll 4
        for (int t = 0; t < 4; ++t) {
            bf16x8 bv = *(bf16x8*)(ldsb + n * 256 + ((t * 64 + lg * 16) ^ ((n & 7) << 4)));
            acc[c] = __builtin_amdgcn_mfma_f32_16x16x32_bf16(a[t], bv, acc[c], 0, 0, 0);
        }
    }
    #pragma unroll 8
    for (int c = 0; c < 8; ++c) {
        int col = c * 16 + lr;
        float bc = b[col];
        #pragma unroll 4
        for (int r = 0; r < 4; ++r) {
            float v = acc[c][r] + bc;
            out[(size_t)(row0 + lg * 4 + r) * DD + col] = f2b(fmaxf(v, 0.f));
        }
    }
}

// ---------------------------------------------------------------------------
// S[p] = sum_n tanh(z_p[n] @ W_att + b_att) . q_att  via bf16 MFMA (z f32)
// ---------------------------------------------------------------------------
__global__ __launch_bounds__(256) void k_attn_mfma(
    const float* __restrict__ z0, const float* __restrict__ z1,
    const short* __restrict__ WT, const float* __restrict__ b,
    const float* __restrict__ q, float* __restrict__ S)
{
    __shared__ char ldsb[32768];
    __shared__ float red[4];
    const float* z = blockIdx.y ? z1 : z0;
    int tid = threadIdx.x;
    for (int i = tid; i < DD * DD / 8; i += 256) {
        int n = i >> 4, k8 = i & 15;
        int4 v = ((const int4*)WT)[i];
        *(int4*)(ldsb + n * 256 + ((k8 * 16) ^ ((n & 7) << 4))) = v;
    }
    __syncthreads();
    int wid = tid >> 6, l = tid & 63;
    int s = blockIdx.x * 4 + wid;
    float part = 0.f;
    if (s < NSTRIP) {
        int lr = l & 15, lg = l >> 4;
        int row0 = s * 16;
        const float4* ap = (const float4*)(z + (size_t)(row0 + lr) * DD + lg * 8);
        bf16x8 a[4];
        #pragma unroll 4
        for (int t = 0; t < 4; ++t) {
            float4 f0 = ap[8 * t], f1 = ap[8 * t + 1];
            a[t][0] = f2b(f0.x); a[t][1] = f2b(f0.y); a[t][2] = f2b(f0.z); a[t][3] = f2b(f0.w);
            a[t][4] = f2b(f1.x); a[t][5] = f2b(f1.y); a[t][6] = f2b(f1.z); a[t][7] = f2b(f1.w);
        }
        f32x4 acc[8];
        #pragma unroll 8
        for (int c = 0; c < 8; ++c) acc[c] = (f32x4){0.f, 0.f, 0.f, 0.f};
        #pragma unroll 8
        for (int c = 0; c < 8; ++c) {
            int n = c * 16 + lr;
            #pragma unroll 4
            for (int t = 0; t < 4; ++t) {
                bf16x8 bv = *(bf16x8*)(ldsb + n * 256 + ((t * 64 + lg * 16) ^ ((n & 7) << 4)));
                acc[c] = __builtin_amdgcn_mfma_f32_16x16x32_bf16(a[t], bv, acc[c], 0, 0, 0);
            }
        }
        #pragma unroll 8
        for (int c = 0; c < 8; ++c) {
            int col = c * 16 + lr;
            float bc = b[col], qc = q[col];
            #pragma unroll 4
            for (int r = 0; r < 4; ++r)
                part += tanhf(acc[c][r] + bc) * qc;
        }
    }
    for (int sh = 32; sh > 0; sh >>= 1)
        part += __shfl_down(part, sh);
    if (l == 0) red[wid] = part;
    __syncthreads();
    if (tid == 0)
        atomicAdd(&S[blockIdx.y], red[0] + red[1] + red[2] + red[3]);
}

// ---------------------------------------------------------------------------
// per-chunk partial histograms, LDS-atomic only, plain stores out.
// ---------------------------------------------------------------------------
__global__ __launch_bounds__(256) void k_hist(
    const int* __restrict__ s0, const int* __restrict__ d0,
    const int* __restrict__ s1, const int* __restrict__ d1,
    int* __restrict__ partial)
{
    __shared__ int hist[RSIZE];          // 50 KB
    int c = blockIdx.x, rg = blockIdx.y, a = blockIdx.z;
    const int* idx = (a == 0) ? s0 : (a == 1) ? d0 : (a == 2) ? s1 : d1;
    int lo = rg * RSIZE;
    for (int i = threadIdx.x; i < RSIZE; i += 256) hist[i] = 0;
    __syncthreads();
    int beg = c * CH, end = beg + CH;
    for (int i = beg + threadIdx.x; i < end; i += 256) {
        int v = idx[i] - lo;
        if ((unsigned)v < (unsigned)RSIZE) atomicAdd(&hist[v], 1);
    }
    __syncthreads();
    int* dst = partial + ((size_t)a * NCHUNK + c) * NN + lo;
    for (int i = threadIdx.x; i < RSIZE; i += 256) dst[i] = hist[i];
}

// ---------------------------------------------------------------------------
// reduce partials -> degree + norm; dst arrays get in-place chunk prefixes
// ---------------------------------------------------------------------------
__global__ __launch_bounds__(256) void k_reduce(
    int* __restrict__ partial,
    float* ns0, float* nd0, float* ns1, float* nd1,
    int* cdeg0, int* cdeg1)
{
    int n = blockIdx.x * 256 + threadIdx.x;
    int a = blockIdx.y;
    if (n >= NN) return;
    int run = 0;
    bool isdst = a & 1;
    for (int c = 0; c < NCHUNK; ++c) {
        size_t ix = ((size_t)a * NCHUNK + c) * NN + n;
        int t = partial[ix];
        if (isdst) partial[ix] = run;
        run += t;
    }
    float nv = rsqrtf((float)(run > 1 ? run : 1));
    if (a == 0) ns0[n] = nv;
    else if (a == 1) { nd0[n] = nv; cdeg0[n] = run; }
    else if (a == 2) ns1[n] = nv;
    else { nd1[n] = nv; cdeg1[n] = run; }
}

// ---------------------------------------------------------------------------
__global__ __launch_bounds__(256) void k_scan1(
    const int* __restrict__ cdeg0, const int* __restrict__ cdeg1,
    int* __restrict__ bsum)
{
    const int* dg = blockIdx.y ? cdeg1 : cdeg0;
    __shared__ int ws_[4];
    int tid = threadIdx.x;
    int n0 = blockIdx.x * 1024 + tid * 4;
    int s = 0;
    #pragma unroll
    for (int k = 0; k < 4; ++k) {
        int n = n0 + k;
        if (n < NN) s += dg[n];
    }
    for (int sh = 32; sh > 0; sh >>= 1) s += __shfl_down(s, sh);
    if ((tid & 63) == 0) ws_[tid >> 6] = s;
    __syncthreads();
    if (tid == 0)
        bsum[blockIdx.y * NSB + blockIdx.x] = ws_[0] + ws_[1] + ws_[2] + ws_[3];
}

__global__ __launch_bounds__(64) void k_scan2(
    const int* __restrict__ bsum, int* __restrict__ bbase,
    int* off0, int* off1)
{
    int p = threadIdx.x;
    if (p < 2) {
        int run = 0;
        for (int b = 0; b < NSB; ++b) {
            bbase[p * NSB + b] = run;
            run += bsum[p * NSB + b];
        }
        (p ? off1 : off0)[NN] = run;
    }
}

__global__ __launch_bounds__(256) void k_scan3(
    const int* __restrict__ cdeg0, const int* __restrict__ cdeg1,
    const int* __restrict__ bbase, int* off0, int* off1)
{
    const int* dg = blockIdx.y ? cdeg1 : cdeg0;
    int* off      = blockIdx.y ? off1  : off0;
    __shared__ int ts[256];
    int tid = threadIdx.x;
    int n0 = blockIdx.x * 1024 + tid * 4;
    int d0 = 0, d1 = 0, d2 = 0, d3 = 0;
    if (n0 + 0 < NN) d0 = dg[n0 + 0];
    if (n0 + 1 < NN) d1 = dg[n0 + 1];
    if (n0 + 2 < NN) d2 = dg[n0 + 2];
    if (n0 + 3 < NN) d3 = dg[n0 + 3];
    int tot = d0 + d1 + d2 + d3;
    ts[tid] = tot;
    __syncthreads();
    for (int s = 1; s < 256; s <<= 1) {
        int u = (tid >= s) ? ts[tid - s] : 0;
        __syncthreads();
        ts[tid] += u;
        __syncthreads();
    }
    int base = bbase[blockIdx.y * NSB + blockIdx.x] + ts[tid] - tot;
    if (n0 + 0 < NN) off[n0 + 0] = base;
    if (n0 + 1 < NN) off[n0 + 1] = base + d0;
    if (n0 + 2 < NN) off[n0 + 2] = base + d0 + d1;
    if (n0 + 3 < NN) off[n0 + 3] = base + d0 + d1 + d2;
}

// ---------------------------------------------------------------------------
// atomic-free CSR fill: slot = off[d] + chunk_prefix[c][d] + lds_rank
// ---------------------------------------------------------------------------
__global__ __launch_bounds__(256) void k_fill2(
    const int* __restrict__ src0, const int* __restrict__ dst0,
    const int* __restrict__ src1, const int* __restrict__ dst1,
    const int* __restrict__ partial,
    const int* __restrict__ off0, const int* __restrict__ off1,
    int* __restrict__ es0, int* __restrict__ es1)
{
    __shared__ int cur[RSIZE];           // 50 KB
    int c = blockIdx.x, rg = blockIdx.y, p = blockIdx.z;
    const int* src = p ? src1 : src0;
    const int* dst = p ? dst1 : dst0;
    const int* off = p ? off1 : off0;
    int* es        = p ? es1  : es0;
    const int* pfx = partial + ((size_t)(1 + 2 * p) * NCHUNK + c) * NN;
    int lo = rg * RSIZE;
    for (int i = threadIdx.x; i < RSIZE; i += 256) cur[i] = 0;
    __syncthreads();
    int beg = c * CH, end = beg + CH;
    for (int i = beg + threadIdx.x; i < end; i += 256) {
        int d = dst[i];
        int v = d - lo;
        if ((unsigned)v < (unsigned)RSIZE) {
            int s = src[i];
            int r = atomicAdd(&cur[v], 1);
            es[off[d] + pfx[d] + r] = s;
        }
    }
}

// ---------------------------------------------------------------------------
// merged APPNP step, 16 B/lane gather + XCD-aware path partition:
// flat grid 25000 blocks; xcd = bid & 7; path = xcd >> 2 (XCDs 0-3 -> path 0,
// XCDs 4-7 -> path 1) so each private L2 caches only ONE path's 12.8 MB.
// Wave = 4 groups x 16 lanes; group g handles edge e+g; lane reads uint4.
// ---------------------------------------------------------------------------
template<int OUTF32>
__global__ __launch_bounds__(256) void k_appnp3(
    const unsigned* __restrict__ xin0, const unsigned* __restrict__ xin1,
    void* __restrict__ xo0, void* __restrict__ xo1,
    const unsigned* __restrict__ h0,
    const int* __restrict__ off0, const int* __restrict__ es0,
    const float* __restrict__ ns0, const float* __restrict__ nd0,
    const int* __restrict__ off1, const int* __restrict__ es1,
    const float* __restrict__ ns1, const float* __restrict__ nd1)
{
    int bid = blockIdx.x;
    int xcd = bid & 7;
    int p = xcd >> 2;                         // path by XCD group
    int pblk = (bid >> 3) * 4 + (xcd & 3);    // 0..12499 within path
    const unsigned* xin = p ? xin1 : xin0;
    const int* off = p ? off1 : off0;
    const int* es  = p ? es1  : es0;
    const float* ns = p ? ns1 : ns0;
    const float* nd = p ? nd1 : nd0;
    int wid = pblk * 4 + (threadIdx.x >> 6);  // node id, < 50000 always
    int l = threadIdx.x & 63;
    int g = l >> 4, f = l & 15;
    int v = wid;
    int beg = off[v], end = off[v + 1];
    const uint4* xin4 = (const uint4*)xin;
    float acc[8];
    #pragma unroll
    for (int i = 0; i < 8; ++i) acc[i] = 0.f;
    for (int e = beg; e < end; e += 8) {
        int e0 = e + g, e1 = e + 4 + g;
        bool p0 = e0 < end, p1 = e1 < end;
        int u0 = p0 ? es[e0] : 0;
        int u1 = p1 ? es[e1] : 0;
        float s0 = p0 ? ns[u0] : 0.f;
        float s1 = p1 ? ns[u1] : 0.f;
        uint4 w0 = xin4[(size_t)u0 * 16 + f];
        uint4 w1 = xin4[(size_t)u1 * 16 + f];
        acc[0] = fmaf(b2f_lo(w0.x), s0, acc[0]);
        acc[1] = fmaf(b2f_hi(w0.x), s0, acc[1]);
        acc[2] = fmaf(b2f_lo(w0.y), s0, acc[2]);
        acc[3] = fmaf(b2f_hi(w0.y), s0, acc[3]);
        acc[4] = fmaf(b2f_lo(w0.z), s0, acc[4]);
        acc[5] = fmaf(b2f_hi(w0.z), s0, acc[5]);
        acc[6] = fmaf(b2f_lo(w0.w), s0, acc[6]);
        acc[7] = fmaf(b2f_hi(w0.w), s0, acc[7]);
        acc[0] = fmaf(b2f_lo(w1.x), s1, acc[0]);
        acc[1] = fmaf(b2f_hi(w1.x), s1, acc[1]);
        acc[2] = fmaf(b2f_lo(w1.y), s1, acc[2]);
        acc[3] = fmaf(b2f_hi(w1.y), s1, acc[3]);
        acc[4] = fmaf(b2f_lo(w1.z), s1, acc[4]);
        acc[5] = fmaf(b2f_hi(w1.z), s1, acc[5]);
        acc[6] = fmaf(b2f_lo(w1.w), s1, acc[6]);
        acc[7] = fmaf(b2f_hi(w1.w), s1, acc[7]);
    }
    #pragma unroll
    for (int i = 0; i < 8; ++i) {
        acc[i] += __shfl_xor(acc[i], 16);
        acc[i] += __shfl_xor(acc[i], 32);
    }
    if (g == 0) {
        float scale = 0.9f * nd[v];
        uint4 hw = ((const uint4*)h0)[(size_t)v * 16 + f];
        float r0 = fmaf(acc[0], scale, 0.1f * b2f_lo(hw.x));
        float r1 = fmaf(acc[1], scale, 0.1f * b2f_hi(hw.x));
        float r2 = fmaf(acc[2], scale, 0.1f * b2f_lo(hw.y));
        float r3 = fmaf(acc[3], scale, 0.1f * b2f_hi(hw.y));
        float r4 = fmaf(acc[4], scale, 0.1f * b2f_lo(hw.z));
        float r5 = fmaf(acc[5], scale, 0.1f * b2f_hi(hw.z));
        float r6 = fmaf(acc[6], scale, 0.1f * b2f_lo(hw.w));
        float r7 = fmaf(acc[7], scale, 0.1f * b2f_hi(hw.w));
        if (OUTF32) {
            float4* xo = (float4*)(p ? xo1 : xo0);
            xo[(size_t)v * 32 + f * 2]     = make_float4(r0, r1, r2, r3);
            xo[(size_t)v * 32 + f * 2 + 1] = make_float4(r4, r5, r6, r7);
        } else {
            uint4* xo = (uint4*)(p ? xo1 : xo0);
            uint4 ov;
            ov.x = (unsigned)f2b(r0) | ((unsigned)f2b(r1) << 16);
            ov.y = (unsigned)f2b(r2) | ((unsigned)f2b(r3) << 16);
            ov.z = (unsigned)f2b(r4) | ((unsigned)f2b(r5) << 16);
            ov.w = (unsigned)f2b(r6) | ((unsigned)f2b(r7) << 16);
            xo[(size_t)v * 16 + f] = ov;
        }
    }
}

// ---------------------------------------------------------------------------
// beta = softmax(S/N); out = beta0*z0 + beta1*z1
// ---------------------------------------------------------------------------
__global__ __launch_bounds__(256) void k_combine(
    const float* __restrict__ z0, const float* __restrict__ z1,
    const float* __restrict__ S, float* __restrict__ out)
{
    float w0 = S[0] * (1.0f / NN);
    float w1 = S[1] * (1.0f / NN);
    float m  = fmaxf(w0, w1);
    float e0 = expf(w0 - m), e1 = expf(w1 - m);
    float inv = 1.0f / (e0 + e1);
    float b0 = e0 * inv, b1 = e1 * inv;
    const float4* a = (const float4*)z0;
    const float4* c = (const float4*)z1;
    float4* o = (float4*)out;
    int i = blockIdx.x * 256 + threadIdx.x;
    int stride = gridDim.x * 256;
    for (; i < NN * DD / 4; i += stride) {
        float4 x = a[i], y = c[i];
        float4 r;
        r.x = b0 * x.x + b1 * y.x;
        r.y = b0 * x.y + b1 * y.y;
        r.z = b0 * x.z + b1 * y.z;
        r.w = b0 * x.w + b1 * y.w;
        o[i] = r;
    }
}

// ---------------------------------------------------------------------------
extern "C" void kernel_launch(void* const* d_in, const int* in_sizes, int n_in,
                              void* d_out, int out_size, void* d_ws, size_t ws_size,
                              hipStream_t stream)
{
    const float* h     = (const float*)d_in[0];
    const int*   src0  = (const int*)d_in[1];
    const int*   dst0  = (const int*)d_in[2];
    const int*   src1  = (const int*)d_in[3];
    const int*   dst1  = (const int*)d_in[4];
    const float* W_h   = (const float*)d_in[5];
    const float* b_h   = (const float*)d_in[6];
    const float* W_att = (const float*)d_in[7];
    const float* b_att = (const float*)d_in[8];
    const float* q_att = (const float*)d_in[9];
    float* out = (float*)d_out;

    char* ws = (char*)d_ws;
    size_t o = 0;
    auto alloc = [&](size_t bytes) -> void* {
        void* p = ws + o;
        o += (bytes + 255) & ~(size_t)255;
        return p;
    };
    const size_t ND  = (size_t)NN * DD * sizeof(float);
    const size_t NDb = (size_t)NN * DD * sizeof(short);
    unsigned short* h1b = (unsigned short*)alloc(NDb);           // bf16 h1
    int*   partial = (int*)alloc((size_t)4 * NCHUNK * NN * sizeof(int));
    // A0/A1 (bf16 step-1 outputs) alias partial — dead after k_fill2
    unsigned* A0 = (unsigned*)partial;
    unsigned* A1 = A0 + (size_t)NN * DD / 2;
    float* z0 = (float*)alloc(ND);
    float* z1 = (float*)alloc(ND);
    unsigned* B0 = (unsigned*)alloc(NDb);
    unsigned* B1 = (unsigned*)alloc(NDb);
    float* ns0 = (float*)alloc(NN * 4);
    float* nd0 = (float*)alloc(NN * 4);
    float* ns1 = (float*)alloc(NN * 4);
    float* nd1 = (float*)alloc(NN * 4);
    int* cdeg0 = (int*)alloc(NN * 4);
    int* cdeg1 = (int*)alloc(NN * 4);
    int* off0 = (int*)alloc((NN + 1) * 4);
    int* off1 = (int*)alloc((NN + 1) * 4);
    int* es0  = (int*)alloc(EE * 4);
    int* es1  = (int*)alloc(EE * 4);
    int* bsum  = (int*)alloc(2 * NSB * 4);
    int* bbase = (int*)alloc(2 * NSB * 4);
    short* WTh = (short*)alloc(DD * DD * 2);
    short* WTa = (short*)alloc(DD * DD * 2);
    float* S   = (float*)alloc(256);
    hipMemsetAsync(S, 0, 256, stream);

    // 0. transpose+convert weights to bf16
    k_prep<<<2, 256, 0, stream>>>(W_h, W_att, WTh, WTa);
    // 1. h1 = relu(h @ W_h + b_h)  (MFMA, bf16 out)
    k_linear_mfma<<<(NSTRIP + 3) / 4, 256, 0, stream>>>(h, WTh, b_h, h1b);
    // 2. per-chunk histograms
    k_hist<<<dim3(NCHUNK, NRANGE, 4), 256, 0, stream>>>(src0, dst0, src1, dst1, partial);
    // 3. reduce -> degrees/norms + chunk prefixes
    k_reduce<<<dim3((NN + 255) / 256, 4), 256, 0, stream>>>(
        partial, ns0, nd0, ns1, nd1, cdeg0, cdeg1);
    // 4. CSR offsets: 3-pass scan
    k_scan1<<<dim3(NSB, 2), 256, 0, stream>>>(cdeg0, cdeg1, bsum);
    k_scan2<<<1, 64, 0, stream>>>(bsum, bbase, off0, off1);
    k_scan3<<<dim3(NSB, 2), 256, 0, stream>>>(cdeg0, cdeg1, bbase, off0, off1);
    // 5. atomic-free CSR fill
    k_fill2<<<dim3(NCHUNK, NRANGE, 2), 256, 0, stream>>>(
        src0, dst0, src1, dst1, partial, off0, off1, es0, es1);
    // 6. APPNP: 3 merged steps, XCD-partitioned flat grid (25000 blocks)
    const unsigned* h1u = (const unsigned*)h1b;
    const int agrid = 2 * ((NN + 3) / 4);     // 25000
    k_appnp3<0><<<agrid, 256, 0, stream>>>(
        h1u, h1u, A0, A1, h1u,
        off0, es0, ns0, nd0, off1, es1, ns1, nd1);
    k_appnp3<0><<<agrid, 256, 0, stream>>>(
        A0, A1, B0, B1, h1u,
        off0, es0, ns0, nd0, off1, es1, ns1, nd1);
    k_appnp3<1><<<agrid, 256, 0, stream>>>(
        B0, B1, z0, z1, h1u,
        off0, es0, ns0, nd0, off1, es1, ns1, nd1);
    // 7. semantic attention scores (MFMA)
    k_attn_mfma<<<dim3((NSTRIP + 3) / 4, 2), 256, 0, stream>>>(
        z0, z1, WTa, b_att, q_att, S);
    // 8. softmax + weighted combine
    k_combine<<<2048, 256, 0, stream>>>(z0, z1, S, out);
    (void)in_sizes; (void)n_in; (void)out_size; (void)ws_size;
}

// Round 11
// 430.433 us; speedup vs baseline: 3.1402x; 1.0736x over previous
//
#include <hip/hip_runtime.h>

#define NN 50000
#define EE 800000
#define DD 128
#define NCHUNK 32
#define CH (EE / NCHUNK)        // 25000
#define NRANGE 2
#define RSIZE (NN / NRANGE)     // 25000
#define NSB 49                  // ceil(NN/1024)
#define NSTRIP (NN / 16)        // 3125 (exact)

typedef __attribute__((ext_vector_type(8))) short bf16x8;
typedef __attribute__((ext_vector_type(4))) float f32x4;

// f32 -> bf16 bits, round-to-nearest-even
__device__ __forceinline__ unsigned short f2b(float x) {
    unsigned u = __float_as_uint(x);
    unsigned r = (u + 0x7fffu + ((u >> 16) & 1u)) >> 16;
    return (unsigned short)r;
}
__device__ __forceinline__ float b2f_lo(unsigned w) {
    return __uint_as_float((w & 0xffffu) << 16);
}
__device__ __forceinline__ float b2f_hi(unsigned w) {
    return __uint_as_float(w & 0xffff0000u);
}

// ---------------------------------------------------------------------------
// prep: WT[n][k] = bf16(W[k][n]) for W_h (block 0) and W_att (block 1)
// ---------------------------------------------------------------------------
__global__ __launch_bounds__(256) void k_prep(
    const float* __restrict__ Wh, const float* __restrict__ Wa,
    short* __restrict__ WTh, short* __restrict__ WTa)
{
    const float* W = blockIdx.x ? Wa : Wh;
    short* WT      = blockIdx.x ? WTa : WTh;
    for (int i = threadIdx.x; i < DD * DD; i += 256) {
        int n = i >> 7, k = i & 127;
        WT[i] = (short)f2b(W[k * DD + n]);
    }
}

// ---------------------------------------------------------------------------
// h1 = relu(h @ W + b) via bf16 MFMA -> bf16 output (gather payload format)
// ---------------------------------------------------------------------------
__global__ __launch_bounds__(256) void k_linear_mfma(
    const float* __restrict__ h, const short* __restrict__ WT,
    const float* __restrict__ b, unsigned short* __restrict__ out)
{
    __shared__ char ldsb[32768];
    int tid = threadIdx.x;
    for (int i = tid; i < DD * DD / 8; i += 256) {
        int n = i >> 4, k8 = i & 15;
        int4 v = ((const int4*)WT)[i];
        *(int4*)(ldsb + n * 256 + ((k8 * 16) ^ ((n & 7) << 4))) = v;
    }
    __syncthreads();
    int wid = tid >> 6, l = tid & 63;
    int s = blockIdx.x * 4 + wid;
    if (s >= NSTRIP) return;
    int lr = l & 15, lg = l >> 4;
    int row0 = s * 16;
    const float4* ap = (const float4*)(h + (size_t)(row0 + lr) * DD + lg * 8);
    bf16x8 a[4];
    #pragma unroll 4
    for (int t = 0; t < 4; ++t) {
        float4 f0 = ap[8 * t], f1 = ap[8 * t + 1];
        a[t][0] = f2b(f0.x); a[t][1] = f2b(f0.y); a[t][2] = f2b(f0.z); a[t][3] = f2b(f0.w);
        a[t][4] = f2b(f1.x); a[t][5] = f2b(f1.y); a[t][6] = f2b(f1.z); a[t][7] = f2b(f1.w);
    }
    f32x4 acc[8];
    #pragma unroll 8
    for (int c = 0; c < 8; ++c) acc[c] = (f32x4){0.f, 0.f, 0.f, 0.f};
    #pragma unroll 8
    for (int c = 0; c < 8; ++c) {
        int n = c * 16 + lr;
        #pragma unroll 4
        for (int t = 0; t < 4; ++t) {
            bf16x8 bv = *(bf16x8*)(ldsb + n * 256 + ((t * 64 + lg * 16) ^ ((n & 7) << 4)));
            acc[c] = __builtin_amdgcn_mfma_f32_16x16x32_bf16(a[t], bv, acc[c], 0, 0, 0);
        }
    }
    #pragma unroll 8
    for (int c = 0; c < 8; ++c) {
        int col = c * 16 + lr;
        float bc = b[col];
        #pragma unroll 4
        for (int r = 0; r < 4; ++r) {
            float v = acc[c][r] + bc;
            out[(size_t)(row0 + lg * 4 + r) * DD + col] = f2b(fmaxf(v, 0.f));
        }
    }
}

// ---------------------------------------------------------------------------
// S[p] = sum_n tanh(z_p[n] @ W_att + b_att) . q_att  via bf16 MFMA (z f32)
// ---------------------------------------------------------------------------
__global__ __launch_bounds__(256) void k_attn_mfma(
    const float* __restrict__ z0, const float* __restrict__ z1,
    const short* __restrict__ WT, const float* __restrict__ b,
    const float* __restrict__ q, float* __restrict__ S)
{
    __shared__ char ldsb[32768];
    __shared__ float red[4];
    const float* z = blockIdx.y ? z1 : z0;
    int tid = threadIdx.x;
    for (int i = tid; i < DD * DD / 8; i += 256) {
        int n = i >> 4, k8 = i & 15;
        int4 v = ((const int4*)WT)[i];
        *(int4*)(ldsb + n * 256 + ((k8 * 16) ^ ((n & 7) << 4))) = v;
    }
    __syncthreads();
    int wid = tid >> 6, l = tid & 63;
    int s = blockIdx.x * 4 + wid;
    float part = 0.f;
    if (s < NSTRIP) {
        int lr = l & 15, lg = l >> 4;
        int row0 = s * 16;
        const float4* ap = (const float4*)(z + (size_t)(row0 + lr) * DD + lg * 8);
        bf16x8 a[4];
        #pragma unroll 4
        for (int t = 0; t < 4; ++t) {
            float4 f0 = ap[8 * t], f1 = ap[8 * t + 1];
            a[t][0] = f2b(f0.x); a[t][1] = f2b(f0.y); a[t][2] = f2b(f0.z); a[t][3] = f2b(f0.w);
            a[t][4] = f2b(f1.x); a[t][5] = f2b(f1.y); a[t][6] = f2b(f1.z); a[t][7] = f2b(f1.w);
        }
        f32x4 acc[8];
        #pragma unroll 8
        for (int c = 0; c < 8; ++c) acc[c] = (f32x4){0.f, 0.f, 0.f, 0.f};
        #pragma unroll 8
        for (int c = 0; c < 8; ++c) {
            int n = c * 16 + lr;
            #pragma unroll 4
            for (int t = 0; t < 4; ++t) {
                bf16x8 bv = *(bf16x8*)(ldsb + n * 256 + ((t * 64 + lg * 16) ^ ((n & 7) << 4)));
                acc[c] = __builtin_amdgcn_mfma_f32_16x16x32_bf16(a[t], bv, acc[c], 0, 0, 0);
            }
        }
        #pragma unroll 8
        for (int c = 0; c < 8; ++c) {
            int col = c * 16 + lr;
            float bc = b[col], qc = q[col];
            #pragma unroll 4
            for (int r = 0; r < 4; ++r)
                part += tanhf(acc[c][r] + bc) * qc;
        }
    }
    for (int sh = 32; sh > 0; sh >>= 1)
        part += __shfl_down(part, sh);
    if (l == 0) red[wid] = part;
    __syncthreads();
    if (tid == 0)
        atomicAdd(&S[blockIdx.y], red[0] + red[1] + red[2] + red[3]);
}

// ---------------------------------------------------------------------------
// per-chunk partial histograms: packed-uint LDS counters (2 nodes/word),
// ushort partial out.  grid = (NCHUNK, NRANGE, 4 arrays), 512 threads.
// ---------------------------------------------------------------------------
__global__ __launch_bounds__(512) void k_hist(
    const int* __restrict__ s0, const int* __restrict__ d0,
    const int* __restrict__ s1, const int* __restrict__ d1,
    unsigned short* __restrict__ partial)
{
    __shared__ unsigned h2[RSIZE / 2];   // 50 KB
    int c = blockIdx.x, rg = blockIdx.y, a = blockIdx.z;
    const int* idx = (a == 0) ? s0 : (a == 1) ? d0 : (a == 2) ? s1 : d1;
    int lo = rg * RSIZE;
    for (int i = threadIdx.x; i < RSIZE / 2; i += 512) h2[i] = 0;
    __syncthreads();
    int beg = c * CH, end = beg + CH;
    for (int i = beg + threadIdx.x; i < end; i += 512) {
        int v = idx[i] - lo;
        if ((unsigned)v < (unsigned)RSIZE)
            atomicAdd(&h2[v >> 1], (v & 1) ? 0x10000u : 1u);
    }
    __syncthreads();
    // lo is even -> uint-aligned; packed uint == two little-endian ushorts
    unsigned* dst = (unsigned*)(partial + ((size_t)a * NCHUNK + c) * NN + lo);
    for (int i = threadIdx.x; i < RSIZE / 2; i += 512) dst[i] = h2[i];
}

// ---------------------------------------------------------------------------
// reduce partials -> degree + norm; dst arrays get in-place chunk prefixes
// ---------------------------------------------------------------------------
__global__ __launch_bounds__(256) void k_reduce(
    unsigned short* __restrict__ partial,
    float* ns0, float* nd0, float* ns1, float* nd1,
    int* cdeg0, int* cdeg1)
{
    int n = blockIdx.x * 256 + threadIdx.x;
    int a = blockIdx.y;
    if (n >= NN) return;
    int run = 0;
    bool isdst = a & 1;
    for (int c = 0; c < NCHUNK; ++c) {
        size_t ix = ((size_t)a * NCHUNK + c) * NN + n;
        int t = partial[ix];
        if (isdst) partial[ix] = (unsigned short)run;
        run += t;
    }
    float nv = rsqrtf((float)(run > 1 ? run : 1));
    if (a == 0) ns0[n] = nv;
    else if (a == 1) { nd0[n] = nv; cdeg0[n] = run; }
    else if (a == 2) ns1[n] = nv;
    else { nd1[n] = nv; cdeg1[n] = run; }
}

// ---------------------------------------------------------------------------
__global__ __launch_bounds__(256) void k_scan1(
    const int* __restrict__ cdeg0, const int* __restrict__ cdeg1,
    int* __restrict__ bsum)
{
    const int* dg = blockIdx.y ? cdeg1 : cdeg0;
    __shared__ int ws_[4];
    int tid = threadIdx.x;
    int n0 = blockIdx.x * 1024 + tid * 4;
    int s = 0;
    #pragma unroll
    for (int k = 0; k < 4; ++k) {
        int n = n0 + k;
        if (n < NN) s += dg[n];
    }
    for (int sh = 32; sh > 0; sh >>= 1) s += __shfl_down(s, sh);
    if ((tid & 63) == 0) ws_[tid >> 6] = s;
    __syncthreads();
    if (tid == 0)
        bsum[blockIdx.y * NSB + blockIdx.x] = ws_[0] + ws_[1] + ws_[2] + ws_[3];
}

__global__ __launch_bounds__(64) void k_scan2(
    const int* __restrict__ bsum, int* __restrict__ bbase,
    int* off0, int* off1)
{
    int p = threadIdx.x;
    if (p < 2) {
        int run = 0;
        for (int b = 0; b < NSB; ++b) {
            bbase[p * NSB + b] = run;
            run += bsum[p * NSB + b];
        }
        (p ? off1 : off0)[NN] = run;
    }
}

__global__ __launch_bounds__(256) void k_scan3(
    const int* __restrict__ cdeg0, const int* __restrict__ cdeg1,
    const int* __restrict__ bbase, int* off0, int* off1)
{
    const int* dg = blockIdx.y ? cdeg1 : cdeg0;
    int* off      = blockIdx.y ? off1  : off0;
    __shared__ int ts[256];
    int tid = threadIdx.x;
    int n0 = blockIdx.x * 1024 + tid * 4;
    int d0 = 0, d1 = 0, d2 = 0, d3 = 0;
    if (n0 + 0 < NN) d0 = dg[n0 + 0];
    if (n0 + 1 < NN) d1 = dg[n0 + 1];
    if (n0 + 2 < NN) d2 = dg[n0 + 2];
    if (n0 + 3 < NN) d3 = dg[n0 + 3];
    int tot = d0 + d1 + d2 + d3;
    ts[tid] = tot;
    __syncthreads();
    for (int s = 1; s < 256; s <<= 1) {
        int u = (tid >= s) ? ts[tid - s] : 0;
        __syncthreads();
        ts[tid] += u;
        __syncthreads();
    }
    int base = bbase[blockIdx.y * NSB + blockIdx.x] + ts[tid] - tot;
    if (n0 + 0 < NN) off[n0 + 0] = base;
    if (n0 + 1 < NN) off[n0 + 1] = base + d0;
    if (n0 + 2 < NN) off[n0 + 2] = base + d0 + d1;
    if (n0 + 3 < NN) off[n0 + 3] = base + d0 + d1 + d2;
}

// ---------------------------------------------------------------------------
// atomic-free CSR fill (packed-uint cur counters, ushort es):
// slot = off[d] + chunk_prefix[c][d] + lds_rank.  512 threads.
// ---------------------------------------------------------------------------
__global__ __launch_bounds__(512) void k_fill2(
    const int* __restrict__ src0, const int* __restrict__ dst0,
    const int* __restrict__ src1, const int* __restrict__ dst1,
    const unsigned short* __restrict__ partial,
    const int* __restrict__ off0, const int* __restrict__ off1,
    unsigned short* __restrict__ es0, unsigned short* __restrict__ es1)
{
    __shared__ unsigned cur2[RSIZE / 2]; // 50 KB
    int c = blockIdx.x, rg = blockIdx.y, p = blockIdx.z;
    const int* src = p ? src1 : src0;
    const int* dst = p ? dst1 : dst0;
    const int* off = p ? off1 : off0;
    unsigned short* es = p ? es1 : es0;
    const unsigned short* pfx = partial + ((size_t)(1 + 2 * p) * NCHUNK + c) * NN;
    int lo = rg * RSIZE;
    for (int i = threadIdx.x; i < RSIZE / 2; i += 512) cur2[i] = 0;
    __syncthreads();
    int beg = c * CH, end = beg + CH;
    for (int i = beg + threadIdx.x; i < end; i += 512) {
        int d = dst[i];
        int v = d - lo;
        if ((unsigned)v < (unsigned)RSIZE) {
            int s = src[i];
            unsigned old = atomicAdd(&cur2[v >> 1], (v & 1) ? 0x10000u : 1u);
            int r = (v & 1) ? (int)(old >> 16) : (int)(old & 0xffffu);
            es[off[d] + (int)pfx[d] + r] = (unsigned short)s;
        }
    }
}

// ---------------------------------------------------------------------------
// merged APPNP step, 16 B/lane gather + XCD-aware path partition (ushort es).
// ---------------------------------------------------------------------------
template<int OUTF32>
__global__ __launch_bounds__(256) void k_appnp3(
    const unsigned* __restrict__ xin0, const unsigned* __restrict__ xin1,
    void* __restrict__ xo0, void* __restrict__ xo1,
    const unsigned* __restrict__ h0,
    const int* __restrict__ off0, const unsigned short* __restrict__ es0,
    const float* __restrict__ ns0, const float* __restrict__ nd0,
    const int* __restrict__ off1, const unsigned short* __restrict__ es1,
    const float* __restrict__ ns1, const float* __restrict__ nd1)
{
    int bid = blockIdx.x;
    int xcd = bid & 7;
    int p = xcd >> 2;                         // path by XCD group
    int pblk = (bid >> 3) * 4 + (xcd & 3);    // 0..12499 within path
    const unsigned* xin = p ? xin1 : xin0;
    const int* off = p ? off1 : off0;
    const unsigned short* es = p ? es1 : es0;
    const float* ns = p ? ns1 : ns0;
    const float* nd = p ? nd1 : nd0;
    int wid = pblk * 4 + (threadIdx.x >> 6);  // node id, < 50000 always
    int l = threadIdx.x & 63;
    int g = l >> 4, f = l & 15;
    int v = wid;
    int beg = off[v], end = off[v + 1];
    const uint4* xin4 = (const uint4*)xin;
    float acc[8];
    #pragma unroll
    for (int i = 0; i < 8; ++i) acc[i] = 0.f;
    for (int e = beg; e < end; e += 8) {
        int e0 = e + g, e1 = e + 4 + g;
        bool p0 = e0 < end, p1 = e1 < end;
        int u0 = p0 ? (int)es[e0] : 0;
        int u1 = p1 ? (int)es[e1] : 0;
        float s0 = p0 ? ns[u0] : 0.f;
        float s1 = p1 ? ns[u1] : 0.f;
        uint4 w0 = xin4[(size_t)u0 * 16 + f];
        uint4 w1 = xin4[(size_t)u1 * 16 + f];
        acc[0] = fmaf(b2f_lo(w0.x), s0, acc[0]);
        acc[1] = fmaf(b2f_hi(w0.x), s0, acc[1]);
        acc[2] = fmaf(b2f_lo(w0.y), s0, acc[2]);
        acc[3] = fmaf(b2f_hi(w0.y), s0, acc[3]);
        acc[4] = fmaf(b2f_lo(w0.z), s0, acc[4]);
        acc[5] = fmaf(b2f_hi(w0.z), s0, acc[5]);
        acc[6] = fmaf(b2f_lo(w0.w), s0, acc[6]);
        acc[7] = fmaf(b2f_hi(w0.w), s0, acc[7]);
        acc[0] = fmaf(b2f_lo(w1.x), s1, acc[0]);
        acc[1] = fmaf(b2f_hi(w1.x), s1, acc[1]);
        acc[2] = fmaf(b2f_lo(w1.y), s1, acc[2]);
        acc[3] = fmaf(b2f_hi(w1.y), s1, acc[3]);
        acc[4] = fmaf(b2f_lo(w1.z), s1, acc[4]);
        acc[5] = fmaf(b2f_hi(w1.z), s1, acc[5]);
        acc[6] = fmaf(b2f_lo(w1.w), s1, acc[6]);
        acc[7] = fmaf(b2f_hi(w1.w), s1, acc[7]);
    }
    #pragma unroll
    for (int i = 0; i < 8; ++i) {
        acc[i] += __shfl_xor(acc[i], 16);
        acc[i] += __shfl_xor(acc[i], 32);
    }
    if (g == 0) {
        float scale = 0.9f * nd[v];
        uint4 hw = ((const uint4*)h0)[(size_t)v * 16 + f];
        float r0 = fmaf(acc[0], scale, 0.1f * b2f_lo(hw.x));
        float r1 = fmaf(acc[1], scale, 0.1f * b2f_hi(hw.x));
        float r2 = fmaf(acc[2], scale, 0.1f * b2f_lo(hw.y));
        float r3 = fmaf(acc[3], scale, 0.1f * b2f_hi(hw.y));
        float r4 = fmaf(acc[4], scale, 0.1f * b2f_lo(hw.z));
        float r5 = fmaf(acc[5], scale, 0.1f * b2f_hi(hw.z));
        float r6 = fmaf(acc[6], scale, 0.1f * b2f_lo(hw.w));
        float r7 = fmaf(acc[7], scale, 0.1f * b2f_hi(hw.w));
        if (OUTF32) {
            float4* xo = (float4*)(p ? xo1 : xo0);
            xo[(size_t)v * 32 + f * 2]     = make_float4(r0, r1, r2, r3);
            xo[(size_t)v * 32 + f * 2 + 1] = make_float4(r4, r5, r6, r7);
        } else {
            uint4* xo = (uint4*)(p ? xo1 : xo0);
            uint4 ov;
            ov.x = (unsigned)f2b(r0) | ((unsigned)f2b(r1) << 16);
            ov.y = (unsigned)f2b(r2) | ((unsigned)f2b(r3) << 16);
            ov.z = (unsigned)f2b(r4) | ((unsigned)f2b(r5) << 16);
            ov.w = (unsigned)f2b(r6) | ((unsigned)f2b(r7) << 16);
            xo[(size_t)v * 16 + f] = ov;
        }
    }
}

// ---------------------------------------------------------------------------
// beta = softmax(S/N); out = beta0*z0 + beta1*z1
// ---------------------------------------------------------------------------
__global__ __launch_bounds__(256) void k_combine(
    const float* __restrict__ z0, const float* __restrict__ z1,
    const float* __restrict__ S, float* __restrict__ out)
{
    float w0 = S[0] * (1.0f / NN);
    float w1 = S[1] * (1.0f / NN);
    float m  = fmaxf(w0, w1);
    float e0 = expf(w0 - m), e1 = expf(w1 - m);
    float inv = 1.0f / (e0 + e1);
    float b0 = e0 * inv, b1 = e1 * inv;
    const float4* a = (const float4*)z0;
    const float4* c = (const float4*)z1;
    float4* o = (float4*)out;
    int i = blockIdx.x * 256 + threadIdx.x;
    int stride = gridDim.x * 256;
    for (; i < NN * DD / 4; i += stride) {
        float4 x = a[i], y = c[i];
        float4 r;
        r.x = b0 * x.x + b1 * y.x;
        r.y = b0 * x.y + b1 * y.y;
        r.z = b0 * x.z + b1 * y.z;
        r.w = b0 * x.w + b1 * y.w;
        o[i] = r;
    }
}

// ---------------------------------------------------------------------------
extern "C" void kernel_launch(void* const* d_in, const int* in_sizes, int n_in,
                              void* d_out, int out_size, void* d_ws, size_t ws_size,
                              hipStream_t stream)
{
    const float* h     = (const float*)d_in[0];
    const int*   src0  = (const int*)d_in[1];
    const int*   dst0  = (const int*)d_in[2];
    const int*   src1  = (const int*)d_in[3];
    const int*   dst1  = (const int*)d_in[4];
    const float* W_h   = (const float*)d_in[5];
    const float* b_h   = (const float*)d_in[6];
    const float* W_att = (const float*)d_in[7];
    const float* b_att = (const float*)d_in[8];
    const float* q_att = (const float*)d_in[9];
    float* out = (float*)d_out;

    char* ws = (char*)d_ws;
    size_t o = 0;
    auto alloc = [&](size_t bytes) -> void* {
        void* p = ws + o;
        o += (bytes + 255) & ~(size_t)255;
        return p;
    };
    const size_t ND  = (size_t)NN * DD * sizeof(float);
    const size_t NDb = (size_t)NN * DD * sizeof(short);
    unsigned short* h1b = (unsigned short*)alloc(NDb);           // bf16 h1
    unsigned short* partial =
        (unsigned short*)alloc((size_t)4 * NCHUNK * NN * sizeof(short));
    unsigned* A0 = (unsigned*)alloc(NDb);
    unsigned* A1 = (unsigned*)alloc(NDb);
    unsigned* B0 = (unsigned*)alloc(NDb);
    unsigned* B1 = (unsigned*)alloc(NDb);
    float* z0 = (float*)alloc(ND);
    float* z1 = (float*)alloc(ND);
    float* ns0 = (float*)alloc(NN * 4);
    float* nd0 = (float*)alloc(NN * 4);
    float* ns1 = (float*)alloc(NN * 4);
    float* nd1 = (float*)alloc(NN * 4);
    int* cdeg0 = (int*)alloc(NN * 4);
    int* cdeg1 = (int*)alloc(NN * 4);
    int* off0 = (int*)alloc((NN + 1) * 4);
    int* off1 = (int*)alloc((NN + 1) * 4);
    unsigned short* es0 = (unsigned short*)alloc(EE * 2);
    unsigned short* es1 = (unsigned short*)alloc(EE * 2);
    int* bsum  = (int*)alloc(2 * NSB * 4);
    int* bbase = (int*)alloc(2 * NSB * 4);
    short* WTh = (short*)alloc(DD * DD * 2);
    short* WTa = (short*)alloc(DD * DD * 2);
    float* S   = (float*)alloc(256);
    hipMemsetAsync(S, 0, 256, stream);

    // 0. transpose+convert weights to bf16
    k_prep<<<2, 256, 0, stream>>>(W_h, W_att, WTh, WTa);
    // 1. h1 = relu(h @ W_h + b_h)  (MFMA, bf16 out)
    k_linear_mfma<<<(NSTRIP + 3) / 4, 256, 0, stream>>>(h, WTh, b_h, h1b);
    // 2. per-chunk histograms (2 ranges, packed counters, ushort partial)
    k_hist<<<dim3(NCHUNK, NRANGE, 4), 512, 0, stream>>>(src0, dst0, src1, dst1, partial);
    // 3. reduce -> degrees/norms + chunk prefixes
    k_reduce<<<dim3((NN + 255) / 256, 4), 256, 0, stream>>>(
        partial, ns0, nd0, ns1, nd1, cdeg0, cdeg1);
    // 4. CSR offsets: 3-pass scan
    k_scan1<<<dim3(NSB, 2), 256, 0, stream>>>(cdeg0, cdeg1, bsum);
    k_scan2<<<1, 64, 0, stream>>>(bsum, bbase, off0, off1);
    k_scan3<<<dim3(NSB, 2), 256, 0, stream>>>(cdeg0, cdeg1, bbase, off0, off1);
    // 5. atomic-free CSR fill (ushort es)
    k_fill2<<<dim3(NCHUNK, NRANGE, 2), 512, 0, stream>>>(
        src0, dst0, src1, dst1, partial, off0, off1, es0, es1);
    // 6. APPNP: 3 merged steps, XCD-partitioned flat grid (25000 blocks)
    const unsigned* h1u = (const unsigned*)h1b;
    const int agrid = 2 * ((NN + 3) / 4);     // 25000
    k_appnp3<0><<<agrid, 256, 0, stream>>>(
        h1u, h1u, A0, A1, h1u,
        off0, es0, ns0, nd0, off1, es1, ns1, nd1);
    k_appnp3<0><<<agrid, 256, 0, stream>>>(
        A0, A1, B0, B1, h1u,
        off0, es0, ns0, nd0, off1, es1, ns1, nd1);
    k_appnp3<1><<<agrid, 256, 0, stream>>>(
        B0, B1, z0, z1, h1u,
        off0, es0, ns0, nd0, off1, es1, ns1, nd1);
    // 7. semantic attention scores (MFMA)
    k_attn_mfma<<<dim3((NSTRIP + 3) / 4, 2), 256, 0, stream>>>(
        z0, z1, WTa, b_att, q_att, S);
    // 8. softmax + weighted combine
    k_combine<<<2048, 256, 0, stream>>>(z0, z1, S, out);
    (void)in_sizes; (void)n_in; (void)out_size; (void)ws_size;
}

// Round 13
// 427.113 us; speedup vs baseline: 3.1646x; 1.0078x over previous
//
#include <hip/hip_runtime.h>

#define NN 50000
#define EE 800000
#define DD 128
#define NCHUNK 32
#define CH (EE / NCHUNK)        // 25000
#define NRANGE 2
#define RSIZE (NN / NRANGE)     // 25000
#define NSB 49                  // ceil(NN/1024)
#define NSTRIP (NN / 16)        // 3125 (exact)

typedef __attribute__((ext_vector_type(8))) short bf16x8;
typedef __attribute__((ext_vector_type(4))) float f32x4;

// f32 -> bf16 bits, round-to-nearest-even
__device__ __forceinline__ unsigned short f2b(float x) {
    unsigned u = __float_as_uint(x);
    unsigned r = (u + 0x7fffu + ((u >> 16) & 1u)) >> 16;
    return (unsigned short)r;
}
__device__ __forceinline__ float b2f_lo(unsigned w) {
    return __uint_as_float((w & 0xffffu) << 16);
}
__device__ __forceinline__ float b2f_hi(unsigned w) {
    return __uint_as_float(w & 0xffff0000u);
}

// ---------------------------------------------------------------------------
// prep: WT[n][k] = bf16(W[k][n]) for W_h (block 0) and W_att (block 1)
// ---------------------------------------------------------------------------
__global__ __launch_bounds__(256) void k_prep(
    const float* __restrict__ Wh, const float* __restrict__ Wa,
    short* __restrict__ WTh, short* __restrict__ WTa)
{
    const float* W = blockIdx.x ? Wa : Wh;
    short* WT      = blockIdx.x ? WTa : WTh;
    for (int i = threadIdx.x; i < DD * DD; i += 256) {
        int n = i >> 7, k = i & 127;
        WT[i] = (short)f2b(W[k * DD + n]);
    }
}

// ---------------------------------------------------------------------------
// h1 = relu(h @ W + b) via bf16 MFMA -> bf16 output (gather payload format)
// ---------------------------------------------------------------------------
__global__ __launch_bounds__(256) void k_linear_mfma(
    const float* __restrict__ h, const short* __restrict__ WT,
    const float* __restrict__ b, unsigned short* __restrict__ out)
{
    __shared__ char ldsb[32768];
    int tid = threadIdx.x;
    for (int i = tid; i < DD * DD / 8; i += 256) {
        int n = i >> 4, k8 = i & 15;
        int4 v = ((const int4*)WT)[i];
        *(int4*)(ldsb + n * 256 + ((k8 * 16) ^ ((n & 7) << 4))) = v;
    }
    __syncthreads();
    int wid = tid >> 6, l = tid & 63;
    int s = blockIdx.x * 4 + wid;
    if (s >= NSTRIP) return;
    int lr = l & 15, lg = l >> 4;
    int row0 = s * 16;
    const float4* ap = (const float4*)(h + (size_t)(row0 + lr) * DD + lg * 8);
    bf16x8 a[4];
    #pragma unroll 4
    for (int t = 0; t < 4; ++t) {
        float4 f0 = ap[8 * t], f1 = ap[8 * t + 1];
        a[t][0] = f2b(f0.x); a[t][1] = f2b(f0.y); a[t][2] = f2b(f0.z); a[t][3] = f2b(f0.w);
        a[t][4] = f2b(f1.x); a[t][5] = f2b(f1.y); a[t][6] = f2b(f1.z); a[t][7] = f2b(f1.w);
    }
    f32x4 acc[8];
    #pragma unroll 8
    for (int c = 0; c < 8; ++c) acc[c] = (f32x4){0.f, 0.f, 0.f, 0.f};
    #pragma unroll 8
    for (int c = 0; c < 8; ++c) {
        int n = c * 16 + lr;
        #pragma unroll 4
        for (int t = 0; t < 4; ++t) {
            bf16x8 bv = *(bf16x8*)(ldsb + n * 256 + ((t * 64 + lg * 16) ^ ((n & 7) << 4)));
            acc[c] = __builtin_amdgcn_mfma_f32_16x16x32_bf16(a[t], bv, acc[c], 0, 0, 0);
        }
    }
    #pragma unroll 8
    for (int c = 0; c < 8; ++c) {
        int col = c * 16 + lr;
        float bc = b[col];
        #pragma unroll 4
        for (int r = 0; r < 4; ++r) {
            float v = acc[c][r] + bc;
            out[(size_t)(row0 + lg * 4 + r) * DD + col] = f2b(fmaxf(v, 0.f));
        }
    }
}

// ---------------------------------------------------------------------------
// S[p] = sum_n tanh(z_p[n] @ W_att + b_att) . q_att  via bf16 MFMA (z f32)
// ---------------------------------------------------------------------------
__global__ __launch_bounds__(256) void k_attn_mfma(
    const float* __restrict__ z0, const float* __restrict__ z1,
    const short* __restrict__ WT, const float* __restrict__ b,
    const float* __restrict__ q, float* __restrict__ S)
{
    __shared__ char ldsb[32768];
    __shared__ float red[4];
    const float* z = blockIdx.y ? z1 : z0;
    int tid = threadIdx.x;
    for (int i = tid; i < DD * DD / 8; i += 256) {
        int n = i >> 4, k8 = i & 15;
        int4 v = ((const int4*)WT)[i];
        *(int4*)(ldsb + n * 256 + ((k8 * 16) ^ ((n & 7) << 4))) = v;
    }
    __syncthreads();
    int wid = tid >> 6, l = tid & 63;
    int s = blockIdx.x * 4 + wid;
    float part = 0.f;
    if (s < NSTRIP) {
        int lr = l & 15, lg = l >> 4;
        int row0 = s * 16;
        const float4* ap = (const float4*)(z + (size_t)(row0 + lr) * DD + lg * 8);
        bf16x8 a[4];
        #pragma unroll 4
        for (int t = 0; t < 4; ++t) {
            float4 f0 = ap[8 * t], f1 = ap[8 * t + 1];
            a[t][0] = f2b(f0.x); a[t][1] = f2b(f0.y); a[t][2] = f2b(f0.z); a[t][3] = f2b(f0.w);
            a[t][4] = f2b(f1.x); a[t][5] = f2b(f1.y); a[t][6] = f2b(f1.z); a[t][7] = f2b(f1.w);
        }
        f32x4 acc[8];
        #pragma unroll 8
        for (int c = 0; c < 8; ++c) acc[c] = (f32x4){0.f, 0.f, 0.f, 0.f};
        #pragma unroll 8
        for (int c = 0; c < 8; ++c) {
            int n = c * 16 + lr;
            #pragma unroll 4
            for (int t = 0; t < 4; ++t) {
                bf16x8 bv = *(bf16x8*)(ldsb + n * 256 + ((t * 64 + lg * 16) ^ ((n & 7) << 4)));
                acc[c] = __builtin_amdgcn_mfma_f32_16x16x32_bf16(a[t], bv, acc[c], 0, 0, 0);
            }
        }
        #pragma unroll 8
        for (int c = 0; c < 8; ++c) {
            int col = c * 16 + lr;
            float bc = b[col], qc = q[col];
            #pragma unroll 4
            for (int r = 0; r < 4; ++r)
                part += tanhf(acc[c][r] + bc) * qc;
        }
    }
    for (int sh = 32; sh > 0; sh >>= 1)
        part += __shfl_down(part, sh);
    if (l == 0) red[wid] = part;
    __syncthreads();
    if (tid == 0)
        atomicAdd(&S[blockIdx.y], red[0] + red[1] + red[2] + red[3]);
}

// ---------------------------------------------------------------------------
// per-chunk partial histograms: packed-uint LDS counters (2 nodes/word),
// ushort partial out.  grid = (NCHUNK, NRANGE, 4 arrays), 512 threads.
// ---------------------------------------------------------------------------
__global__ __launch_bounds__(512) void k_hist(
    const int* __restrict__ s0, const int* __restrict__ d0,
    const int* __restrict__ s1, const int* __restrict__ d1,
    unsigned short* __restrict__ partial)
{
    __shared__ unsigned h2[RSIZE / 2];   // 50 KB
    int c = blockIdx.x, rg = blockIdx.y, a = blockIdx.z;
    const int* idx = (a == 0) ? s0 : (a == 1) ? d0 : (a == 2) ? s1 : d1;
    int lo = rg * RSIZE;
    for (int i = threadIdx.x; i < RSIZE / 2; i += 512) h2[i] = 0;
    __syncthreads();
    int beg = c * CH, end = beg + CH;
    for (int i = beg + threadIdx.x; i < end; i += 512) {
        int v = idx[i] - lo;
        if ((unsigned)v < (unsigned)RSIZE)
            atomicAdd(&h2[v >> 1], (v & 1) ? 0x10000u : 1u);
    }
    __syncthreads();
    unsigned* dst = (unsigned*)(partial + ((size_t)a * NCHUNK + c) * NN + lo);
    for (int i = threadIdx.x; i < RSIZE / 2; i += 512) dst[i] = h2[i];
}

// ---------------------------------------------------------------------------
// reduce partials -> degree + norm; dst arrays get in-place chunk prefixes
// ---------------------------------------------------------------------------
__global__ __launch_bounds__(256) void k_reduce(
    unsigned short* __restrict__ partial,
    float* ns0, float* nd0, float* ns1, float* nd1,
    int* cdeg0, int* cdeg1)
{
    int n = blockIdx.x * 256 + threadIdx.x;
    int a = blockIdx.y;
    if (n >= NN) return;
    int run = 0;
    bool isdst = a & 1;
    for (int c = 0; c < NCHUNK; ++c) {
        size_t ix = ((size_t)a * NCHUNK + c) * NN + n;
        int t = partial[ix];
        if (isdst) partial[ix] = (unsigned short)run;
        run += t;
    }
    float nv = rsqrtf((float)(run > 1 ? run : 1));
    if (a == 0) ns0[n] = nv;
    else if (a == 1) { nd0[n] = nv; cdeg0[n] = run; }
    else if (a == 2) ns1[n] = nv;
    else { nd1[n] = nv; cdeg1[n] = run; }
}

// ---------------------------------------------------------------------------
__global__ __launch_bounds__(256) void k_scan1(
    const int* __restrict__ cdeg0, const int* __restrict__ cdeg1,
    int* __restrict__ bsum)
{
    const int* dg = blockIdx.y ? cdeg1 : cdeg0;
    __shared__ int ws_[4];
    int tid = threadIdx.x;
    int n0 = blockIdx.x * 1024 + tid * 4;
    int s = 0;
    #pragma unroll
    for (int k = 0; k < 4; ++k) {
        int n = n0 + k;
        if (n < NN) s += dg[n];
    }
    for (int sh = 32; sh > 0; sh >>= 1) s += __shfl_down(s, sh);
    if ((tid & 63) == 0) ws_[tid >> 6] = s;
    __syncthreads();
    if (tid == 0)
        bsum[blockIdx.y * NSB + blockIdx.x] = ws_[0] + ws_[1] + ws_[2] + ws_[3];
}

__global__ __launch_bounds__(64) void k_scan2(
    const int* __restrict__ bsum, int* __restrict__ bbase,
    int* off0, int* off1)
{
    int p = threadIdx.x;
    if (p < 2) {
        int run = 0;
        for (int b = 0; b < NSB; ++b) {
            bbase[p * NSB + b] = run;
            run += bsum[p * NSB + b];
        }
        (p ? off1 : off0)[NN] = run;
    }
}

__global__ __launch_bounds__(256) void k_scan3(
    const int* __restrict__ cdeg0, const int* __restrict__ cdeg1,
    const int* __restrict__ bbase, int* off0, int* off1)
{
    const int* dg = blockIdx.y ? cdeg1 : cdeg0;
    int* off      = blockIdx.y ? off1  : off0;
    __shared__ int ts[256];
    int tid = threadIdx.x;
    int n0 = blockIdx.x * 1024 + tid * 4;
    int d0 = 0, d1 = 0, d2 = 0, d3 = 0;
    if (n0 + 0 < NN) d0 = dg[n0 + 0];
    if (n0 + 1 < NN) d1 = dg[n0 + 1];
    if (n0 + 2 < NN) d2 = dg[n0 + 2];
    if (n0 + 3 < NN) d3 = dg[n0 + 3];
    int tot = d0 + d1 + d2 + d3;
    ts[tid] = tot;
    __syncthreads();
    for (int s = 1; s < 256; s <<= 1) {
        int u = (tid >= s) ? ts[tid - s] : 0;
        __syncthreads();
        ts[tid] += u;
        __syncthreads();
    }
    int base = bbase[blockIdx.y * NSB + blockIdx.x] + ts[tid] - tot;
    if (n0 + 0 < NN) off[n0 + 0] = base;
    if (n0 + 1 < NN) off[n0 + 1] = base + d0;
    if (n0 + 2 < NN) off[n0 + 2] = base + d0 + d1;
    if (n0 + 3 < NN) off[n0 + 3] = base + d0 + d1 + d2;
}

// ---------------------------------------------------------------------------
// atomic-free CSR fill (packed-uint cur counters, ushort es)
// ---------------------------------------------------------------------------
__global__ __launch_bounds__(512) void k_fill2(
    const int* __restrict__ src0, const int* __restrict__ dst0,
    const int* __restrict__ src1, const int* __restrict__ dst1,
    const unsigned short* __restrict__ partial,
    const int* __restrict__ off0, const int* __restrict__ off1,
    unsigned short* __restrict__ es0, unsigned short* __restrict__ es1)
{
    __shared__ unsigned cur2[RSIZE / 2]; // 50 KB
    int c = blockIdx.x, rg = blockIdx.y, p = blockIdx.z;
    const int* src = p ? src1 : src0;
    const int* dst = p ? dst1 : dst0;
    const int* off = p ? off1 : off0;
    unsigned short* es = p ? es1 : es0;
    const unsigned short* pfx = partial + ((size_t)(1 + 2 * p) * NCHUNK + c) * NN;
    int lo = rg * RSIZE;
    for (int i = threadIdx.x; i < RSIZE / 2; i += 512) cur2[i] = 0;
    __syncthreads();
    int beg = c * CH, end = beg + CH;
    for (int i = beg + threadIdx.x; i < end; i += 512) {
        int d = dst[i];
        int v = d - lo;
        if ((unsigned)v < (unsigned)RSIZE) {
            int s = src[i];
            unsigned old = atomicAdd(&cur2[v >> 1], (v & 1) ? 0x10000u : 1u);
            int r = (v & 1) ? (int)(old >> 16) : (int)(old & 0xffffu);
            es[off[d] + (int)pfx[d] + r] = (unsigned short)s;
        }
    }
}

// ---------------------------------------------------------------------------
// merged APPNP step, premultiplied-payload variant.
// NSIN=1: input rows are raw -> multiply by ns[u] during gather (step 1).
// NSIN=0: input rows already premultiplied by ns (steps 2,3) -> chain is
//         es[e] -> xin (2 dependent levels instead of 3).
// OUTF32=0: store bf16 PREMULTIPLIED by ns[v] (feeds next step).
// OUTF32=1: store f32 z (final).
// 16 edges/iter (4 uint4 loads in flight); XCD-aware path partition.
// ---------------------------------------------------------------------------
template<int NSIN, int OUTF32>
__global__ __launch_bounds__(256) void k_appnp4(
    const unsigned* __restrict__ xin0, const unsigned* __restrict__ xin1,
    void* __restrict__ xo0, void* __restrict__ xo1,
    const unsigned* __restrict__ h0,
    const int* __restrict__ off0, const unsigned short* __restrict__ es0,
    const float* __restrict__ ns0, const float* __restrict__ nd0,
    const int* __restrict__ off1, const unsigned short* __restrict__ es1,
    const float* __restrict__ ns1, const float* __restrict__ nd1)
{
    int bid = blockIdx.x;
    int xcd = bid & 7;
    int p = xcd >> 2;
    int pblk = (bid >> 3) * 4 + (xcd & 3);
    const unsigned* xin = p ? xin1 : xin0;
    const int* off = p ? off1 : off0;
    const unsigned short* es = p ? es1 : es0;
    const float* ns = p ? ns1 : ns0;
    const float* nd = p ? nd1 : nd0;
    int wid = pblk * 4 + (threadIdx.x >> 6);
    int l = threadIdx.x & 63;
    int g = l >> 4, f = l & 15;
    int v = wid;
    int beg = off[v], end = off[v + 1];
    const uint4* xin4 = (const uint4*)xin;
    float acc[8];
    #pragma unroll
    for (int i = 0; i < 8; ++i) acc[i] = 0.f;
    for (int e = beg; e < end; e += 16) {
        int e0 = e + g, e1 = e + 4 + g, e2 = e + 8 + g, e3 = e + 12 + g;
        bool q0 = e0 < end, q1 = e1 < end, q2 = e2 < end, q3 = e3 < end;
        int u0 = q0 ? (int)es[e0] : 0;
        int u1 = q1 ? (int)es[e1] : 0;
        int u2 = q2 ? (int)es[e2] : 0;
        int u3 = q3 ? (int)es[e3] : 0;
        float s0, s1, s2, s3;
        if (NSIN) {
            s0 = q0 ? ns[u0] : 0.f;
            s1 = q1 ? ns[u1] : 0.f;
            s2 = q2 ? ns[u2] : 0.f;
            s3 = q3 ? ns[u3] : 0.f;
        } else {
            s0 = q0 ? 1.f : 0.f;
            s1 = q1 ? 1.f : 0.f;
            s2 = q2 ? 1.f : 0.f;
            s3 = q3 ? 1.f : 0.f;
        }
        uint4 w0 = xin4[(size_t)u0 * 16 + f];
        uint4 w1 = xin4[(size_t)u1 * 16 + f];
        uint4 w2 = xin4[(size_t)u2 * 16 + f];
        uint4 w3 = xin4[(size_t)u3 * 16 + f];
        acc[0] = fmaf(b2f_lo(w0.x), s0, acc[0]); acc[1] = fmaf(b2f_hi(w0.x), s0, acc[1]);
        acc[2] = fmaf(b2f_lo(w0.y), s0, acc[2]); acc[3] = fmaf(b2f_hi(w0.y), s0, acc[3]);
        acc[4] = fmaf(b2f_lo(w0.z), s0, acc[4]); acc[5] = fmaf(b2f_hi(w0.z), s0, acc[5]);
        acc[6] = fmaf(b2f_lo(w0.w), s0, acc[6]); acc[7] = fmaf(b2f_hi(w0.w), s0, acc[7]);
        acc[0] = fmaf(b2f_lo(w1.x), s1, acc[0]); acc[1] = fmaf(b2f_hi(w1.x), s1, acc[1]);
        acc[2] = fmaf(b2f_lo(w1.y), s1, acc[2]); acc[3] = fmaf(b2f_hi(w1.y), s1, acc[3]);
        acc[4] = fmaf(b2f_lo(w1.z), s1, acc[4]); acc[5] = fmaf(b2f_hi(w1.z), s1, acc[5]);
        acc[6] = fmaf(b2f_lo(w1.w), s1, acc[6]); acc[7] = fmaf(b2f_hi(w1.w), s1, acc[7]);
        acc[0] = fmaf(b2f_lo(w2.x), s2, acc[0]); acc[1] = fmaf(b2f_hi(w2.x), s2, acc[1]);
        acc[2] = fmaf(b2f_lo(w2.y), s2, acc[2]); acc[3] = fmaf(b2f_hi(w2.y), s2, acc[3]);
        acc[4] = fmaf(b2f_lo(w2.z), s2, acc[4]); acc[5] = fmaf(b2f_hi(w2.z), s2, acc[5]);
        acc[6] = fmaf(b2f_lo(w2.w), s2, acc[6]); acc[7] = fmaf(b2f_hi(w2.w), s2, acc[7]);
        acc[0] = fmaf(b2f_lo(w3.x), s3, acc[0]); acc[1] = fmaf(b2f_hi(w3.x), s3, acc[1]);
        acc[2] = fmaf(b2f_lo(w3.y), s3, acc[2]); acc[3] = fmaf(b2f_hi(w3.y), s3, acc[3]);
        acc[4] = fmaf(b2f_lo(w3.z), s3, acc[4]); acc[5] = fmaf(b2f_hi(w3.z), s3, acc[5]);
        acc[6] = fmaf(b2f_lo(w3.w), s3, acc[6]); acc[7] = fmaf(b2f_hi(w3.w), s3, acc[7]);
    }
    #pragma unroll
    for (int i = 0; i < 8; ++i) {
        acc[i] += __shfl_xor(acc[i], 16);
        acc[i] += __shfl_xor(acc[i], 32);
    }
    if (g == 0) {
        float scale = 0.9f * nd[v];
        uint4 hw = ((const uint4*)h0)[(size_t)v * 16 + f];
        float r0 = fmaf(acc[0], scale, 0.1f * b2f_lo(hw.x));
        float r1 = fmaf(acc[1], scale, 0.1f * b2f_hi(hw.x));
        float r2 = fmaf(acc[2], scale, 0.1f * b2f_lo(hw.y));
        float r3 = fmaf(acc[3], scale, 0.1f * b2f_hi(hw.y));
        float r4 = fmaf(acc[4], scale, 0.1f * b2f_lo(hw.z));
        float r5 = fmaf(acc[5], scale, 0.1f * b2f_hi(hw.z));
        float r6 = fmaf(acc[6], scale, 0.1f * b2f_lo(hw.w));
        float r7 = fmaf(acc[7], scale, 0.1f * b2f_hi(hw.w));
        if (OUTF32) {
            float4* xo = (float4*)(p ? xo1 : xo0);
            xo[(size_t)v * 32 + f * 2]     = make_float4(r0, r1, r2, r3);
            xo[(size_t)v * 32 + f * 2 + 1] = make_float4(r4, r5, r6, r7);
        } else {
            float nv = ns[v];                  // premultiply for next gather
            uint4* xo = (uint4*)(p ? xo1 : xo0);
            uint4 ov;
            ov.x = (unsigned)f2b(r0 * nv) | ((unsigned)f2b(r1 * nv) << 16);
            ov.y = (unsigned)f2b(r2 * nv) | ((unsigned)f2b(r3 * nv) << 16);
            ov.z = (unsigned)f2b(r4 * nv) | ((unsigned)f2b(r5 * nv) << 16);
            ov.w = (unsigned)f2b(r6 * nv) | ((unsigned)f2b(r7 * nv) << 16);
            xo[(size_t)v * 16 + f] = ov;
        }
    }
}

// ---------------------------------------------------------------------------
// beta = softmax(S/N); out = beta0*z0 + beta1*z1
// ---------------------------------------------------------------------------
__global__ __launch_bounds__(256) void k_combine(
    const float* __restrict__ z0, const float* __restrict__ z1,
    const float* __restrict__ S, float* __restrict__ out)
{
    float w0 = S[0] * (1.0f / NN);
    float w1 = S[1] * (1.0f / NN);
    float m  = fmaxf(w0, w1);
    float e0 = expf(w0 - m), e1 = expf(w1 - m);
    float inv = 1.0f / (e0 + e1);
    float b0 = e0 * inv, b1 = e1 * inv;
    const float4* a = (const float4*)z0;
    const float4* c = (const float4*)z1;
    float4* o = (float4*)out;
    int i = blockIdx.x * 256 + threadIdx.x;
    int stride = gridDim.x * 256;
    for (; i < NN * DD / 4; i += stride) {
        float4 x = a[i], y = c[i];
        float4 r;
        r.x = b0 * x.x + b1 * y.x;
        r.y = b0 * x.y + b1 * y.y;
        r.z = b0 * x.z + b1 * y.z;
        r.w = b0 * x.w + b1 * y.w;
        o[i] = r;
    }
}

// ---------------------------------------------------------------------------
extern "C" void kernel_launch(void* const* d_in, const int* in_sizes, int n_in,
                              void* d_out, int out_size, void* d_ws, size_t ws_size,
                              hipStream_t stream)
{
    const float* h     = (const float*)d_in[0];
    const int*   src0  = (const int*)d_in[1];
    const int*   dst0  = (const int*)d_in[2];
    const int*   src1  = (const int*)d_in[3];
    const int*   dst1  = (const int*)d_in[4];
    const float* W_h   = (const float*)d_in[5];
    const float* b_h   = (const float*)d_in[6];
    const float* W_att = (const float*)d_in[7];
    const float* b_att = (const float*)d_in[8];
    const float* q_att = (const float*)d_in[9];
    float* out = (float*)d_out;

    char* ws = (char*)d_ws;
    size_t o = 0;
    auto alloc = [&](size_t bytes) -> void* {
        void* p = ws + o;
        o += (bytes + 255) & ~(size_t)255;
        return p;
    };
    const size_t ND  = (size_t)NN * DD * sizeof(float);
    const size_t NDb = (size_t)NN * DD * sizeof(short);
    unsigned short* h1b = (unsigned short*)alloc(NDb);           // bf16 h1
    unsigned short* partial =
        (unsigned short*)alloc((size_t)4 * NCHUNK * NN * sizeof(short));
    unsigned* A0 = (unsigned*)alloc(NDb);
    unsigned* A1 = (unsigned*)alloc(NDb);
    unsigned* B0 = (unsigned*)alloc(NDb);
    unsigned* B1 = (unsigned*)alloc(NDb);
    float* z0 = (float*)alloc(ND);
    float* z1 = (float*)alloc(ND);
    float* ns0 = (float*)alloc(NN * 4);
    float* nd0 = (float*)alloc(NN * 4);
    float* ns1 = (float*)alloc(NN * 4);
    float* nd1 = (float*)alloc(NN * 4);
    int* cdeg0 = (int*)alloc(NN * 4);
    int* cdeg1 = (int*)alloc(NN * 4);
    int* off0 = (int*)alloc((NN + 1) * 4);
    int* off1 = (int*)alloc((NN + 1) * 4);
    unsigned short* es0 = (unsigned short*)alloc(EE * 2);
    unsigned short* es1 = (unsigned short*)alloc(EE * 2);
    int* bsum  = (int*)alloc(2 * NSB * 4);
    int* bbase = (int*)alloc(2 * NSB * 4);
    short* WTh = (short*)alloc(DD * DD * 2);
    short* WTa = (short*)alloc(DD * DD * 2);
    float* S   = (float*)alloc(256);
    hipMemsetAsync(S, 0, 256, stream);

    // 0. transpose+convert weights to bf16
    k_prep<<<2, 256, 0, stream>>>(W_h, W_att, WTh, WTa);
    // 1. h1 = relu(h @ W_h + b_h)  (MFMA, bf16 out)
    k_linear_mfma<<<(NSTRIP + 3) / 4, 256, 0, stream>>>(h, WTh, b_h, h1b);
    // 2. per-chunk histograms
    k_hist<<<dim3(NCHUNK, NRANGE, 4), 512, 0, stream>>>(src0, dst0, src1, dst1, partial);
    // 3. reduce -> degrees/norms + chunk prefixes
    k_reduce<<<dim3((NN + 255) / 256, 4), 256, 0, stream>>>(
        partial, ns0, nd0, ns1, nd1, cdeg0, cdeg1);
    // 4. CSR offsets: 3-pass scan
    k_scan1<<<dim3(NSB, 2), 256, 0, stream>>>(cdeg0, cdeg1, bsum);
    k_scan2<<<1, 64, 0, stream>>>(bsum, bbase, off0, off1);
    k_scan3<<<dim3(NSB, 2), 256, 0, stream>>>(cdeg0, cdeg1, bbase, off0, off1);
    // 5. atomic-free CSR fill (ushort es)
    k_fill2<<<dim3(NCHUNK, NRANGE, 2), 512, 0, stream>>>(
        src0, dst0, src1, dst1, partial, off0, off1, es0, es1);
    // 6. APPNP: step1 raw-in/premul-out; steps 2,3 premul-in
    const unsigned* h1u = (const unsigned*)h1b;
    const int agrid = 2 * ((NN + 3) / 4);     // 25000
    k_appnp4<1, 0><<<agrid, 256, 0, stream>>>(
        h1u, h1u, A0, A1, h1u,
        off0, es0, ns0, nd0, off1, es1, ns1, nd1);
    k_appnp4<0, 0><<<agrid, 256, 0, stream>>>(
        A0, A1, B0, B1, h1u,
        off0, es0, ns0, nd0, off1, es1, ns1, nd1);
    k_appnp4<0, 1><<<agrid, 256, 0, stream>>>(
        B0, B1, z0, z1, h1u,
        off0, es0, ns0, nd0, off1, es1, ns1, nd1);
    // 7. semantic attention scores (MFMA)
    k_attn_mfma<<<dim3((NSTRIP + 3) / 4, 2), 256, 0, stream>>>(
        z0, z1, WTa, b_att, q_att, S);
    // 8. softmax + weighted combine
    k_combine<<<2048, 256, 0, stream>>>(z0, z1, S, out);
    (void)in_sizes; (void)n_in; (void)out_size; (void)ws_size;
}